// Round 1
// baseline (6895.329 us; speedup 1.0000x reference)
//
#include <hip/hip_runtime.h>
#include <hip/hip_bf16.h>
#include <math.h>

#define DEV static __device__ __forceinline__

DEV float siluf(float x){ return x / (1.f + expf(-x)); }
DEV float softplusf(float x){ return (x > 20.f) ? x : log1pf(expf(x)); }

DEV unsigned short f2bf(float f){
  unsigned int u = __float_as_uint(f);
  unsigned int r = (u + 0x7FFFu + ((u >> 16) & 1u)) >> 16;
  return (unsigned short)r;
}

// ---------------- input arena offsets (floats) ----------------
constexpr long long I_LD=0, I_C0W=9216, I_C0B=10944, I_MINW=10976, I_MCONVW=1198816,
 I_MCONVB=1203936, I_MDTB=1205216, I_MALOG=1205232, I_MD=1205248, I_MNORMW=1205264,
 I_MOUTW=1206288, I_C1W=1730576, I_C1B=3303440, I_V1LNW=3304464, I_V1LNB=3304496,
 I_V1INW=3304528, I_V1CONVW=3308624, I_V1CONVB=3309200, I_V1XPW=3309264, I_V1DTW=3317968,
 I_V1DTB=3318480, I_V1ALOG=3318736, I_V1D=3322832, I_V1ONW=3323088, I_V1ONB=3323152,
 I_V1OUTW=3323216, I_DW1W=3325264, I_DW1B=3325552, I_PW1W=3325584, I_PW1B=3327632,
 I_DW2W=3327696, I_DW2B=3328272, I_PW2W=3328336, I_PW2B=3336528, I_CV1W=3336656,
 I_CV1B=3484112, I_CV2W=3484240, I_CV2B=3517008, I_FCW=3517264, I_FCB=4696912,
 I_V2LNW=4697424, I_V2LNB=4697936, I_V2INW=4698448, I_V2CONVW=5747024, I_V2CONVB=5756240,
 I_V2XPW=5757264, I_V2DTW=6019408, I_V2DTB=6150480, I_V2ALOG=6154576, I_V2D=6220112,
 I_V2ONW=6224208, I_V2ONB=6225232, I_V2OUTW=6226256;
constexpr long long TOTAL_IN = 6750544;
constexpr long long O_E8 = 6750544;                // (512,4096) lives to the very end
constexpr long long SCR  = 8847696;
// phase 1 (stages A-E)
constexpr long long O_X0=SCR+0, O_ZX=SCR+16384, O_XBCC=SCR+90624, O_DTM=SCR+131584,
 O_TPRE=SCR+132096, O_TG=SCR+164864, O_OUTM=SCR+197632, O_Y1=SCR+214016, O_H1=SCR+246784,
 O_XZ1=SCR+279552, O_XC1=SCR+410624, O_DBL1=SCR+476160, O_YS1=SCR+615424, O_G1=SCR+877568,
 O_OUTD=SCR+943104, O_E1=SCR+975872, O_E2=SCR+1008640, O_E3=SCR+1074176, O_E4=SCR+1139712,
 O_E5=SCR+1270784, O_E6=SCR+1795072, O_E7=SCR+2319360;
// phase 2 (stage F) - reuses phase-1 space (dead by then)
constexpr long long O_XZ2=SCR+0, O_XC2=SCR+8388608, O_DBL2=SCR+12582912,
 O_YS2=SCR+13631488, O_LN2=SCR+30408704, O_G2=SCR+32505856;
constexpr long long WS_FLOATS = SCR + 36700160;

struct PtrTab { const void* p[53]; };

__constant__ long long c_inoff[53] = { 0, 9216, 10944, 10976, 1198816, 1203936, 1205216,
 1205232, 1205248, 1205264, 1206288, 1730576, 3303440, 3304464, 3304496, 3304528, 3308624,
 3309200, 3309264, 3317968, 3318480, 3318736, 3322832, 3323088, 3323152, 3323216, 3325264,
 3325552, 3325584, 3327632, 3327696, 3328272, 3328336, 3336528, 3336656, 3484112, 3484240,
 3517008, 3517264, 4696912, 4697424, 4697936, 4698448, 5747024, 5756240, 5757264, 6019408,
 6150480, 6154576, 6220112, 6224208, 6225232, 6226256 };
__constant__ int c_insz[53] = { 9216, 1728, 32, 1187840, 5120, 1280, 16, 16, 16, 1024,
 524288, 1572864, 1024, 32, 32, 4096, 576, 64, 8704, 512, 256, 4096, 256, 64, 64, 2048,
 288, 32, 2048, 64, 576, 64, 8192, 128, 147456, 128, 32768, 256, 1179648, 512, 512, 512,
 1048576, 9216, 1024, 262144, 131072, 4096, 65536, 4096, 1024, 1024, 524288 };

DEV int scan_addr(int k, int l, int lg, int Lm1){
  int p = (k & 2) ? (Lm1 - l) : l;
  int mask = (1 << lg) - 1;
  if (k & 1) p = ((p & mask) << lg) | (p >> lg);
  return p;
}

// =============== ingest: convert all inputs to f32 arena ===============
__global__ void k_ingest(PtrTab t, float* __restrict__ W){
  int j = blockIdx.y;
  int idx = blockIdx.x*256 + threadIdx.x;
  if (idx >= c_insz[j]) return;
  bool bf = (*(const unsigned int*)t.p[9]) == 0x3F803F80u;
  float v;
  if (bf){
    unsigned short u = ((const unsigned short*)t.p[j])[idx];
    v = __uint_as_float(((unsigned int)u) << 16);
  } else {
    v = ((const float*)t.p[j])[idx];
  }
  W[c_inoff[j] + idx] = v;
}

// =============== stage A: c0 conv1d (18->32, k3, pad1), L=512 ===============
__global__ void k_c0(float* __restrict__ W){
  int i = blockIdx.x*256 + threadIdx.x; if (i >= 32*512) return;
  int c = i >> 9, l = i & 511;
  float acc = W[I_C0B + c];
  for (int ii=0; ii<18; ++ii)
    for (int j=0; j<3; ++j){
      int p = l-1+j;
      if (p >= 0 && p < 512) acc += W[I_LD + ii*512 + p] * W[I_C0W + (c*18+ii)*3 + j];
    }
  W[O_X0 + i] = acc;
}

// =============== stage B: mamba2 ===============
__global__ void k_zx(float* __restrict__ W){
  int i = blockIdx.x*256 + threadIdx.x; if (i >= 32*2320) return;
  int l = i / 2320, j = i % 2320;
  float acc = 0.f;
  const float* u = W + O_X0 + l*512;
  const float* wr = W + I_MINW + (long long)j*512;
  for (int d=0; d<512; ++d) acc += u[d]*wr[d];
  W[O_ZX + i] = acc;
}

__global__ void k_conv4(float* __restrict__ W){
  int i = blockIdx.x*256 + threadIdx.x; if (i >= 32*1280) return;
  int l = i / 1280, c = i % 1280;
  float acc = W[I_MCONVB + c];
  for (int j=0; j<4; ++j){
    int p = l-3+j;
    if (p >= 0) acc += W[O_ZX + p*2320 + 1024 + c] * W[I_MCONVW + c*4 + j];
  }
  W[O_XBCC + l*1280 + c] = siluf(acc);
}

__global__ void k_dtm(float* __restrict__ W){
  int i = blockIdx.x*256 + threadIdx.x; if (i >= 512) return;
  int l = i >> 4, h = i & 15;
  W[O_DTM + i] = softplusf(W[O_ZX + l*2320 + 2304 + h] + W[I_MDTB + h]);
}

__global__ void k_mscan(float* __restrict__ W){
  int h = blockIdx.x >> 6, pp = blockIdx.x & 63;
  int lane = threadIdx.x;
  float A = -expf(W[I_MALOG + h]);
  float Dv = W[I_MD + h];
  float s0 = 0.f, s1 = 0.f;
  for (int l=0; l<32; ++l){
    float dt = W[O_DTM + l*16 + h];
    float xv = W[O_XBCC + l*1280 + h*64 + pp];
    float dA = expf(dt*A);
    float b0 = W[O_XBCC + l*1280 + 1024 + lane];
    float b1 = W[O_XBCC + l*1280 + 1088 + lane];
    float c0 = W[O_XBCC + l*1280 + 1152 + lane];
    float c1 = W[O_XBCC + l*1280 + 1216 + lane];
    float du = dt*xv;
    s0 = s0*dA + du*b0;
    s1 = s1*dA + du*b1;
    float part = s0*c0 + s1*c1;
    for (int off=32; off; off>>=1) part += __shfl_xor(part, off, 64);
    if (lane == 0) W[O_TPRE + l*1024 + h*64 + pp] = part + Dv*xv;
  }
}

__global__ void k_gaterms(float* __restrict__ W){
  int l = blockIdx.x, t = threadIdx.x;
  float vals[4]; float ss = 0.f;
  for (int q=0; q<4; ++q){
    int c = t + q*256;
    float z = W[O_ZX + l*2320 + c];
    float y = W[O_TPRE + l*1024 + c];
    float v = y * siluf(z);
    vals[q] = v; ss += v*v;
  }
  for (int off=32; off; off>>=1) ss += __shfl_xor(ss, off, 64);
  __shared__ float sm[4];
  if ((t & 63) == 0) sm[t>>6] = ss;
  __syncthreads();
  float tot = sm[0]+sm[1]+sm[2]+sm[3];
  float r = rsqrtf(tot/1024.f + 1e-5f);
  for (int q=0; q<4; ++q){
    int c = t + q*256;
    W[O_TG + l*1024 + c] = vals[q]*r*W[I_MNORMW + c];
  }
}

__global__ void k_outm(float* __restrict__ W){
  int i = blockIdx.x*256 + threadIdx.x; if (i >= 32*512) return;
  int l = i >> 9, d = i & 511;
  float acc = 0.f;
  const float* tg = W + O_TG + l*1024;
  const float* wr = W + I_MOUTW + (long long)d*1024;
  for (int c=0; c<1024; ++c) acc += tg[c]*wr[c];
  W[O_OUTM + i] = acc;
}

// =============== stage C: c1 conv1d (512->1024, k3, pad1), L=32 ===============
__global__ void k_c1(float* __restrict__ W){
  int i = blockIdx.x*256 + threadIdx.x; if (i >= 1024*32) return;
  int o = i >> 5, l = i & 31;
  float acc = W[I_C1B + o];
  for (int ii=0; ii<512; ++ii)
    for (int j=0; j<3; ++j){
      int p = l-1+j;
      if (p >= 0 && p < 32) acc += W[O_OUTM + p*512 + ii] * W[I_C1W + ((long long)o*512+ii)*3 + j];
    }
  W[O_Y1 + o*32 + l] = acc;
}

// =============== vssblock shared pieces ===============
__global__ void k_ln1(float* __restrict__ W){
  int l = blockIdx.x*256 + threadIdx.x; if (l >= 1024) return;
  float s = 0.f, s2 = 0.f;
  for (int c=0; c<32; ++c){ float v = W[O_Y1 + l*32 + c]; s += v; s2 += v*v; }
  float mu = s/32.f, var = s2/32.f - mu*mu, rs = rsqrtf(var + 1e-5f);
  for (int c=0; c<32; ++c){
    float v = W[O_Y1 + l*32 + c];
    W[O_H1 + l*32 + c] = (v-mu)*rs*W[I_V1LNW + c] + W[I_V1LNB + c];
  }
}

__global__ void k_xz1(float* __restrict__ W){
  int i = blockIdx.x*256 + threadIdx.x; if (i >= 1024*128) return;
  int l = i >> 7, j = i & 127;
  float acc = 0.f;
  for (int c=0; c<32; ++c) acc += W[O_H1 + l*32 + c] * W[I_V1INW + j*32 + c];
  W[O_XZ1 + i] = acc;
}

__global__ void k_dwcs1(float* __restrict__ W){
  int i = blockIdx.x*256 + threadIdx.x; if (i >= 64*1024) return;
  int ch = i >> 10, pix = i & 1023, a = pix >> 5, b = pix & 31;
  float acc = W[I_V1CONVB + ch];
  for (int dy=0; dy<3; ++dy){
    int aa = a+dy-1; if (aa < 0 || aa > 31) continue;
    for (int dx=0; dx<3; ++dx){
      int bb = b+dx-1; if (bb < 0 || bb > 31) continue;
      acc += W[O_XZ1 + (aa*32+bb)*128 + ch] * W[I_V1CONVW + ch*9 + dy*3 + dx];
    }
  }
  W[O_XC1 + i] = siluf(acc);
}

__global__ void k_dbl1(float* __restrict__ W){
  int i = blockIdx.x*256 + threadIdx.x; if (i >= 4*34*1024) return;
  int k = i / 34816, r = i % 34816, c = r / 1024, l = r % 1024;
  int ua = scan_addr(k, l, 5, 1023);
  float acc = 0.f;
  for (int d=0; d<64; ++d) acc += W[O_XC1 + d*1024 + ua] * W[I_V1XPW + (k*34+c)*64 + d];
  W[O_DBL1 + (k*34+c)*1024 + l] = acc;
}

// fused scan: dt projection + softplus + recurrence + y-reduce + D*u, writes ys[l][k*DCH+dch]
template<int DCH, int L, int LG, int R, int CROWS>
__global__ void k_scan(float* __restrict__ W, long long o_dbl, long long o_xc, long long o_ys,
                       long long i_dtw, long long i_dtb, long long i_alog, long long i_dd){
  int g = threadIdx.x >> 4, n = threadIdx.x & 15;
  const int nb = DCH/16;
  int k = blockIdx.x / nb;
  int dch = (blockIdx.x % nb)*16 + g;
  const float* dbl = W + o_dbl + (long long)k*CROWS*L;
  const float* xc  = W + o_xc + (long long)dch*L;
  float* ys = W + o_ys;
  float A  = -expf(W[i_alog + (long long)(k*DCH+dch)*16 + n]);
  float Dv = W[i_dd + k*DCH + dch];
  float w0 = (n < R)      ? W[i_dtw + (long long)(k*DCH+dch)*R + n]      : 0.f;
  float w1 = (n+16 < R)   ? W[i_dtw + (long long)(k*DCH+dch)*R + n + 16] : 0.f;
  float bias = W[i_dtb + k*DCH + dch];
  const float* dt0 = dbl + (long long)n*L;
  const float* dt1 = dbl + (long long)(n+16)*L;
  const float* Br  = dbl + (long long)(R+n)*L;
  const float* Cr  = dbl + (long long)(R+16+n)*L;
  float s = 0.f;
  const int Lm1 = L-1, mask = (1<<LG)-1;
  for (int l=0; l<L; ++l){
    int p_ = (k & 2) ? (Lm1 - l) : l;
    int ua = (k & 1) ? (((p_ & mask) << LG) | (p_ >> LG)) : p_;
    float u = xc[ua];
    float p = 0.f;
    if (n < R)    p  = dt0[l]*w0;
    if (n+16 < R) p += dt1[l]*w1;
    p += __shfl_xor(p, 8, 16); p += __shfl_xor(p, 4, 16);
    p += __shfl_xor(p, 2, 16); p += __shfl_xor(p, 1, 16);
    float dt = softplusf(p + bias);
    float B = Br[l], C = Cr[l];
    s = s*expf(dt*A) + (dt*u)*B;
    float yv = s*C;
    yv += __shfl_xor(yv, 8, 16); yv += __shfl_xor(yv, 4, 16);
    yv += __shfl_xor(yv, 2, 16); yv += __shfl_xor(yv, 1, 16);
    if (n == 0) ys[(long long)l*(4*DCH) + k*DCH + dch] = yv + Dv*u;
  }
}

__global__ void k_comb1(float* __restrict__ W){
  int l = blockIdx.x, dch = threadIdx.x;
  int t1 = ((l & 31) << 5) | (l >> 5);
  float x = W[O_YS1 + l*256 + dch]
          + W[O_YS1 + t1*256 + 64 + dch]
          + W[O_YS1 + (1023-l)*256 + 128 + dch]
          + W[O_YS1 + (1023-t1)*256 + 192 + dch];
  float s = x, s2 = x*x;
  for (int off=32; off; off>>=1){ s += __shfl_xor(s, off, 64); s2 += __shfl_xor(s2, off, 64); }
  float mu = s/64.f, var = s2/64.f - mu*mu, rs = rsqrtf(var + 1e-5f);
  float yn = (x-mu)*rs*W[I_V1ONW + dch] + W[I_V1ONB + dch];
  float z = W[O_XZ1 + l*128 + 64 + dch];
  W[O_G1 + l*64 + dch] = yn * siluf(z);
}

__global__ void k_oproj1(float* __restrict__ W){
  int i = blockIdx.x*256 + threadIdx.x; if (i >= 1024*32) return;
  int l = i >> 5, c = i & 31;
  float acc = W[O_Y1 + i];
  for (int d=0; d<64; ++d) acc += W[O_G1 + l*64 + d] * W[I_V1OUTW + c*64 + d];
  W[O_OUTD + i] = acc;
}

// =============== stage E: conv stack ===============
__global__ void k_dw1(float* __restrict__ W){
  int i = blockIdx.x*256 + threadIdx.x; if (i >= 32*1024) return;
  int c = i >> 10, pix = i & 1023, a = pix >> 5, b = pix & 31;
  float acc = W[I_DW1B + c];
  for (int dy=0; dy<3; ++dy){
    int aa = a+dy-1; if (aa < 0 || aa > 31) continue;
    for (int dx=0; dx<3; ++dx){
      int bb = b+dx-1; if (bb < 0 || bb > 31) continue;
      acc += W[O_OUTD + (aa*32+bb)*32 + c] * W[I_DW1W + c*9 + dy*3 + dx];
    }
  }
  W[O_E1 + i] = acc;
}

__global__ void k_pw1(float* __restrict__ W){
  int i = blockIdx.x*256 + threadIdx.x; if (i >= 64*1024) return;
  int o = i >> 10, pix = i & 1023;
  float acc = W[I_PW1B + o];
  for (int c=0; c<32; ++c) acc += W[I_PW1W + o*32 + c] * W[O_E1 + c*1024 + pix];
  W[O_E2 + i] = acc;
}

__global__ void k_dw2(float* __restrict__ W){
  int i = blockIdx.x*256 + threadIdx.x; if (i >= 64*1024) return;
  int c = i >> 10, pix = i & 1023, a = pix >> 5, b = pix & 31;
  float acc = W[I_DW2B + c];
  for (int dy=0; dy<3; ++dy){
    int aa = a+dy-1; if (aa < 0 || aa > 31) continue;
    for (int dx=0; dx<3; ++dx){
      int bb = b+dx-1; if (bb < 0 || bb > 31) continue;
      acc += W[O_E2 + c*1024 + aa*32 + bb] * W[I_DW2W + c*9 + dy*3 + dx];
    }
  }
  W[O_E3 + i] = acc;
}

__global__ void k_pw2(float* __restrict__ W){
  int i = blockIdx.x*256 + threadIdx.x; if (i >= 128*1024) return;
  int o = i >> 10, pix = i & 1023;
  float acc = W[I_PW2B + o];
  for (int c=0; c<64; ++c) acc += W[I_PW2W + o*64 + c] * W[O_E3 + c*1024 + pix];
  W[O_E4 + i] = acc;
}

DEV void rs_coef(int o, int n, int& i0, int& i1, float& w0, float& w1){
  float src = 0.5f*(float)o - 0.25f;
  float f = floorf(src);
  float fr = src - f;
  int a = (int)f;
  if (a < 0){ i0 = 0; i1 = 0; w0 = 0.f; w1 = 1.f; }
  else if (a >= n-1){ i0 = n-1; i1 = n-1; w0 = 1.f; w1 = 0.f; }
  else { i0 = a; i1 = a+1; w0 = 1.f-fr; w1 = fr; }
}

__global__ void k_resize(float* __restrict__ W){
  int i = blockIdx.x*256 + threadIdx.x; if (i >= 128*4096) return;
  int c = i >> 12, pix = i & 4095, y = pix >> 6, x = pix & 63;
  int iy0, iy1, ix0, ix1; float wy0, wy1, wx0, wx1;
  rs_coef(y, 32, iy0, iy1, wy0, wy1);
  rs_coef(x, 32, ix0, ix1, wx0, wx1);
  const float* in = W + O_E4 + c*1024;
  float v = wy0*(wx0*in[iy0*32+ix0] + wx1*in[iy0*32+ix1])
          + wy1*(wx0*in[iy1*32+ix0] + wx1*in[iy1*32+ix1]);
  W[O_E5 + i] = v;
}

__global__ void k_cv1(float* __restrict__ W){
  int og = blockIdx.x >> 4, pt = blockIdx.x & 15;
  int pix = pt*256 + threadIdx.x;
  int y = pix >> 6, x = pix & 63;
  float acc[4];
  #pragma unroll
  for (int q=0; q<4; ++q) acc[q] = W[I_CV1B + og*4 + q];
  for (int i2=0; i2<128; ++i2){
    const float* in = W + O_E5 + i2*4096;
    for (int dy=0; dy<3; ++dy){
      int yy = y+dy-1; if (yy < 0 || yy > 63) continue;
      for (int dx=0; dx<3; ++dx){
        int xx = x+dx-1; if (xx < 0 || xx > 63) continue;
        float v = in[yy*64+xx];
        #pragma unroll
        for (int q=0; q<4; ++q)
          acc[q] += v * W[I_CV1W + ((long long)(og*4+q)*128 + i2)*9 + dy*3 + dx];
      }
    }
  }
  #pragma unroll
  for (int q=0; q<4; ++q) W[O_E6 + (long long)(og*4+q)*4096 + pix] = acc[q];
}

__global__ void k_cv2(float* __restrict__ W){
  int i = blockIdx.x*256 + threadIdx.x; if (i >= 256*4096) return;
  int o = i >> 12, pix = i & 4095;
  float acc = W[I_CV2B + o];
  for (int c=0; c<128; ++c) acc += W[I_CV2W + o*128 + c] * W[O_E6 + c*4096 + pix];
  W[O_E7 + i] = acc;
}

__global__ void k_fc(float* __restrict__ W){
  int og = blockIdx.x >> 4, pt = blockIdx.x & 15;
  int pix = pt*256 + threadIdx.x;
  int y = pix >> 6, x = pix & 63;
  float acc[4];
  #pragma unroll
  for (int q=0; q<4; ++q) acc[q] = W[I_FCB + og*4 + q];
  for (int i2=0; i2<256; ++i2){
    const float* in = W + O_E7 + i2*4096;
    for (int dy=0; dy<3; ++dy){
      int yy = y+dy-1; if (yy < 0 || yy > 63) continue;
      for (int dx=0; dx<3; ++dx){
        int xx = x+dx-1; if (xx < 0 || xx > 63) continue;
        float v = in[yy*64+xx];
        #pragma unroll
        for (int q=0; q<4; ++q)
          acc[q] += v * W[I_FCW + ((long long)(og*4+q)*256 + i2)*9 + dy*3 + dx];
      }
    }
  }
  #pragma unroll
  for (int q=0; q<4; ++q) W[O_E8 + (long long)(og*4+q)*4096 + pix] = acc[q];
}

// =============== stage F: vssblock2 ===============
__global__ void k_ln2(float* __restrict__ W){
  int l = blockIdx.x, t = threadIdx.x;
  float v0 = W[O_E8 + (long long)t*4096 + l];
  float v1 = W[O_E8 + (long long)(t+256)*4096 + l];
  float s = v0+v1, s2 = v0*v0 + v1*v1;
  for (int off=32; off; off>>=1){ s += __shfl_xor(s, off, 64); s2 += __shfl_xor(s2, off, 64); }
  __shared__ float a[4], b[4];
  if ((t & 63) == 0){ a[t>>6] = s; b[t>>6] = s2; }
  __syncthreads();
  float S = a[0]+a[1]+a[2]+a[3], S2 = b[0]+b[1]+b[2]+b[3];
  float mu = S/512.f, var = S2/512.f - mu*mu, rs = rsqrtf(var + 1e-5f);
  W[O_LN2 + (long long)l*512 + t]     = (v0-mu)*rs*W[I_V2LNW + t]     + W[I_V2LNB + t];
  W[O_LN2 + (long long)l*512 + t+256] = (v1-mu)*rs*W[I_V2LNW + t+256] + W[I_V2LNB + t+256];
}

__global__ void k_xz2(float* __restrict__ W){
  // grid (64 ltiles, 64 jtiles), block 256 = 64 l x 4 jg, 8 j per thread
  int l = blockIdx.x*64 + (threadIdx.x & 63);
  int jbase = blockIdx.y*32 + (threadIdx.x >> 6)*8;
  float acc[8];
  #pragma unroll
  for (int q=0; q<8; ++q) acc[q] = 0.f;
  const float* h = W + O_LN2 + (long long)l*512;
  const float* wgt = W + I_V2INW;
  for (int d=0; d<512; ++d){
    float hv = h[d];
    #pragma unroll
    for (int q=0; q<8; ++q) acc[q] += hv * wgt[(long long)(jbase+q)*512 + d];
  }
  #pragma unroll
  for (int q=0; q<8; ++q) W[O_XZ2 + (long long)l*2048 + jbase + q] = acc[q];
}

__global__ void k_dwcs2(float* __restrict__ W){
  int i = blockIdx.x*256 + threadIdx.x; if (i >= 1024*4096) return;
  int ch = i >> 12, pix = i & 4095, a = pix >> 6, b = pix & 63;
  float acc = W[I_V2CONVB + ch];
  for (int dy=0; dy<3; ++dy){
    int aa = a+dy-1; if (aa < 0 || aa > 63) continue;
    for (int dx=0; dx<3; ++dx){
      int bb = b+dx-1; if (bb < 0 || bb > 63) continue;
      acc += W[O_XZ2 + (long long)(aa*64+bb)*2048 + ch] * W[I_V2CONVW + ch*9 + dy*3 + dx];
    }
  }
  W[O_XC2 + (long long)i] = siluf(acc);
}

__global__ void k_dbl2(float* __restrict__ W){
  int bx = blockIdx.x;
  int k = bx >> 6, cg = (bx >> 4) & 3, lt = bx & 15;
  int l = lt*256 + threadIdx.x;
  float acc[16];
  #pragma unroll
  for (int q=0; q<16; ++q) acc[q] = 0.f;
  int ua = scan_addr(k, l, 6, 4095);
  for (int d=0; d<1024; ++d){
    float v = W[O_XC2 + (long long)d*4096 + ua];
    #pragma unroll
    for (int q=0; q<16; ++q)
      acc[q] += v * W[I_V2XPW + (long long)(k*64 + cg*16 + q)*1024 + d];
  }
  #pragma unroll
  for (int q=0; q<16; ++q) W[O_DBL2 + (long long)(k*64 + cg*16 + q)*4096 + l] = acc[q];
}

__global__ void k_comb2(float* __restrict__ W){
  int l = blockIdx.x, t = threadIdx.x;
  int t1 = ((l & 63) << 6) | (l >> 6);
  float v[4]; float s = 0.f, s2 = 0.f;
  for (int q=0; q<4; ++q){
    int dch = t + q*256;
    float x = W[O_YS2 + (long long)l*4096 + dch]
            + W[O_YS2 + (long long)t1*4096 + 1024 + dch]
            + W[O_YS2 + (long long)(4095-l)*4096 + 2048 + dch]
            + W[O_YS2 + (long long)(4095-t1)*4096 + 3072 + dch];
    v[q] = x; s += x; s2 += x*x;
  }
  for (int off=32; off; off>>=1){ s += __shfl_xor(s, off, 64); s2 += __shfl_xor(s2, off, 64); }
  __shared__ float a[4], b[4];
  if ((t & 63) == 0){ a[t>>6] = s; b[t>>6] = s2; }
  __syncthreads();
  float S = a[0]+a[1]+a[2]+a[3], S2 = b[0]+b[1]+b[2]+b[3];
  float mu = S/1024.f, var = S2/1024.f - mu*mu, rs = rsqrtf(var + 1e-5f);
  for (int q=0; q<4; ++q){
    int dch = t + q*256;
    float yn = (v[q]-mu)*rs*W[I_V2ONW + dch] + W[I_V2ONB + dch];
    float z = W[O_XZ2 + (long long)l*2048 + 1024 + dch];
    W[O_G2 + (long long)l*1024 + dch] = yn * siluf(z);
  }
}

__global__ void k_oproj2(float* __restrict__ W, const unsigned int* flagp, void* dout){
  int cg = blockIdx.x >> 4, lt = blockIdx.x & 15;
  int l = lt*256 + threadIdx.x;
  float acc[8];
  #pragma unroll
  for (int q=0; q<8; ++q) acc[q] = 0.f;
  const float* g = W + O_G2 + (long long)l*1024;
  for (int d=0; d<1024; ++d){
    float gv = g[d];
    #pragma unroll
    for (int q=0; q<8; ++q) acc[q] += gv * W[I_V2OUTW + (long long)(cg*8+q)*1024 + d];
  }
  bool bf = (*flagp) == 0x3F803F80u;
  #pragma unroll
  for (int q=0; q<8; ++q){
    int c = cg*8 + q;
    long long o = (long long)c*4096 + l;
    float v = W[O_E8 + o] + acc[q];
    if (bf) ((unsigned short*)dout)[o] = f2bf(v);
    else    ((float*)dout)[o] = v;
  }
}

// =============== launch ===============
extern "C" void kernel_launch(void* const* d_in, const int* in_sizes, int n_in,
                              void* d_out, int out_size, void* d_ws, size_t ws_size,
                              hipStream_t stream){
  if (ws_size < (size_t)WS_FLOATS * sizeof(float)) return; // insufficient scratch
  float* W = (float*)d_ws;
  PtrTab tab;
  for (int i=0; i<53; ++i) tab.p[i] = d_in[i];

  k_ingest<<<dim3(6144, 53), 256, 0, stream>>>(tab, W);
  k_c0    <<<64, 256, 0, stream>>>(W);
  k_zx    <<<290, 256, 0, stream>>>(W);
  k_conv4 <<<160, 256, 0, stream>>>(W);
  k_dtm   <<<2, 256, 0, stream>>>(W);
  k_mscan <<<1024, 64, 0, stream>>>(W);
  k_gaterms<<<32, 256, 0, stream>>>(W);
  k_outm  <<<64, 256, 0, stream>>>(W);
  k_c1    <<<128, 256, 0, stream>>>(W);
  k_ln1   <<<4, 256, 0, stream>>>(W);
  k_xz1   <<<512, 256, 0, stream>>>(W);
  k_dwcs1 <<<256, 256, 0, stream>>>(W);
  k_dbl1  <<<544, 256, 0, stream>>>(W);
  k_scan<64, 1024, 5, 2, 34><<<16, 256, 0, stream>>>(W, O_DBL1, O_XC1, O_YS1,
                                                     I_V1DTW, I_V1DTB, I_V1ALOG, I_V1D);
  k_comb1 <<<1024, 64, 0, stream>>>(W);
  k_oproj1<<<128, 256, 0, stream>>>(W);
  k_dw1   <<<128, 256, 0, stream>>>(W);
  k_pw1   <<<256, 256, 0, stream>>>(W);
  k_dw2   <<<256, 256, 0, stream>>>(W);
  k_pw2   <<<512, 256, 0, stream>>>(W);
  k_resize<<<2048, 256, 0, stream>>>(W);
  k_cv1   <<<512, 256, 0, stream>>>(W);
  k_cv2   <<<4096, 256, 0, stream>>>(W);
  k_fc    <<<2048, 256, 0, stream>>>(W);
  k_ln2   <<<4096, 256, 0, stream>>>(W);
  k_xz2   <<<dim3(64, 64), 256, 0, stream>>>(W);
  k_dwcs2 <<<16384, 256, 0, stream>>>(W);
  k_dbl2  <<<256, 256, 0, stream>>>(W);
  k_scan<1024, 4096, 6, 32, 64><<<256, 256, 0, stream>>>(W, O_DBL2, O_XC2, O_YS2,
                                                         I_V2DTW, I_V2DTB, I_V2ALOG, I_V2D);
  k_comb2 <<<4096, 256, 0, stream>>>(W);
  k_oproj2<<<1024, 256, 0, stream>>>(W, (const unsigned int*)d_in[9], d_out);
}

// Round 3
// 2778.643 us; speedup vs baseline: 2.4815x; 2.4815x over previous
//
#include <hip/hip_runtime.h>
#include <hip/hip_bf16.h>
#include <hip/hip_fp16.h>
#include <math.h>

#define DEV static __device__ __forceinline__

DEV float siluf(float x){ return x / (1.f + expf(-x)); }
DEV float softplusf(float x){ return (x > 20.f) ? x : log1pf(__expf(x)); }

DEV unsigned short f2bf(float f){
  unsigned int u = __float_as_uint(f);
  unsigned int r = (u + 0x7FFFu + ((u >> 16) & 1u)) >> 16;
  return (unsigned short)r;
}

// ---------------- input arena offsets (floats) ----------------
constexpr long long I_LD=0, I_C0W=9216, I_C0B=10944, I_MINW=10976, I_MCONVW=1198816,
 I_MCONVB=1203936, I_MDTB=1205216, I_MALOG=1205232, I_MD=1205248, I_MNORMW=1205264,
 I_MOUTW=1206288, I_C1W=1730576, I_C1B=3303440, I_V1LNW=3304464, I_V1LNB=3304496,
 I_V1INW=3304528, I_V1CONVW=3308624, I_V1CONVB=3309200, I_V1XPW=3309264, I_V1DTW=3317968,
 I_V1DTB=3318480, I_V1ALOG=3318736, I_V1D=3322832, I_V1ONW=3323088, I_V1ONB=3323152,
 I_V1OUTW=3323216, I_DW1W=3325264, I_DW1B=3325552, I_PW1W=3325584, I_PW1B=3327632,
 I_DW2W=3327696, I_DW2B=3328272, I_PW2W=3328336, I_PW2B=3336528, I_CV1W=3336656,
 I_CV1B=3484112, I_CV2W=3484240, I_CV2B=3517008, I_FCW=3517264, I_FCB=4696912,
 I_V2LNW=4697424, I_V2LNB=4697936, I_V2INW=4698448, I_V2CONVW=5747024, I_V2CONVB=5756240,
 I_V2XPW=5757264, I_V2DTW=6019408, I_V2DTB=6150480, I_V2ALOG=6154576, I_V2D=6220112,
 I_V2ONW=6224208, I_V2ONB=6225232, I_V2OUTW=6226256;
constexpr long long TOTAL_IN = 6750544;
constexpr int INGEST_BLOCKS = (int)((TOTAL_IN + 255) / 256);   // R2 bug: was 26369, missing tail 80 elems
constexpr long long O_E8 = 6750544;                // (512,4096) lives to the very end
constexpr long long SCR  = 8847696;
// phase 1 (stages A-E)
constexpr long long O_X0=SCR+0, O_ZX=SCR+16384, O_XBCC=SCR+90624, O_DTM=SCR+131584,
 O_TPRE=SCR+132096, O_TG=SCR+164864, O_OUTM=SCR+197632, O_Y1=SCR+214016, O_H1=SCR+246784,
 O_XZ1=SCR+279552, O_XC1=SCR+410624, O_DBL1=SCR+476160, O_YS1=SCR+615424, O_G1=SCR+877568,
 O_OUTD=SCR+943104, O_E1=SCR+975872, O_E2=SCR+1008640, O_E3=SCR+1074176, O_E4=SCR+1139712,
 O_E5=SCR+1270784, O_E6=SCR+1795072, O_E7=SCR+2319360;
// vss1 scan scratch
constexpr long long O_XT1=SCR+3367936, O_P1=SCR+3433472, O_S1=SCR+3499008;
// phase 2 (stage F) - reuses phase-1 space (dead by then)
constexpr long long O_XZ2=SCR+0;                        // 8.4M  (z half live till comb2)
constexpr long long O_XC2=SCR+8388608;                  // 4.19M (dead after xt2)
constexpr long long O_P2 =O_XC2;                        // overlay: written in pass1
constexpr long long O_XT2=SCR+12582912;                 // 4.19M (XP first, then XT2)
constexpr long long O_G2 =O_XT2;                        // overlay: written in comb2
constexpr long long O_DBL2=SCR+16777216;                // 1.05M
constexpr long long O_S2 =SCR+17825792;                 // 4.19M
constexpr long long O_YS2=SCR+22020096;                 // 8.4M float-slots (fp16 ys)
constexpr long long O_LN2=SCR+30408704;                 // 2.1M
constexpr long long WS_FLOATS = SCR + 36700160;

struct PtrTab { const void* p[53]; };

__constant__ long long c_inoff[53] = { 0, 9216, 10944, 10976, 1198816, 1203936, 1205216,
 1205232, 1205248, 1205264, 1206288, 1730576, 3303440, 3304464, 3304496, 3304528, 3308624,
 3309200, 3309264, 3317968, 3318480, 3318736, 3322832, 3323088, 3323152, 3323216, 3325264,
 3325552, 3325584, 3327632, 3327696, 3328272, 3328336, 3336528, 3336656, 3484112, 3484240,
 3517008, 3517264, 4696912, 4697424, 4697936, 4698448, 5747024, 5756240, 5757264, 6019408,
 6150480, 6154576, 6220112, 6224208, 6225232, 6226256 };

DEV int scan_addr(int k, int l, int lg, int Lm1){
  int p = (k & 2) ? (Lm1 - l) : l;
  int mask = (1 << lg) - 1;
  if (k & 1) p = ((p & mask) << lg) | (p >> lg);
  return p;
}

// =============== ingest: convert all inputs to f32 arena ===============
__global__ void k_ingest(PtrTab t, float* __restrict__ W){
  long long idx = (long long)blockIdx.x*256 + threadIdx.x;
  if (idx >= TOTAL_IN) return;
  int j = 0;
  #pragma unroll
  for (int q=1; q<53; ++q) if (idx >= c_inoff[q]) j = q;
  int local = (int)(idx - c_inoff[j]);
  bool bf = (*(const unsigned int*)t.p[9]) == 0x3F803F80u;
  float v;
  if (bf){
    unsigned short u = ((const unsigned short*)t.p[j])[local];
    v = __uint_as_float(((unsigned int)u) << 16);
  } else {
    v = ((const float*)t.p[j])[local];
  }
  W[idx] = v;
}

// =============== generic 32x32 tiled transpose ===============
__global__ void k_transpose(const float* __restrict__ in, float* __restrict__ out,
                            int rows, int cols, long long instride, long long outstride){
  __shared__ float tile[32][33];
  int tx = threadIdx.x & 31, ty = threadIdx.x >> 5;
  long long c0 = (long long)blockIdx.x*32, r0 = (long long)blockIdx.y*32;
  #pragma unroll
  for (int i=0;i<32;i+=8){
    long long r = r0 + ty + i, c = c0 + tx;
    if (r < rows && c < cols) tile[ty+i][tx] = in[r*instride + c];
  }
  __syncthreads();
  #pragma unroll
  for (int i=0;i<32;i+=8){
    long long r = r0 + tx, c = c0 + ty + i;
    if (r < rows && c < cols) out[c*outstride + r] = tile[tx][ty+i];
  }
}

// =============== chunked selective-scan (3 passes) ===============
template<int DCH, int TD, int L, int LG, int T, int R, int CROWS>
__global__ void k_scan_p1(float* __restrict__ W, long long o_dbl, long long o_xt,
                          long long o_p, long long o_s,
                          long long i_dtw, long long i_dtb, long long i_alog){
  constexpr int NT = DCH/TD;
  int k = blockIdx.x / NT, tile = blockIdx.x % NT;
  int c = blockIdx.y;
  int t = threadIdx.x;
  int dch = tile*TD + t;
  __shared__ float lds[CROWS*T];
  const float* dbl = W + o_dbl + (long long)k*CROWS*L + (long long)c*T;
  for (int idx = t; idx < CROWS*T; idx += TD){
    int row = idx / T, col = idx % T;
    lds[idx] = dbl[(long long)row*L + col];
  }
  __syncthreads();
  float w[R], A[16], p[16], s[16];
  #pragma unroll
  for (int r=0;r<R;++r) w[r] = W[i_dtw + (long long)(k*DCH+dch)*R + r];
  float bias = W[i_dtb + k*DCH + dch];
  #pragma unroll
  for (int n=0;n<16;++n){
    A[n] = -expf(W[i_alog + (long long)(k*DCH+dch)*16 + n]);
    p[n] = 1.f; s[n] = 0.f;
  }
  const float* XT = W + o_xt;
  const int Lm1 = L-1, mask = (1<<LG)-1;
  for (int j=0;j<T;++j){
    int l = c*T + j;
    int p_ = (k&2)? (Lm1-l) : l;
    int ua = (k&1)? (((p_&mask)<<LG)|(p_>>LG)) : p_;
    float u = XT[(long long)ua*DCH + dch];
    float dt = bias;
    #pragma unroll
    for (int r=0;r<R;++r) dt += lds[r*T+j]*w[r];
    dt = softplusf(dt);
    float du = dt*u;
    #pragma unroll
    for (int n=0;n<16;++n){
      float dA = __expf(dt*A[n]);
      float B = lds[(R+n)*T + j];
      p[n] *= dA;
      s[n] = s[n]*dA + du*B;
    }
  }
  float* P = W + o_p; float* S = W + o_s;
  long long base = (long long)c*(4LL*DCH*16) + (long long)k*DCH*16 + (long long)dch*16;
  #pragma unroll
  for (int n=0;n<16;++n){ P[base+n] = p[n]; S[base+n] = s[n]; }
}

template<int NSTATE, int CH>
__global__ void k_carry(float* __restrict__ W, long long o_p, long long o_s){
  int idx = blockIdx.x*256 + threadIdx.x;
  if (idx >= NSTATE) return;
  const float* P = W + o_p; float* S = W + o_s;
  float h = 0.f;
  for (int c=0;c<CH;++c){
    float p = P[(long long)c*NSTATE + idx];
    float s = S[(long long)c*NSTATE + idx];
    S[(long long)c*NSTATE + idx] = h;
    h = h*p + s;
  }
}

template<int DCH, int TD, int L, int LG, int T, int R, int CROWS>
__global__ void k_scan_p3(float* __restrict__ W, long long o_dbl, long long o_xt,
                          long long o_s, long long o_ys,
                          long long i_dtw, long long i_dtb, long long i_alog, long long i_dd){
  constexpr int NT = DCH/TD;
  int k = blockIdx.x / NT, tile = blockIdx.x % NT;
  int c = blockIdx.y;
  int t = threadIdx.x;
  int dch = tile*TD + t;
  __shared__ float lds[CROWS*T];
  const float* dbl = W + o_dbl + (long long)k*CROWS*L + (long long)c*T;
  for (int idx = t; idx < CROWS*T; idx += TD){
    int row = idx / T, col = idx % T;
    lds[idx] = dbl[(long long)row*L + col];
  }
  __syncthreads();
  float w[R], A[16], s[16];
  #pragma unroll
  for (int r=0;r<R;++r) w[r] = W[i_dtw + (long long)(k*DCH+dch)*R + r];
  float bias = W[i_dtb + k*DCH + dch];
  float Dv = W[i_dd + k*DCH + dch];
  long long sbase = (long long)c*(4LL*DCH*16) + (long long)k*DCH*16 + (long long)dch*16;
  #pragma unroll
  for (int n=0;n<16;++n){
    A[n] = -expf(W[i_alog + (long long)(k*DCH+dch)*16 + n]);
    s[n] = W[o_s + sbase + n];
  }
  const float* XT = W + o_xt;
  __half* Y = (__half*)(W + o_ys);
  const int Lm1 = L-1, mask = (1<<LG)-1;
  for (int j=0;j<T;++j){
    int l = c*T + j;
    int p_ = (k&2)? (Lm1-l) : l;
    int ua = (k&1)? (((p_&mask)<<LG)|(p_>>LG)) : p_;
    float u = XT[(long long)ua*DCH + dch];
    float dt = bias;
    #pragma unroll
    for (int r=0;r<R;++r) dt += lds[r*T+j]*w[r];
    dt = softplusf(dt);
    float du = dt*u;
    float y = Dv*u;
    #pragma unroll
    for (int n=0;n<16;++n){
      float dA = __expf(dt*A[n]);
      float B = lds[(R+n)*T + j];
      float C = lds[(R+16+n)*T + j];
      s[n] = s[n]*dA + du*B;
      y += s[n]*C;
    }
    Y[(long long)l*(4*DCH) + k*DCH + dch] = __float2half(y);
  }
}

// =============== stage A: c0 conv1d (18->32, k3, pad1), L=512 ===============
__global__ void k_c0(float* __restrict__ W){
  int i = blockIdx.x*256 + threadIdx.x; if (i >= 32*512) return;
  int c = i >> 9, l = i & 511;
  float acc = W[I_C0B + c];
  for (int ii=0; ii<18; ++ii)
    for (int j=0; j<3; ++j){
      int p = l-1+j;
      if (p >= 0 && p < 512) acc += W[I_LD + ii*512 + p] * W[I_C0W + (c*18+ii)*3 + j];
    }
  W[O_X0 + i] = acc;
}

// =============== stage B: mamba2 ===============
__global__ void k_zx(float* __restrict__ W){
  int i = blockIdx.x*256 + threadIdx.x; if (i >= 32*2320) return;
  int l = i / 2320, j = i % 2320;
  float acc = 0.f;
  const float* u = W + O_X0 + l*512;
  const float* wr = W + I_MINW + (long long)j*512;
  for (int d=0; d<512; ++d) acc += u[d]*wr[d];
  W[O_ZX + i] = acc;
}

__global__ void k_conv4(float* __restrict__ W){
  int i = blockIdx.x*256 + threadIdx.x; if (i >= 32*1280) return;
  int l = i / 1280, c = i % 1280;
  float acc = W[I_MCONVB + c];
  for (int j=0; j<4; ++j){
    int p = l-3+j;
    if (p >= 0) acc += W[O_ZX + p*2320 + 1024 + c] * W[I_MCONVW + c*4 + j];
  }
  W[O_XBCC + l*1280 + c] = siluf(acc);
}

__global__ void k_dtm(float* __restrict__ W){
  int i = blockIdx.x*256 + threadIdx.x; if (i >= 512) return;
  int l = i >> 4, h = i & 15;
  W[O_DTM + i] = softplusf(W[O_ZX + l*2320 + 2304 + h] + W[I_MDTB + h]);
}

__global__ void k_mscan(float* __restrict__ W){
  int h = blockIdx.x >> 6, pp = blockIdx.x & 63;
  int lane = threadIdx.x;
  float A = -expf(W[I_MALOG + h]);
  float Dv = W[I_MD + h];
  float s0 = 0.f, s1 = 0.f;
  for (int l=0; l<32; ++l){
    float dt = W[O_DTM + l*16 + h];
    float xv = W[O_XBCC + l*1280 + h*64 + pp];
    float dA = expf(dt*A);
    float b0 = W[O_XBCC + l*1280 + 1024 + lane];
    float b1 = W[O_XBCC + l*1280 + 1088 + lane];
    float c0 = W[O_XBCC + l*1280 + 1152 + lane];
    float c1 = W[O_XBCC + l*1280 + 1216 + lane];
    float du = dt*xv;
    s0 = s0*dA + du*b0;
    s1 = s1*dA + du*b1;
    float part = s0*c0 + s1*c1;
    for (int off=32; off; off>>=1) part += __shfl_xor(part, off, 64);
    if (lane == 0) W[O_TPRE + l*1024 + h*64 + pp] = part + Dv*xv;
  }
}

__global__ void k_gaterms(float* __restrict__ W){
  int l = blockIdx.x, t = threadIdx.x;
  float vals[4]; float ss = 0.f;
  for (int q=0; q<4; ++q){
    int c = t + q*256;
    float z = W[O_ZX + l*2320 + c];
    float y = W[O_TPRE + l*1024 + c];
    float v = y * siluf(z);
    vals[q] = v; ss += v*v;
  }
  for (int off=32; off; off>>=1) ss += __shfl_xor(ss, off, 64);
  __shared__ float sm[4];
  if ((t & 63) == 0) sm[t>>6] = ss;
  __syncthreads();
  float tot = sm[0]+sm[1]+sm[2]+sm[3];
  float r = rsqrtf(tot/1024.f + 1e-5f);
  for (int q=0; q<4; ++q){
    int c = t + q*256;
    W[O_TG + l*1024 + c] = vals[q]*r*W[I_MNORMW + c];
  }
}

__global__ void k_outm(float* __restrict__ W){
  int i = blockIdx.x*256 + threadIdx.x; if (i >= 32*512) return;
  int l = i >> 9, d = i & 511;
  float acc = 0.f;
  const float* tg = W + O_TG + l*1024;
  const float* wr = W + I_MOUTW + (long long)d*1024;
  for (int c=0; c<1024; ++c) acc += tg[c]*wr[c];
  W[O_OUTM + i] = acc;
}

// =============== stage C: c1 conv1d (512->1024, k3, pad1), L=32 ===============
__global__ void k_c1(float* __restrict__ W){
  int i = blockIdx.x*256 + threadIdx.x; if (i >= 1024*32) return;
  int o = i >> 5, l = i & 31;
  float acc = W[I_C1B + o];
  for (int ii=0; ii<512; ++ii)
    for (int j=0; j<3; ++j){
      int p = l-1+j;
      if (p >= 0 && p < 32) acc += W[O_OUTM + p*512 + ii] * W[I_C1W + ((long long)o*512+ii)*3 + j];
    }
  W[O_Y1 + o*32 + l] = acc;
}

// =============== vssblock 1 ===============
__global__ void k_ln1(float* __restrict__ W){
  int l = blockIdx.x*256 + threadIdx.x; if (l >= 1024) return;
  float s = 0.f, s2 = 0.f;
  for (int c=0; c<32; ++c){ float v = W[O_Y1 + l*32 + c]; s += v; s2 += v*v; }
  float mu = s/32.f, var = s2/32.f - mu*mu, rs = rsqrtf(var + 1e-5f);
  for (int c=0; c<32; ++c){
    float v = W[O_Y1 + l*32 + c];
    W[O_H1 + l*32 + c] = (v-mu)*rs*W[I_V1LNW + c] + W[I_V1LNB + c];
  }
}

__global__ void k_xz1(float* __restrict__ W){
  int i = blockIdx.x*256 + threadIdx.x; if (i >= 1024*128) return;
  int l = i >> 7, j = i & 127;
  float acc = 0.f;
  for (int c=0; c<32; ++c) acc += W[O_H1 + l*32 + c] * W[I_V1INW + j*32 + c];
  W[O_XZ1 + i] = acc;
}

__global__ void k_dwcs1(float* __restrict__ W){
  int i = blockIdx.x*256 + threadIdx.x; if (i >= 64*1024) return;
  int ch = i >> 10, pix = i & 1023, a = pix >> 5, b = pix & 31;
  float acc = W[I_V1CONVB + ch];
  for (int dy=0; dy<3; ++dy){
    int aa = a+dy-1; if (aa < 0 || aa > 31) continue;
    for (int dx=0; dx<3; ++dx){
      int bb = b+dx-1; if (bb < 0 || bb > 31) continue;
      acc += W[O_XZ1 + (aa*32+bb)*128 + ch] * W[I_V1CONVW + ch*9 + dy*3 + dx];
    }
  }
  W[O_XC1 + i] = siluf(acc);
}

__global__ void k_dbl1(float* __restrict__ W){
  int i = blockIdx.x*256 + threadIdx.x; if (i >= 4*34*1024) return;
  int k = i / 34816, r = i % 34816, c = r / 1024, l = r % 1024;
  int ua = scan_addr(k, l, 5, 1023);
  float acc = 0.f;
  for (int d=0; d<64; ++d) acc += W[O_XC1 + d*1024 + ua] * W[I_V1XPW + (k*34+c)*64 + d];
  W[O_DBL1 + (k*34+c)*1024 + l] = acc;
}

__global__ void k_comb1(float* __restrict__ W){
  int l = blockIdx.x, dch = threadIdx.x;
  int t1 = ((l & 31) << 5) | (l >> 5);
  const __half* Y = (const __half*)(W + O_YS1);
  float x = __half2float(Y[l*256 + dch])
          + __half2float(Y[t1*256 + 64 + dch])
          + __half2float(Y[(1023-l)*256 + 128 + dch])
          + __half2float(Y[(1023-t1)*256 + 192 + dch]);
  float s = x, s2 = x*x;
  for (int off=32; off; off>>=1){ s += __shfl_xor(s, off, 64); s2 += __shfl_xor(s2, off, 64); }
  float mu = s/64.f, var = s2/64.f - mu*mu, rs = rsqrtf(var + 1e-5f);
  float yn = (x-mu)*rs*W[I_V1ONW + dch] + W[I_V1ONB + dch];
  float z = W[O_XZ1 + l*128 + 64 + dch];
  W[O_G1 + l*64 + dch] = yn * siluf(z);
}

__global__ void k_oproj1(float* __restrict__ W){
  int i = blockIdx.x*256 + threadIdx.x; if (i >= 1024*32) return;
  int l = i >> 5, c = i & 31;
  float acc = W[O_Y1 + i];
  for (int d=0; d<64; ++d) acc += W[O_G1 + l*64 + d] * W[I_V1OUTW + c*64 + d];
  W[O_OUTD + i] = acc;
}

// =============== stage E: conv stack ===============
__global__ void k_dw1(float* __restrict__ W){
  int i = blockIdx.x*256 + threadIdx.x; if (i >= 32*1024) return;
  int c = i >> 10, pix = i & 1023, a = pix >> 5, b = pix & 31;
  float acc = W[I_DW1B + c];
  for (int dy=0; dy<3; ++dy){
    int aa = a+dy-1; if (aa < 0 || aa > 31) continue;
    for (int dx=0; dx<3; ++dx){
      int bb = b+dx-1; if (bb < 0 || bb > 31) continue;
      acc += W[O_OUTD + (aa*32+bb)*32 + c] * W[I_DW1W + c*9 + dy*3 + dx];
    }
  }
  W[O_E1 + i] = acc;
}

__global__ void k_pw1(float* __restrict__ W){
  int i = blockIdx.x*256 + threadIdx.x; if (i >= 64*1024) return;
  int o = i >> 10, pix = i & 1023;
  float acc = W[I_PW1B + o];
  for (int c=0; c<32; ++c) acc += W[I_PW1W + o*32 + c] * W[O_E1 + c*1024 + pix];
  W[O_E2 + i] = acc;
}

__global__ void k_dw2(float* __restrict__ W){
  int i = blockIdx.x*256 + threadIdx.x; if (i >= 64*1024) return;
  int c = i >> 10, pix = i & 1023, a = pix >> 5, b = pix & 31;
  float acc = W[I_DW2B + c];
  for (int dy=0; dy<3; ++dy){
    int aa = a+dy-1; if (aa < 0 || aa > 31) continue;
    for (int dx=0; dx<3; ++dx){
      int bb = b+dx-1; if (bb < 0 || bb > 31) continue;
      acc += W[O_E2 + c*1024 + aa*32 + bb] * W[I_DW2W + c*9 + dy*3 + dx];
    }
  }
  W[O_E3 + i] = acc;
}

__global__ void k_pw2(float* __restrict__ W){
  int i = blockIdx.x*256 + threadIdx.x; if (i >= 128*1024) return;
  int o = i >> 10, pix = i & 1023;
  float acc = W[I_PW2B + o];
  for (int c=0; c<64; ++c) acc += W[I_PW2W + o*64 + c] * W[O_E3 + c*1024 + pix];
  W[O_E4 + i] = acc;
}

DEV void rs_coef(int o, int n, int& i0, int& i1, float& w0, float& w1){
  float src = 0.5f*(float)o - 0.25f;
  float f = floorf(src);
  float fr = src - f;
  int a = (int)f;
  if (a < 0){ i0 = 0; i1 = 0; w0 = 0.f; w1 = 1.f; }
  else if (a >= n-1){ i0 = n-1; i1 = n-1; w0 = 1.f; w1 = 0.f; }
  else { i0 = a; i1 = a+1; w0 = 1.f-fr; w1 = fr; }
}

__global__ void k_resize(float* __restrict__ W){
  int i = blockIdx.x*256 + threadIdx.x; if (i >= 128*4096) return;
  int c = i >> 12, pix = i & 4095, y = pix >> 6, x = pix & 63;
  int iy0, iy1, ix0, ix1; float wy0, wy1, wx0, wx1;
  rs_coef(y, 32, iy0, iy1, wy0, wy1);
  rs_coef(x, 32, ix0, ix1, wx0, wx1);
  const float* in = W + O_E4 + c*1024;
  float v = wy0*(wx0*in[iy0*32+ix0] + wx1*in[iy0*32+ix1])
          + wy1*(wx0*in[iy1*32+ix0] + wx1*in[iy1*32+ix1]);
  W[O_E5 + i] = v;
}

__global__ void k_cv1(float* __restrict__ W){
  int og = blockIdx.x >> 4, pt = blockIdx.x & 15;
  int pix = pt*256 + threadIdx.x;
  int y = pix >> 6, x = pix & 63;
  float acc[4];
  #pragma unroll
  for (int q=0; q<4; ++q) acc[q] = W[I_CV1B + og*4 + q];
  for (int i2=0; i2<128; ++i2){
    const float* in = W + O_E5 + i2*4096;
    for (int dy=0; dy<3; ++dy){
      int yy = y+dy-1; if (yy < 0 || yy > 63) continue;
      for (int dx=0; dx<3; ++dx){
        int xx = x+dx-1; if (xx < 0 || xx > 63) continue;
        float v = in[yy*64+xx];
        #pragma unroll
        for (int q=0; q<4; ++q)
          acc[q] += v * W[I_CV1W + ((long long)(og*4+q)*128 + i2)*9 + dy*3 + dx];
      }
    }
  }
  #pragma unroll
  for (int q=0; q<4; ++q) W[O_E6 + (long long)(og*4+q)*4096 + pix] = acc[q];
}

__global__ void k_cv2(float* __restrict__ W){
  int i = blockIdx.x*256 + threadIdx.x; if (i >= 256*4096) return;
  int o = i >> 12, pix = i & 4095;
  float acc = W[I_CV2B + o];
  for (int c=0; c<128; ++c) acc += W[I_CV2W + o*128 + c] * W[O_E6 + c*4096 + pix];
  W[O_E7 + i] = acc;
}

__global__ void k_fc(float* __restrict__ W){
  int og = blockIdx.x >> 4, pt = blockIdx.x & 15;
  int pix = pt*256 + threadIdx.x;
  int y = pix >> 6, x = pix & 63;
  float acc[4];
  #pragma unroll
  for (int q=0; q<4; ++q) acc[q] = W[I_FCB + og*4 + q];
  for (int i2=0; i2<256; ++i2){
    const float* in = W + O_E7 + i2*4096;
    for (int dy=0; dy<3; ++dy){
      int yy = y+dy-1; if (yy < 0 || yy > 63) continue;
      for (int dx=0; dx<3; ++dx){
        int xx = x+dx-1; if (xx < 0 || xx > 63) continue;
        float v = in[yy*64+xx];
        #pragma unroll
        for (int q=0; q<4; ++q)
          acc[q] += v * W[I_FCW + ((long long)(og*4+q)*256 + i2)*9 + dy*3 + dx];
      }
    }
  }
  #pragma unroll
  for (int q=0; q<4; ++q) W[O_E8 + (long long)(og*4+q)*4096 + pix] = acc[q];
}

// =============== stage F: vssblock2 ===============
__global__ void k_ln2(float* __restrict__ W){
  int l = blockIdx.x, t = threadIdx.x;
  float v0 = W[O_E8 + (long long)t*4096 + l];
  float v1 = W[O_E8 + (long long)(t+256)*4096 + l];
  float s = v0+v1, s2 = v0*v0 + v1*v1;
  for (int off=32; off; off>>=1){ s += __shfl_xor(s, off, 64); s2 += __shfl_xor(s2, off, 64); }
  __shared__ float a[4], b[4];
  if ((t & 63) == 0){ a[t>>6] = s; b[t>>6] = s2; }
  __syncthreads();
  float S = a[0]+a[1]+a[2]+a[3], S2 = b[0]+b[1]+b[2]+b[3];
  float mu = S/512.f, var = S2/512.f - mu*mu, rs = rsqrtf(var + 1e-5f);
  W[O_LN2 + (long long)l*512 + t]     = (v0-mu)*rs*W[I_V2LNW + t]     + W[I_V2LNB + t];
  W[O_LN2 + (long long)l*512 + t+256] = (v1-mu)*rs*W[I_V2LNW + t+256] + W[I_V2LNB + t+256];
}

__global__ void k_xz2(float* __restrict__ W){
  int l = blockIdx.x*64 + (threadIdx.x & 63);
  int jbase = blockIdx.y*32 + (threadIdx.x >> 6)*8;
  float acc[8];
  #pragma unroll
  for (int q=0; q<8; ++q) acc[q] = 0.f;
  const float* h = W + O_LN2 + (long long)l*512;
  const float* wgt = W + I_V2INW;
  for (int d=0; d<512; ++d){
    float hv = h[d];
    #pragma unroll
    for (int q=0; q<8; ++q) acc[q] += hv * wgt[(long long)(jbase+q)*512 + d];
  }
  #pragma unroll
  for (int q=0; q<8; ++q) W[O_XZ2 + (long long)l*2048 + jbase + q] = acc[q];
}

__global__ void k_dwcs2(float* __restrict__ W){
  long long i = (long long)blockIdx.x*256 + threadIdx.x;
  int ch = (int)(i >> 12), pix = (int)(i & 4095), a = pix >> 6, b = pix & 63;
  float acc = W[I_V2CONVB + ch];
  const float* xp = W + O_XT2 + (long long)ch*4096;
  for (int dy=0; dy<3; ++dy){
    int aa = a+dy-1; if (aa < 0 || aa > 63) continue;
    for (int dx=0; dx<3; ++dx){
      int bb = b+dx-1; if (bb < 0 || bb > 63) continue;
      acc += xp[aa*64+bb] * W[I_V2CONVW + ch*9 + dy*3 + dx];
    }
  }
  W[O_XC2 + i] = siluf(acc);
}

__global__ void k_dbl2(float* __restrict__ W){
  int bx = blockIdx.x;
  int k = bx >> 6, cg = (bx >> 4) & 3, lt = bx & 15;
  int l = lt*256 + threadIdx.x;
  float acc[16];
  #pragma unroll
  for (int q=0; q<16; ++q) acc[q] = 0.f;
  int ua = scan_addr(k, l, 6, 4095);
  for (int d=0; d<1024; ++d){
    float v = W[O_XC2 + (long long)d*4096 + ua];
    #pragma unroll
    for (int q=0; q<16; ++q)
      acc[q] += v * W[I_V2XPW + (long long)(k*64 + cg*16 + q)*1024 + d];
  }
  #pragma unroll
  for (int q=0; q<16; ++q) W[O_DBL2 + (long long)(k*64 + cg*16 + q)*4096 + l] = acc[q];
}

__global__ void k_comb2(float* __restrict__ W){
  int l = blockIdx.x, t = threadIdx.x;
  int t1 = ((l & 63) << 6) | (l >> 6);
  const __half* Y = (const __half*)(W + O_YS2);
  float v[4]; float s = 0.f, s2 = 0.f;
  for (int q=0; q<4; ++q){
    int dch = t + q*256;
    float x = __half2float(Y[(long long)l*4096 + dch])
            + __half2float(Y[(long long)t1*4096 + 1024 + dch])
            + __half2float(Y[(long long)(4095-l)*4096 + 2048 + dch])
            + __half2float(Y[(long long)(4095-t1)*4096 + 3072 + dch]);
    v[q] = x; s += x; s2 += x*x;
  }
  for (int off=32; off; off>>=1){ s += __shfl_xor(s, off, 64); s2 += __shfl_xor(s2, off, 64); }
  __shared__ float a[4], b[4];
  if ((t & 63) == 0){ a[t>>6] = s; b[t>>6] = s2; }
  __syncthreads();
  float S = a[0]+a[1]+a[2]+a[3], S2 = b[0]+b[1]+b[2]+b[3];
  float mu = S/1024.f, var = S2/1024.f - mu*mu, rs = rsqrtf(var + 1e-5f);
  for (int q=0; q<4; ++q){
    int dch = t + q*256;
    float yn = (v[q]-mu)*rs*W[I_V2ONW + dch] + W[I_V2ONB + dch];
    float z = W[O_XZ2 + (long long)l*2048 + 1024 + dch];
    W[O_G2 + (long long)l*1024 + dch] = yn * siluf(z);
  }
}

__global__ void k_oproj2(float* __restrict__ W, const unsigned int* flagp, void* dout){
  int cg = blockIdx.x >> 4, lt = blockIdx.x & 15;
  int l = lt*256 + threadIdx.x;
  float acc[8];
  #pragma unroll
  for (int q=0; q<8; ++q) acc[q] = 0.f;
  const float* g = W + O_G2 + (long long)l*1024;
  for (int d=0; d<1024; ++d){
    float gv = g[d];
    #pragma unroll
    for (int q=0; q<8; ++q) acc[q] += gv * W[I_V2OUTW + (long long)(cg*8+q)*1024 + d];
  }
  bool bf = (*flagp) == 0x3F803F80u;
  #pragma unroll
  for (int q=0; q<8; ++q){
    int c = cg*8 + q;
    long long o = (long long)c*4096 + l;
    float v = W[O_E8 + o] + acc[q];
    if (bf) ((unsigned short*)dout)[o] = f2bf(v);
    else    ((float*)dout)[o] = v;
  }
}

// =============== launch ===============
extern "C" void kernel_launch(void* const* d_in, const int* in_sizes, int n_in,
                              void* d_out, int out_size, void* d_ws, size_t ws_size,
                              hipStream_t stream){
  if (ws_size < (size_t)WS_FLOATS * sizeof(float)) return;
  float* W = (float*)d_ws;
  PtrTab tab;
  for (int i=0; i<53; ++i) tab.p[i] = d_in[i];

  k_ingest<<<INGEST_BLOCKS, 256, 0, stream>>>(tab, W);
  k_c0    <<<64, 256, 0, stream>>>(W);
  k_zx    <<<290, 256, 0, stream>>>(W);
  k_conv4 <<<160, 256, 0, stream>>>(W);
  k_dtm   <<<2, 256, 0, stream>>>(W);
  k_mscan <<<1024, 64, 0, stream>>>(W);
  k_gaterms<<<32, 256, 0, stream>>>(W);
  k_outm  <<<64, 256, 0, stream>>>(W);
  k_c1    <<<128, 256, 0, stream>>>(W);
  k_ln1   <<<4, 256, 0, stream>>>(W);
  k_xz1   <<<512, 256, 0, stream>>>(W);
  k_dwcs1 <<<256, 256, 0, stream>>>(W);
  k_dbl1  <<<544, 256, 0, stream>>>(W);
  // vss1 chunked scan
  k_transpose<<<dim3(32, 2), 256, 0, stream>>>(W + O_XC1, W + O_XT1, 64, 1024, 1024, 64);
  k_scan_p1<64,64,1024,5,64,2,34><<<dim3(4,16), 64, 0, stream>>>(W, O_DBL1, O_XT1, O_P1, O_S1,
                                                                 I_V1DTW, I_V1DTB, I_V1ALOG);
  k_carry<4096,16><<<16, 256, 0, stream>>>(W, O_P1, O_S1);
  k_scan_p3<64,64,1024,5,64,2,34><<<dim3(4,16), 64, 0, stream>>>(W, O_DBL1, O_XT1, O_S1, O_YS1,
                                                                 I_V1DTW, I_V1DTB, I_V1ALOG, I_V1D);
  k_comb1 <<<1024, 64, 0, stream>>>(W);
  k_oproj1<<<128, 256, 0, stream>>>(W);
  k_dw1   <<<128, 256, 0, stream>>>(W);
  k_pw1   <<<256, 256, 0, stream>>>(W);
  k_dw2   <<<256, 256, 0, stream>>>(W);
  k_pw2   <<<512, 256, 0, stream>>>(W);
  k_resize<<<2048, 256, 0, stream>>>(W);
  k_cv1   <<<512, 256, 0, stream>>>(W);
  k_cv2   <<<4096, 256, 0, stream>>>(W);
  k_fc    <<<2048, 256, 0, stream>>>(W);
  // vss2
  k_ln2   <<<4096, 256, 0, stream>>>(W);
  k_xz2   <<<dim3(64, 64), 256, 0, stream>>>(W);
  k_transpose<<<dim3(32, 128), 256, 0, stream>>>(W + O_XZ2, W + O_XT2, 4096, 1024, 2048, 4096); // XP[ch][pix]
  k_dwcs2 <<<16384, 256, 0, stream>>>(W);
  k_dbl2  <<<256, 256, 0, stream>>>(W);
  k_transpose<<<dim3(128, 32), 256, 0, stream>>>(W + O_XC2, W + O_XT2, 1024, 4096, 4096, 1024); // XT[pix][ch]
  k_scan_p1<1024,256,4096,6,64,32,64><<<dim3(16,64), 256, 0, stream>>>(W, O_DBL2, O_XT2, O_P2, O_S2,
                                                                       I_V2DTW, I_V2DTB, I_V2ALOG);
  k_carry<65536,64><<<256, 256, 0, stream>>>(W, O_P2, O_S2);
  k_scan_p3<1024,256,4096,6,64,32,64><<<dim3(16,64), 256, 0, stream>>>(W, O_DBL2, O_XT2, O_S2, O_YS2,
                                                                       I_V2DTW, I_V2DTB, I_V2ALOG, I_V2D);
  k_comb2 <<<4096, 256, 0, stream>>>(W);
  k_oproj2<<<1024, 256, 0, stream>>>(W, (const unsigned int*)d_in[9], d_out);
}

// Round 6
// 1438.202 us; speedup vs baseline: 4.7944x; 1.9320x over previous
//
#include <hip/hip_runtime.h>
#include <hip/hip_bf16.h>
#include <hip/hip_fp16.h>
#include <math.h>

#define DEV static __device__ __forceinline__

DEV float siluf(float x){ return x / (1.f + expf(-x)); }
DEV float softplusf(float x){ return (x > 20.f) ? x : log1pf(__expf(x)); }

DEV unsigned short f2bf(float f){
  unsigned int u = __float_as_uint(f);
  unsigned int r = (u + 0x7FFFu + ((u >> 16) & 1u)) >> 16;
  return (unsigned short)r;
}

using bf16x8 = __attribute__((ext_vector_type(8))) short;
using u16x8  = __attribute__((ext_vector_type(8))) unsigned short;
using f32x4  = __attribute__((ext_vector_type(4))) float;

// ---------------- input arena offsets (floats) ----------------
constexpr long long I_LD=0, I_C0W=9216, I_C0B=10944, I_MINW=10976, I_MCONVW=1198816,
 I_MCONVB=1203936, I_MDTB=1205216, I_MALOG=1205232, I_MD=1205248, I_MNORMW=1205264,
 I_MOUTW=1206288, I_C1W=1730576, I_C1B=3303440, I_V1LNW=3304464, I_V1LNB=3304496,
 I_V1INW=3304528, I_V1CONVW=3308624, I_V1CONVB=3309200, I_V1XPW=3309264, I_V1DTW=3317968,
 I_V1DTB=3318480, I_V1ALOG=3318736, I_V1D=3322832, I_V1ONW=3323088, I_V1ONB=3323152,
 I_V1OUTW=3323216, I_DW1W=3325264, I_DW1B=3325552, I_PW1W=3325584, I_PW1B=3327632,
 I_DW2W=3327696, I_DW2B=3328272, I_PW2W=3328336, I_PW2B=3336528, I_CV1W=3336656,
 I_CV1B=3484112, I_CV2W=3484240, I_CV2B=3517008, I_FCW=3517264, I_FCB=4696912,
 I_V2LNW=4697424, I_V2LNB=4697936, I_V2INW=4698448, I_V2CONVW=5747024, I_V2CONVB=5756240,
 I_V2XPW=5757264, I_V2DTW=6019408, I_V2DTB=6150480, I_V2ALOG=6154576, I_V2D=6220112,
 I_V2ONW=6224208, I_V2ONB=6225232, I_V2OUTW=6226256;
constexpr long long TOTAL_IN = 6750544;
constexpr int INGEST_BLOCKS = (int)((TOTAL_IN + 255) / 256);
constexpr long long O_E8 = 6750544;                // (512,4096) f32, lives to the end
constexpr long long SCR  = 8847696;
// phase 1 (stages A-E)
constexpr long long O_X0=SCR+0, O_ZX=SCR+16384, O_XBCC=SCR+90624, O_DTM=SCR+131584,
 O_TPRE=SCR+132096, O_TG=SCR+164864, O_OUTM=SCR+197632, O_Y1=SCR+214016, O_H1=SCR+246784,
 O_XZ1=SCR+279552, O_XC1=SCR+410624, O_DBL1=SCR+476160, O_YS1=SCR+615424, O_G1=SCR+877568,
 O_OUTD=SCR+943104, O_E1=SCR+975872, O_E2=SCR+1008640, O_E3=SCR+1074176, O_E4=SCR+1139712,
 O_E5=SCR+1270784, O_E6=SCR+1795072, O_E7=SCR+2319360;
// vss1 scan scratch
constexpr long long O_XT1=SCR+3367936, O_P1=SCR+3433472, O_S1=SCR+3499008;
// fc MFMA scratch (phase-1 tail; dead before XZ2 is written)
constexpr long long O_FCW2=SCR+4000000;   // 512x2304 bf16 (589824 slots, ends 4589824)
constexpr long long O_E7T =SCR+4600000;   // 4096x256 bf16 (524288 slots, ends 5124288)
constexpr long long O_B2  =SCR+5242880;   // 4096x2304 bf16 (4718592 slots, ends 9961472)
// phase 2 (stage F)
constexpr long long O_XZ2=SCR+0;                        // 4096x2048 f32 (ends 8388608)
constexpr long long O_XC2=SCR+8388608;                  // 1024x4096 f32 (dead after dual transpose)
constexpr long long O_P2 =O_XC2;                        // overlay: P written in scan pass 1 (ends 12582912)
constexpr long long O_XT2=SCR+12582912;                 // XP[ch][pix] f32, then XT[pix][ch] f32
constexpr long long O_G2 =O_XT2;                        // overlay: bf16 G2 (comb2 out, XT2 dead)
constexpr long long O_DBL2=SCR+16777216;                // G[256][4096] f32 (ends 17825792)
constexpr long long O_S2 =SCR+17825792;                 // (ends 22020096)
constexpr long long O_YS2=SCR+22020096;                 // fp16 ys (ends 30408704)
constexpr long long O_LN2=SCR+30408704;                 // bf16 LN2 (524288 slots, ends 31457280)
// bf16 weights / staging (top region) — R5 bug: W2INB overlapped XPWB/OUTWB; repacked:
constexpr long long O_W2INB=SCR+32505856;               // 2048x512 bf16 = 524288 slots, ends 33030144
constexpr long long O_XPWB =SCR+33030144;               // 256x1024 bf16 = 131072 slots, ends 33161216
constexpr long long O_OUTWB=SCR+33161216;               // 512x1024 bf16 = 262144 slots, ends 33423360
constexpr long long O_XT2B =SCR+33423360;               // 4096x1024 bf16 = 2097152 slots, ends 35520512
constexpr long long WS_FLOATS = SCR + 36700160;

struct PtrTab { const void* p[53]; };

__constant__ long long c_inoff[53] = { 0, 9216, 10944, 10976, 1198816, 1203936, 1205216,
 1205232, 1205248, 1205264, 1206288, 1730576, 3303440, 3304464, 3304496, 3304528, 3308624,
 3309200, 3309264, 3317968, 3318480, 3318736, 3322832, 3323088, 3323152, 3323216, 3325264,
 3325552, 3325584, 3327632, 3327696, 3328272, 3328336, 3336528, 3336656, 3484112, 3484240,
 3517008, 3517264, 4696912, 4697424, 4697936, 4698448, 5747024, 5756240, 5757264, 6019408,
 6150480, 6154576, 6220112, 6224208, 6225232, 6226256 };

DEV int scan_addr(int k, int l, int lg, int Lm1){
  int p = (k & 2) ? (Lm1 - l) : l;
  int mask = (1 << lg) - 1;
  if (k & 1) p = ((p & mask) << lg) | (p >> lg);
  return p;
}

// =============== ingest ===============
__global__ void k_ingest(PtrTab t, float* __restrict__ W){
  long long idx = (long long)blockIdx.x*256 + threadIdx.x;
  if (idx >= TOTAL_IN) return;
  int j = 0;
  #pragma unroll
  for (int q=1; q<53; ++q) if (idx >= c_inoff[q]) j = q;
  int local = (int)(idx - c_inoff[j]);
  bool bf = (*(const unsigned int*)t.p[9]) == 0x3F803F80u;
  float v;
  if (bf){
    unsigned short u = ((const unsigned short*)t.p[j])[local];
    v = __uint_as_float(((unsigned int)u) << 16);
  } else {
    v = ((const float*)t.p[j])[local];
  }
  W[idx] = v;
}

// =============== converts ===============
__global__ void k_tobf16(const float* __restrict__ src, unsigned short* __restrict__ dst, int n){
  int i = blockIdx.x*256 + threadIdx.x;
  if (i < n) dst[i] = f2bf(src[i]);
}

// FCW (512,256,3,3) -> A2[c][tap*256+i2] bf16
__global__ void k_fcw2(const float* __restrict__ W, unsigned short* __restrict__ dst){
  int i = blockIdx.x*256 + threadIdx.x;
  if (i >= 512*2304) return;
  int c = i / 2304, r = i % 2304, tap = r >> 8, i2 = r & 255;
  dst[i] = f2bf(W[I_FCW + ((long long)(c*256 + i2))*9 + tap]);
}

// =============== transposes ===============
__global__ void k_transpose(const float* __restrict__ in, float* __restrict__ out,
                            int rows, int cols, long long instride, long long outstride){
  __shared__ float tile[32][33];
  int tx = threadIdx.x & 31, ty = threadIdx.x >> 5;
  long long c0 = (long long)blockIdx.x*32, r0 = (long long)blockIdx.y*32;
  #pragma unroll
  for (int i=0;i<32;i+=8){
    long long r = r0 + ty + i, c = c0 + tx;
    if (r < rows && c < cols) tile[ty+i][tx] = in[r*instride + c];
  }
  __syncthreads();
  #pragma unroll
  for (int i=0;i<32;i+=8){
    long long r = r0 + tx, c = c0 + ty + i;
    if (r < rows && c < cols) out[c*outstride + r] = tile[tx][ty+i];
  }
}

// transpose with optional f32 + bf16 outputs
__global__ void k_transpose_dual(const float* __restrict__ in, float* __restrict__ outF,
                                 unsigned short* __restrict__ outB,
                                 int rows, int cols, long long instride, long long outstride){
  __shared__ float tile[32][33];
  int tx = threadIdx.x & 31, ty = threadIdx.x >> 5;
  long long c0 = (long long)blockIdx.x*32, r0 = (long long)blockIdx.y*32;
  #pragma unroll
  for (int i=0;i<32;i+=8){
    long long r = r0 + ty + i, c = c0 + tx;
    if (r < rows && c < cols) tile[ty+i][tx] = in[r*instride + c];
  }
  __syncthreads();
  #pragma unroll
  for (int i=0;i<32;i+=8){
    long long r = r0 + tx, c = c0 + ty + i;
    if (r < rows && c < cols){
      float v = tile[tx][ty+i];
      if (outF) outF[c*outstride + r] = v;
      outB[c*outstride + r] = f2bf(v);
    }
  }
}

// =============== bf16 MFMA GEMM: C[m][n] = sum_k A[m][k]*B[n][k] ===============
// A: M x K bf16 row-major, B: N x K bf16 row-major. M,N mult of 128; K mult of 64.
// MODE 0: Cout[m*N+n] = v    MODE 1: v += bias[m], store Cout
// MODE 2: v += res[m*N+n]; store to dout (bf16 if flag else f32)
template<int MODE>
__global__ __launch_bounds__(256)
void k_gemm_bt(const unsigned short* __restrict__ A, const unsigned short* __restrict__ B,
               int K, int N, float* __restrict__ Cout, const float* __restrict__ bias,
               const float* __restrict__ res, const unsigned int* flagp, void* dout){
  constexpr int LDK = 72;  // 64 + 8 pad
  __shared__ unsigned short As[128*LDK], Bs[128*LDK];
  int m0 = blockIdx.x*128, n0 = blockIdx.y*128;
  int tid = threadIdx.x;
  int wave = tid >> 6, lane = tid & 63, quad = lane >> 4, l16 = lane & 15;
  int wm = wave >> 1, wn = wave & 1;
  f32x4 acc[4][4];
  #pragma unroll
  for (int a=0;a<4;++a)
    #pragma unroll
    for (int b=0;b<4;++b) acc[a][b] = (f32x4){0.f,0.f,0.f,0.f};
  int srow = tid >> 1, shalf = (tid & 1)*32;
  for (int kt = 0; kt < K; kt += 64){
    const u16x8* ga = (const u16x8*)(A + (long long)(m0+srow)*K + kt + shalf);
    const u16x8* gb = (const u16x8*)(B + (long long)(n0+srow)*K + kt + shalf);
    u16x8* da = (u16x8*)&As[srow*LDK + shalf];
    u16x8* db = (u16x8*)&Bs[srow*LDK + shalf];
    #pragma unroll
    for (int c=0;c<4;++c){ da[c] = ga[c]; db[c] = gb[c]; }
    __syncthreads();
    #pragma unroll
    for (int ks=0; ks<64; ks+=32){
      bf16x8 af[4], bfr[4];
      #pragma unroll
      for (int mi=0;mi<4;++mi)
        af[mi] = *(const bf16x8*)&As[(wm*64 + mi*16 + l16)*LDK + ks + quad*8];
      #pragma unroll
      for (int ni=0;ni<4;++ni)
        bfr[ni] = *(const bf16x8*)&Bs[(wn*64 + ni*16 + l16)*LDK + ks + quad*8];
      #pragma unroll
      for (int mi=0;mi<4;++mi)
        #pragma unroll
        for (int ni=0;ni<4;++ni)
          acc[mi][ni] = __builtin_amdgcn_mfma_f32_16x16x32_bf16(af[mi], bfr[ni], acc[mi][ni], 0, 0, 0);
    }
    __syncthreads();
  }
  bool bf = (MODE == 2) ? ((*flagp) == 0x3F803F80u) : false;
  #pragma unroll
  for (int mi=0;mi<4;++mi){
    #pragma unroll
    for (int ni=0;ni<4;++ni){
      #pragma unroll
      for (int r=0;r<4;++r){
        int m = m0 + wm*64 + mi*16 + quad*4 + r;
        int n = n0 + wn*64 + ni*16 + l16;
        float v = acc[mi][ni][r];
        if (MODE == 1) v += bias[m];
        if (MODE == 2){
          v += res[(long long)m*N + n];
          if (bf) ((unsigned short*)dout)[(long long)m*N + n] = f2bf(v);
          else    ((float*)dout)[(long long)m*N + n] = v;
        } else {
          Cout[(long long)m*N + n] = v;
        }
      }
    }
  }
}

// =============== chunked selective-scan (3 passes) ===============
// GATHER=true: dbl rows are stored in PIXEL order; stage via scan_addr gather.
template<int DCH, int TD, int L, int LG, int T, int R, int CROWS, bool GATHER>
__global__ void k_scan_p1(float* __restrict__ W, long long o_dbl, long long o_xt,
                          long long o_p, long long o_s,
                          long long i_dtw, long long i_dtb, long long i_alog){
  constexpr int NT = DCH/TD;
  int k = blockIdx.x / NT, tile = blockIdx.x % NT;
  int c = blockIdx.y;
  int t = threadIdx.x;
  int dch = tile*TD + t;
  __shared__ float lds[CROWS*T];
  const float* dbl = W + o_dbl + (long long)k*CROWS*L;
  const int Lm1 = L-1, mask = (1<<LG)-1;
  for (int idx = t; idx < CROWS*T; idx += TD){
    int row = idx / T, col = idx % T;
    int l = c*T + col;
    int cc = GATHER ? scan_addr(k, l, LG, Lm1) : l;
    lds[idx] = dbl[(long long)row*L + cc];
  }
  __syncthreads();
  float w[R], A[16], p[16], s[16];
  #pragma unroll
  for (int r=0;r<R;++r) w[r] = W[i_dtw + (long long)(k*DCH+dch)*R + r];
  float bias = W[i_dtb + k*DCH + dch];
  #pragma unroll
  for (int n=0;n<16;++n){
    A[n] = -expf(W[i_alog + (long long)(k*DCH+dch)*16 + n]);
    p[n] = 1.f; s[n] = 0.f;
  }
  const float* XT = W + o_xt;
  for (int j=0;j<T;++j){
    int l = c*T + j;
    int p_ = (k&2)? (Lm1-l) : l;
    int ua = (k&1)? (((p_&mask)<<LG)|(p_>>LG)) : p_;
    float u = XT[(long long)ua*DCH + dch];
    float dt = bias;
    #pragma unroll
    for (int r=0;r<R;++r) dt += lds[r*T+j]*w[r];
    dt = softplusf(dt);
    float du = dt*u;
    #pragma unroll
    for (int n=0;n<16;++n){
      float dA = __expf(dt*A[n]);
      float B = lds[(R+n)*T + j];
      p[n] *= dA;
      s[n] = s[n]*dA + du*B;
    }
  }
  float* P = W + o_p; float* S = W + o_s;
  long long base = (long long)c*(4LL*DCH*16) + (long long)k*DCH*16 + (long long)dch*16;
  #pragma unroll
  for (int n=0;n<16;++n){ P[base+n] = p[n]; S[base+n] = s[n]; }
}

template<int NSTATE, int CH>
__global__ void k_carry(float* __restrict__ W, long long o_p, long long o_s){
  int idx = blockIdx.x*256 + threadIdx.x;
  if (idx >= NSTATE) return;
  const float* P = W + o_p; float* S = W + o_s;
  float h = 0.f;
  for (int c=0;c<CH;++c){
    float p = P[(long long)c*NSTATE + idx];
    float s = S[(long long)c*NSTATE + idx];
    S[(long long)c*NSTATE + idx] = h;
    h = h*p + s;
  }
}

template<int DCH, int TD, int L, int LG, int T, int R, int CROWS, bool GATHER>
__global__ void k_scan_p3(float* __restrict__ W, long long o_dbl, long long o_xt,
                          long long o_s, long long o_ys,
                          long long i_dtw, long long i_dtb, long long i_alog, long long i_dd){
  constexpr int NT = DCH/TD;
  int k = blockIdx.x / NT, tile = blockIdx.x % NT;
  int c = blockIdx.y;
  int t = threadIdx.x;
  int dch = tile*TD + t;
  __shared__ float lds[CROWS*T];
  const float* dbl = W + o_dbl + (long long)k*CROWS*L;
  const int Lm1 = L-1, mask = (1<<LG)-1;
  for (int idx = t; idx < CROWS*T; idx += TD){
    int row = idx / T, col = idx % T;
    int l = c*T + col;
    int cc = GATHER ? scan_addr(k, l, LG, Lm1) : l;
    lds[idx] = dbl[(long long)row*L + cc];
  }
  __syncthreads();
  float w[R], A[16], s[16];
  #pragma unroll
  for (int r=0;r<R;++r) w[r] = W[i_dtw + (long long)(k*DCH+dch)*R + r];
  float bias = W[i_dtb + k*DCH + dch];
  float Dv = W[i_dd + k*DCH + dch];
  long long sbase = (long long)c*(4LL*DCH*16) + (long long)k*DCH*16 + (long long)dch*16;
  #pragma unroll
  for (int n=0;n<16;++n){
    A[n] = -expf(W[i_alog + (long long)(k*DCH+dch)*16 + n]);
    s[n] = W[o_s + sbase + n];
  }
  const float* XT = W + o_xt;
  __half* Y = (__half*)(W + o_ys);
  for (int j=0;j<T;++j){
    int l = c*T + j;
    int p_ = (k&2)? (Lm1-l) : l;
    int ua = (k&1)? (((p_&mask)<<LG)|(p_>>LG)) : p_;
    float u = XT[(long long)ua*DCH + dch];
    float dt = bias;
    #pragma unroll
    for (int r=0;r<R;++r) dt += lds[r*T+j]*w[r];
    dt = softplusf(dt);
    float du = dt*u;
    float y = Dv*u;
    #pragma unroll
    for (int n=0;n<16;++n){
      float dA = __expf(dt*A[n]);
      float B = lds[(R+n)*T + j];
      float C = lds[(R+16+n)*T + j];
      s[n] = s[n]*dA + du*B;
      y += s[n]*C;
    }
    Y[(long long)l*(4*DCH) + k*DCH + dch] = __float2half(y);
  }
}

// =============== stage A: c0 ===============
__global__ void k_c0(float* __restrict__ W){
  int i = blockIdx.x*256 + threadIdx.x; if (i >= 32*512) return;
  int c = i >> 9, l = i & 511;
  float acc = W[I_C0B + c];
  for (int ii=0; ii<18; ++ii)
    for (int j=0; j<3; ++j){
      int p = l-1+j;
      if (p >= 0 && p < 512) acc += W[I_LD + ii*512 + p] * W[I_C0W + (c*18+ii)*3 + j];
    }
  W[O_X0 + i] = acc;
}

// =============== stage B: mamba2 ===============
__global__ void k_zx(float* __restrict__ W){
  int i = blockIdx.x*256 + threadIdx.x; if (i >= 32*2320) return;
  int l = i / 2320, j = i % 2320;
  float acc = 0.f;
  const float* u = W + O_X0 + l*512;
  const float* wr = W + I_MINW + (long long)j*512;
  for (int d=0; d<512; ++d) acc += u[d]*wr[d];
  W[O_ZX + i] = acc;
}

__global__ void k_conv4(float* __restrict__ W){
  int i = blockIdx.x*256 + threadIdx.x; if (i >= 32*1280) return;
  int l = i / 1280, c = i % 1280;
  float acc = W[I_MCONVB + c];
  for (int j=0; j<4; ++j){
    int p = l-3+j;
    if (p >= 0) acc += W[O_ZX + p*2320 + 1024 + c] * W[I_MCONVW + c*4 + j];
  }
  W[O_XBCC + l*1280 + c] = siluf(acc);
}

__global__ void k_dtm(float* __restrict__ W){
  int i = blockIdx.x*256 + threadIdx.x; if (i >= 512) return;
  int l = i >> 4, h = i & 15;
  W[O_DTM + i] = softplusf(W[O_ZX + l*2320 + 2304 + h] + W[I_MDTB + h]);
}

__global__ void k_mscan(float* __restrict__ W){
  int h = blockIdx.x >> 6, pp = blockIdx.x & 63;
  int lane = threadIdx.x;
  float A = -expf(W[I_MALOG + h]);
  float Dv = W[I_MD + h];
  float s0 = 0.f, s1 = 0.f;
  for (int l=0; l<32; ++l){
    float dt = W[O_DTM + l*16 + h];
    float xv = W[O_XBCC + l*1280 + h*64 + pp];
    float dA = expf(dt*A);
    float b0 = W[O_XBCC + l*1280 + 1024 + lane];
    float b1 = W[O_XBCC + l*1280 + 1088 + lane];
    float c0 = W[O_XBCC + l*1280 + 1152 + lane];
    float c1 = W[O_XBCC + l*1280 + 1216 + lane];
    float du = dt*xv;
    s0 = s0*dA + du*b0;
    s1 = s1*dA + du*b1;
    float part = s0*c0 + s1*c1;
    for (int off=32; off; off>>=1) part += __shfl_xor(part, off, 64);
    if (lane == 0) W[O_TPRE + l*1024 + h*64 + pp] = part + Dv*xv;
  }
}

__global__ void k_gaterms(float* __restrict__ W){
  int l = blockIdx.x, t = threadIdx.x;
  float vals[4]; float ss = 0.f;
  for (int q=0; q<4; ++q){
    int c = t + q*256;
    float z = W[O_ZX + l*2320 + c];
    float y = W[O_TPRE + l*1024 + c];
    float v = y * siluf(z);
    vals[q] = v; ss += v*v;
  }
  for (int off=32; off; off>>=1) ss += __shfl_xor(ss, off, 64);
  __shared__ float sm[4];
  if ((t & 63) == 0) sm[t>>6] = ss;
  __syncthreads();
  float tot = sm[0]+sm[1]+sm[2]+sm[3];
  float r = rsqrtf(tot/1024.f + 1e-5f);
  for (int q=0; q<4; ++q){
    int c = t + q*256;
    W[O_TG + l*1024 + c] = vals[q]*r*W[I_MNORMW + c];
  }
}

__global__ void k_outm(float* __restrict__ W){
  int i = blockIdx.x*256 + threadIdx.x; if (i >= 32*512) return;
  int l = i >> 9, d = i & 511;
  float acc = 0.f;
  const float* tg = W + O_TG + l*1024;
  const float* wr = W + I_MOUTW + (long long)d*1024;
  for (int c=0; c<1024; ++c) acc += tg[c]*wr[c];
  W[O_OUTM + i] = acc;
}

// =============== stage C: c1 ===============
__global__ void k_c1(float* __restrict__ W){
  int i = blockIdx.x*256 + threadIdx.x; if (i >= 1024*32) return;
  int o = i >> 5, l = i & 31;
  float acc = W[I_C1B + o];
  for (int ii=0; ii<512; ++ii)
    for (int j=0; j<3; ++j){
      int p = l-1+j;
      if (p >= 0 && p < 32) acc += W[O_OUTM + p*512 + ii] * W[I_C1W + ((long long)o*512+ii)*3 + j];
    }
  W[O_Y1 + o*32 + l] = acc;
}

// =============== vssblock 1 ===============
__global__ void k_ln1(float* __restrict__ W){
  int l = blockIdx.x*256 + threadIdx.x; if (l >= 1024) return;
  float s = 0.f, s2 = 0.f;
  for (int c=0; c<32; ++c){ float v = W[O_Y1 + l*32 + c]; s += v; s2 += v*v; }
  float mu = s/32.f, var = s2/32.f - mu*mu, rs = rsqrtf(var + 1e-5f);
  for (int c=0; c<32; ++c){
    float v = W[O_Y1 + l*32 + c];
    W[O_H1 + l*32 + c] = (v-mu)*rs*W[I_V1LNW + c] + W[I_V1LNB + c];
  }
}

__global__ void k_xz1(float* __restrict__ W){
  int i = blockIdx.x*256 + threadIdx.x; if (i >= 1024*128) return;
  int l = i >> 7, j = i & 127;
  float acc = 0.f;
  for (int c=0; c<32; ++c) acc += W[O_H1 + l*32 + c] * W[I_V1INW + j*32 + c];
  W[O_XZ1 + i] = acc;
}

__global__ void k_dwcs1(float* __restrict__ W){
  int i = blockIdx.x*256 + threadIdx.x; if (i >= 64*1024) return;
  int ch = i >> 10, pix = i & 1023, a = pix >> 5, b = pix & 31;
  float acc = W[I_V1CONVB + ch];
  for (int dy=0; dy<3; ++dy){
    int aa = a+dy-1; if (aa < 0 || aa > 31) continue;
    for (int dx=0; dx<3; ++dx){
      int bb = b+dx-1; if (bb < 0 || bb > 31) continue;
      acc += W[O_XZ1 + (aa*32+bb)*128 + ch] * W[I_V1CONVW + ch*9 + dy*3 + dx];
    }
  }
  W[O_XC1 + i] = siluf(acc);
}

__global__ void k_dbl1(float* __restrict__ W){
  int i = blockIdx.x*256 + threadIdx.x; if (i >= 4*34*1024) return;
  int k = i / 34816, r = i % 34816, c = r / 1024, l = r % 1024;
  int ua = scan_addr(k, l, 5, 1023);
  float acc = 0.f;
  for (int d=0; d<64; ++d) acc += W[O_XC1 + d*1024 + ua] * W[I_V1XPW + (k*34+c)*64 + d];
  W[O_DBL1 + (k*34+c)*1024 + l] = acc;
}

__global__ void k_comb1(float* __restrict__ W){
  int l = blockIdx.x, dch = threadIdx.x;
  int t1 = ((l & 31) << 5) | (l >> 5);
  const __half* Y = (const __half*)(W + O_YS1);
  float x = __half2float(Y[l*256 + dch])
          + __half2float(Y[t1*256 + 64 + dch])
          + __half2float(Y[(1023-l)*256 + 128 + dch])
          + __half2float(Y[(1023-t1)*256 + 192 + dch]);
  float s = x, s2 = x*x;
  for (int off=32; off; off>>=1){ s += __shfl_xor(s, off, 64); s2 += __shfl_xor(s2, off, 64); }
  float mu = s/64.f, var = s2/64.f - mu*mu, rs = rsqrtf(var + 1e-5f);
  float yn = (x-mu)*rs*W[I_V1ONW + dch] + W[I_V1ONB + dch];
  float z = W[O_XZ1 + l*128 + 64 + dch];
  W[O_G1 + l*64 + dch] = yn * siluf(z);
}

__global__ void k_oproj1(float* __restrict__ W){
  int i = blockIdx.x*256 + threadIdx.x; if (i >= 1024*32) return;
  int l = i >> 5, c = i & 31;
  float acc = W[O_Y1 + i];
  for (int d=0; d<64; ++d) acc += W[O_G1 + l*64 + d] * W[I_V1OUTW + c*64 + d];
  W[O_OUTD + i] = acc;
}

// =============== stage E: conv stack ===============
__global__ void k_dw1(float* __restrict__ W){
  int i = blockIdx.x*256 + threadIdx.x; if (i >= 32*1024) return;
  int c = i >> 10, pix = i & 1023, a = pix >> 5, b = pix & 31;
  float acc = W[I_DW1B + c];
  for (int dy=0; dy<3; ++dy){
    int aa = a+dy-1; if (aa < 0 || aa > 31) continue;
    for (int dx=0; dx<3; ++dx){
      int bb = b+dx-1; if (bb < 0 || bb > 31) continue;
      acc += W[O_OUTD + (aa*32+bb)*32 + c] * W[I_DW1W + c*9 + dy*3 + dx];
    }
  }
  W[O_E1 + i] = acc;
}

__global__ void k_pw1(float* __restrict__ W){
  int i = blockIdx.x*256 + threadIdx.x; if (i >= 64*1024) return;
  int o = i >> 10, pix = i & 1023;
  float acc = W[I_PW1B + o];
  for (int c=0; c<32; ++c) acc += W[I_PW1W + o*32 + c] * W[O_E1 + c*1024 + pix];
  W[O_E2 + i] = acc;
}

__global__ void k_dw2(float* __restrict__ W){
  int i = blockIdx.x*256 + threadIdx.x; if (i >= 64*1024) return;
  int c = i >> 10, pix = i & 1023, a = pix >> 5, b = pix & 31;
  float acc = W[I_DW2B + c];
  for (int dy=0; dy<3; ++dy){
    int aa = a+dy-1; if (aa < 0 || aa > 31) continue;
    for (int dx=0; dx<3; ++dx){
      int bb = b+dx-1; if (bb < 0 || bb > 31) continue;
      acc += W[O_E2 + c*1024 + aa*32 + bb] * W[I_DW2W + c*9 + dy*3 + dx];
    }
  }
  W[O_E3 + i] = acc;
}

__global__ void k_pw2(float* __restrict__ W){
  int i = blockIdx.x*256 + threadIdx.x; if (i >= 128*1024) return;
  int o = i >> 10, pix = i & 1023;
  float acc = W[I_PW2B + o];
  for (int c=0; c<64; ++c) acc += W[I_PW2W + o*64 + c] * W[O_E3 + c*1024 + pix];
  W[O_E4 + i] = acc;
}

DEV void rs_coef(int o, int n, int& i0, int& i1, float& w0, float& w1){
  float src = 0.5f*(float)o - 0.25f;
  float f = floorf(src);
  float fr = src - f;
  int a = (int)f;
  if (a < 0){ i0 = 0; i1 = 0; w0 = 0.f; w1 = 1.f; }
  else if (a >= n-1){ i0 = n-1; i1 = n-1; w0 = 1.f; w1 = 0.f; }
  else { i0 = a; i1 = a+1; w0 = 1.f-fr; w1 = fr; }
}

__global__ void k_resize(float* __restrict__ W){
  int i = blockIdx.x*256 + threadIdx.x; if (i >= 128*4096) return;
  int c = i >> 12, pix = i & 4095, y = pix >> 6, x = pix & 63;
  int iy0, iy1, ix0, ix1; float wy0, wy1, wx0, wx1;
  rs_coef(y, 32, iy0, iy1, wy0, wy1);
  rs_coef(x, 32, ix0, ix1, wx0, wx1);
  const float* in = W + O_E4 + c*1024;
  float v = wy0*(wx0*in[iy0*32+ix0] + wx1*in[iy0*32+ix1])
          + wy1*(wx0*in[iy1*32+ix0] + wx1*in[iy1*32+ix1]);
  W[O_E5 + i] = v;
}

__global__ void k_cv1(float* __restrict__ W){
  int og = blockIdx.x >> 4, pt = blockIdx.x & 15;
  int pix = pt*256 + threadIdx.x;
  int y = pix >> 6, x = pix & 63;
  float acc[4];
  #pragma unroll
  for (int q=0; q<4; ++q) acc[q] = W[I_CV1B + og*4 + q];
  for (int i2=0; i2<128; ++i2){
    const float* in = W + O_E5 + i2*4096;
    for (int dy=0; dy<3; ++dy){
      int yy = y+dy-1; if (yy < 0 || yy > 63) continue;
      for (int dx=0; dx<3; ++dx){
        int xx = x+dx-1; if (xx < 0 || xx > 63) continue;
        float v = in[yy*64+xx];
        #pragma unroll
        for (int q=0; q<4; ++q)
          acc[q] += v * W[I_CV1W + ((long long)(og*4+q)*128 + i2)*9 + dy*3 + dx];
      }
    }
  }
  #pragma unroll
  for (int q=0; q<4; ++q) W[O_E6 + (long long)(og*4+q)*4096 + pix] = acc[q];
}

__global__ void k_cv2(float* __restrict__ W){
  int i = blockIdx.x*256 + threadIdx.x; if (i >= 256*4096) return;
  int o = i >> 12, pix = i & 4095;
  float acc = W[I_CV2B + o];
  for (int c=0; c<128; ++c) acc += W[I_CV2W + o*128 + c] * W[O_E6 + c*4096 + pix];
  W[O_E7 + i] = acc;
}

// fc im2col: B2[p][tap*256+d] = E7T[p shifted by tap][d] (0 if OOB)
__global__ void k_im2col(const unsigned short* __restrict__ E7T, unsigned short* __restrict__ B2){
  int r = blockIdx.x*256 + threadIdx.x;
  if (r >= 2304) return;
  int p = blockIdx.y;
  int tap = r >> 8, d = r & 255;
  int dy = tap/3 - 1, dx = tap%3 - 1;
  int y = p >> 6, x = p & 63;
  int yy = y + dy, xx = x + dx;
  unsigned short v = 0;
  if (yy >= 0 && yy < 64 && xx >= 0 && xx < 64) v = E7T[(yy*64+xx)*256 + d];
  B2[(long long)p*2304 + r] = v;
}

// =============== stage F: vssblock2 ===============
__global__ void k_ln2(float* __restrict__ W){
  int l = blockIdx.x, t = threadIdx.x;
  float v0 = W[O_E8 + (long long)t*4096 + l];
  float v1 = W[O_E8 + (long long)(t+256)*4096 + l];
  float s = v0+v1, s2 = v0*v0 + v1*v1;
  for (int off=32; off; off>>=1){ s += __shfl_xor(s, off, 64); s2 += __shfl_xor(s2, off, 64); }
  __shared__ float a[4], b[4];
  if ((t & 63) == 0){ a[t>>6] = s; b[t>>6] = s2; }
  __syncthreads();
  float S = a[0]+a[1]+a[2]+a[3], S2 = b[0]+b[1]+b[2]+b[3];
  float mu = S/512.f, var = S2/512.f - mu*mu, rs = rsqrtf(var + 1e-5f);
  unsigned short* H = (unsigned short*)(W + O_LN2);
  H[(long long)l*512 + t]     = f2bf((v0-mu)*rs*W[I_V2LNW + t]     + W[I_V2LNB + t]);
  H[(long long)l*512 + t+256] = f2bf((v1-mu)*rs*W[I_V2LNW + t+256] + W[I_V2LNB + t+256]);
}

__global__ void k_dwcs2(float* __restrict__ W){
  long long i = (long long)blockIdx.x*256 + threadIdx.x;
  int ch = (int)(i >> 12), pix = (int)(i & 4095), a = pix >> 6, b = pix & 63;
  float acc = W[I_V2CONVB + ch];
  const float* xp = W + O_XT2 + (long long)ch*4096;
  for (int dy=0; dy<3; ++dy){
    int aa = a+dy-1; if (aa < 0 || aa > 63) continue;
    for (int dx=0; dx<3; ++dx){
      int bb = b+dx-1; if (bb < 0 || bb > 63) continue;
      acc += xp[aa*64+bb] * W[I_V2CONVW + ch*9 + dy*3 + dx];
    }
  }
  W[O_XC2 + i] = siluf(acc);
}

__global__ void k_comb2(float* __restrict__ W){
  int l = blockIdx.x, t = threadIdx.x;
  int t1 = ((l & 63) << 6) | (l >> 6);
  const __half* Y = (const __half*)(W + O_YS2);
  float v[4]; float s = 0.f, s2 = 0.f;
  for (int q=0; q<4; ++q){
    int dch = t + q*256;
    float x = __half2float(Y[(long long)l*4096 + dch])
            + __half2float(Y[(long long)t1*4096 + 1024 + dch])
            + __half2float(Y[(long long)(4095-l)*4096 + 2048 + dch])
            + __half2float(Y[(long long)(4095-t1)*4096 + 3072 + dch]);
    v[q] = x; s += x; s2 += x*x;
  }
  for (int off=32; off; off>>=1){ s += __shfl_xor(s, off, 64); s2 += __shfl_xor(s2, off, 64); }
  __shared__ float a[4], b[4];
  if ((t & 63) == 0){ a[t>>6] = s; b[t>>6] = s2; }
  __syncthreads();
  float S = a[0]+a[1]+a[2]+a[3], S2 = b[0]+b[1]+b[2]+b[3];
  float mu = S/1024.f, var = S2/1024.f - mu*mu, rs = rsqrtf(var + 1e-5f);
  unsigned short* G = (unsigned short*)(W + O_G2);
  for (int q=0; q<4; ++q){
    int dch = t + q*256;
    float yn = (v[q]-mu)*rs*W[I_V2ONW + dch] + W[I_V2ONB + dch];
    float z = W[O_XZ2 + (long long)l*2048 + 1024 + dch];
    G[(long long)l*1024 + dch] = f2bf(yn * siluf(z));
  }
}

// =============== launch ===============
extern "C" void kernel_launch(void* const* d_in, const int* in_sizes, int n_in,
                              void* d_out, int out_size, void* d_ws, size_t ws_size,
                              hipStream_t stream){
  if (ws_size < (size_t)WS_FLOATS * sizeof(float)) return;
  float* W = (float*)d_ws;
  PtrTab tab;
  for (int i=0; i<53; ++i) tab.p[i] = d_in[i];
  const unsigned int* flagp = (const unsigned int*)d_in[9];

  k_ingest<<<INGEST_BLOCKS, 256, 0, stream>>>(tab, W);
  // bf16 weight conversions (depend only on ingest)
  k_tobf16<<<4096, 256, 0, stream>>>(W + I_V2INW,  (unsigned short*)(W + O_W2INB), 2048*512);
  k_tobf16<<<1024, 256, 0, stream>>>(W + I_V2XPW,  (unsigned short*)(W + O_XPWB),  256*1024);
  k_tobf16<<<2048, 256, 0, stream>>>(W + I_V2OUTW, (unsigned short*)(W + O_OUTWB), 512*1024);
  k_fcw2  <<<4608, 256, 0, stream>>>(W, (unsigned short*)(W + O_FCW2));

  k_c0    <<<64, 256, 0, stream>>>(W);
  k_zx    <<<290, 256, 0, stream>>>(W);
  k_conv4 <<<160, 256, 0, stream>>>(W);
  k_dtm   <<<2, 256, 0, stream>>>(W);
  k_mscan <<<1024, 64, 0, stream>>>(W);
  k_gaterms<<<32, 256, 0, stream>>>(W);
  k_outm  <<<64, 256, 0, stream>>>(W);
  k_c1    <<<128, 256, 0, stream>>>(W);
  k_ln1   <<<4, 256, 0, stream>>>(W);
  k_xz1   <<<512, 256, 0, stream>>>(W);
  k_dwcs1 <<<256, 256, 0, stream>>>(W);
  k_dbl1  <<<544, 256, 0, stream>>>(W);
  // vss1 chunked scan (f32 path)
  k_transpose<<<dim3(32, 2), 256, 0, stream>>>(W + O_XC1, W + O_XT1, 64, 1024, 1024, 64);
  k_scan_p1<64,64,1024,5,64,2,34,false><<<dim3(4,16), 64, 0, stream>>>(W, O_DBL1, O_XT1, O_P1, O_S1,
                                                                 I_V1DTW, I_V1DTB, I_V1ALOG);
  k_carry<4096,16><<<16, 256, 0, stream>>>(W, O_P1, O_S1);
  k_scan_p3<64,64,1024,5,64,2,34,false><<<dim3(4,16), 64, 0, stream>>>(W, O_DBL1, O_XT1, O_S1, O_YS1,
                                                                 I_V1DTW, I_V1DTB, I_V1ALOG, I_V1D);
  k_comb1 <<<1024, 64, 0, stream>>>(W);
  k_oproj1<<<128, 256, 0, stream>>>(W);
  k_dw1   <<<128, 256, 0, stream>>>(W);
  k_pw1   <<<256, 256, 0, stream>>>(W);
  k_dw2   <<<256, 256, 0, stream>>>(W);
  k_pw2   <<<512, 256, 0, stream>>>(W);
  k_resize<<<2048, 256, 0, stream>>>(W);
  k_cv1   <<<512, 256, 0, stream>>>(W);
  k_cv2   <<<4096, 256, 0, stream>>>(W);
  // fc via MFMA: E7 -> E7T(bf16) -> im2col B2 -> GEMM(+bias) -> E8
  k_transpose_dual<<<dim3(128, 8), 256, 0, stream>>>(W + O_E7, nullptr,
                      (unsigned short*)(W + O_E7T), 256, 4096, 4096, 256);
  k_im2col<<<dim3(9, 4096), 256, 0, stream>>>((const unsigned short*)(W + O_E7T),
                      (unsigned short*)(W + O_B2));
  k_gemm_bt<1><<<dim3(4, 32), 256, 0, stream>>>((const unsigned short*)(W + O_FCW2),
                      (const unsigned short*)(W + O_B2), 2304, 4096,
                      W + O_E8, W + I_FCB, nullptr, nullptr, nullptr);
  // vss2
  k_ln2   <<<4096, 256, 0, stream>>>(W);
  k_gemm_bt<0><<<dim3(32, 16), 256, 0, stream>>>((const unsigned short*)(W + O_LN2),
                      (const unsigned short*)(W + O_W2INB), 512, 2048,
                      W + O_XZ2, nullptr, nullptr, nullptr, nullptr);
  k_transpose<<<dim3(32, 128), 256, 0, stream>>>(W + O_XZ2, W + O_XT2, 4096, 1024, 2048, 4096); // XP[ch][pix]
  k_dwcs2 <<<16384, 256, 0, stream>>>(W);
  k_transpose_dual<<<dim3(128, 32), 256, 0, stream>>>(W + O_XC2, W + O_XT2,
                      (unsigned short*)(W + O_XT2B), 1024, 4096, 4096, 1024); // XT[pix][ch] f32+bf16
  // dbl2 as one GEMM: G[256][4096] = XPW x XT2B (pixel-major)
  k_gemm_bt<0><<<dim3(2, 32), 256, 0, stream>>>((const unsigned short*)(W + O_XPWB),
                      (const unsigned short*)(W + O_XT2B), 1024, 4096,
                      W + O_DBL2, nullptr, nullptr, nullptr, nullptr);
  k_scan_p1<1024,256,4096,6,64,32,64,true><<<dim3(16,64), 256, 0, stream>>>(W, O_DBL2, O_XT2, O_P2, O_S2,
                                                                       I_V2DTW, I_V2DTB, I_V2ALOG);
  k_carry<65536,64><<<256, 256, 0, stream>>>(W, O_P2, O_S2);
  k_scan_p3<1024,256,4096,6,64,32,64,true><<<dim3(16,64), 256, 0, stream>>>(W, O_DBL2, O_XT2, O_S2, O_YS2,
                                                                       I_V2DTW, I_V2DTB, I_V2ALOG, I_V2D);
  k_comb2 <<<4096, 256, 0, stream>>>(W);
  k_gemm_bt<2><<<dim3(4, 32), 256, 0, stream>>>((const unsigned short*)(W + O_OUTWB),
                      (const unsigned short*)(W + O_G2), 1024, 4096,
                      nullptr, nullptr, W + O_E8, flagp, d_out);
}

// Round 7
// 1257.656 us; speedup vs baseline: 5.4827x; 1.1436x over previous
//
#include <hip/hip_runtime.h>
#include <hip/hip_bf16.h>
#include <hip/hip_fp16.h>
#include <math.h>

#define DEV static __device__ __forceinline__

DEV float siluf(float x){ return x / (1.f + expf(-x)); }
DEV float softplusf(float x){ return (x > 20.f) ? x : log1pf(__expf(x)); }

DEV unsigned short f2bf(float f){
  unsigned int u = __float_as_uint(f);
  unsigned int r = (u + 0x7FFFu + ((u >> 16) & 1u)) >> 16;
  return (unsigned short)r;
}

using bf16x8 = __attribute__((ext_vector_type(8))) short;
using u16x8  = __attribute__((ext_vector_type(8))) unsigned short;
using f32x4  = __attribute__((ext_vector_type(4))) float;

// ---------------- input arena offsets (floats) ----------------
constexpr long long I_LD=0, I_C0W=9216, I_C0B=10944, I_MINW=10976, I_MCONVW=1198816,
 I_MCONVB=1203936, I_MDTB=1205216, I_MALOG=1205232, I_MD=1205248, I_MNORMW=1205264,
 I_MOUTW=1206288, I_C1W=1730576, I_C1B=3303440, I_V1LNW=3304464, I_V1LNB=3304496,
 I_V1INW=3304528, I_V1CONVW=3308624, I_V1CONVB=3309200, I_V1XPW=3309264, I_V1DTW=3317968,
 I_V1DTB=3318480, I_V1ALOG=3318736, I_V1D=3322832, I_V1ONW=3323088, I_V1ONB=3323152,
 I_V1OUTW=3323216, I_DW1W=3325264, I_DW1B=3325552, I_PW1W=3325584, I_PW1B=3327632,
 I_DW2W=3327696, I_DW2B=3328272, I_PW2W=3328336, I_PW2B=3336528, I_CV1W=3336656,
 I_CV1B=3484112, I_CV2W=3484240, I_CV2B=3517008, I_FCW=3517264, I_FCB=4696912,
 I_V2LNW=4697424, I_V2LNB=4697936, I_V2INW=4698448, I_V2CONVW=5747024, I_V2CONVB=5756240,
 I_V2XPW=5757264, I_V2DTW=6019408, I_V2DTB=6150480, I_V2ALOG=6154576, I_V2D=6220112,
 I_V2ONW=6224208, I_V2ONB=6225232, I_V2OUTW=6226256;
constexpr long long TOTAL_IN = 6750544;
constexpr int INGEST_BLOCKS = (int)((TOTAL_IN + 255) / 256);
constexpr long long O_E8 = 6750544;                // (512,4096) f32, lives to the end
constexpr long long SCR  = 8847696;
// phase 1 (stages A-E)
constexpr long long O_X0=SCR+0, O_ZX=SCR+16384, O_XBCC=SCR+90624, O_DTM=SCR+131584,
 O_TPRE=SCR+132096, O_TG=SCR+164864, O_OUTM=SCR+197632, O_Y1=SCR+214016, O_H1=SCR+246784,
 O_XZ1=SCR+279552, O_XC1=SCR+410624, O_DBL1=SCR+476160, O_YS1=SCR+615424, O_G1=SCR+877568,
 O_OUTD=SCR+943104, O_E1=SCR+975872, O_E2=SCR+1008640, O_E3=SCR+1074176, O_E4=SCR+1139712,
 O_E5=SCR+1270784, O_E6=SCR+1795072, O_E7=SCR+2319360;
// vss1 scan scratch
constexpr long long O_XT1=SCR+3367936, O_P1=SCR+3433472, O_S1=SCR+3499008;   // S1 ends 3564544
// free gap 3564544..4000000 (435456 slots)
constexpr long long O_CV2WB=SCR+3564544;  // 256x128 bf16 = 16384 slots, ends 3580928
// fc MFMA scratch (phase-1 tail; dead before XZ2 is written)
constexpr long long O_FCW2=SCR+4000000;   // 512x2304 bf16 (589824 slots, ends 4589824)
constexpr long long O_E7T =SCR+4600000;   // 4096x256 bf16 (524288 slots, ends 5124288)
constexpr long long O_E6TB=O_E7T;         // 4096x128 bf16 (262144) — used before E7T is written
constexpr long long O_B2  =SCR+5242880;   // 4096x2304 bf16 (4718592 slots, ends 9961472)
// phase 2 (stage F)
constexpr long long O_XZ2=SCR+0;                        // 4096x2048 f32 (ends 8388608)
constexpr long long O_XC2=SCR+8388608;                  // 1024x4096 f32 (dead after dual transpose)
constexpr long long O_P2 =O_XC2;                        // overlay: P written in scan pass 1
constexpr long long O_XT2=SCR+12582912;                 // XP[ch][pix] f32, then XT[pix][ch] f32
constexpr long long O_G2 =O_XT2;                        // overlay: bf16 G2 (comb2 out, XT2 dead)
constexpr long long O_DBL2=SCR+16777216;                // G[256][4096] f32 (ends 17825792)
constexpr long long O_S2 =SCR+17825792;                 // (ends 22020096)
constexpr long long O_YS2=SCR+22020096;                 // fp16 ys (ends 30408704)
constexpr long long O_LN2=SCR+30408704;                 // bf16 LN2 (524288 slots, ends 31457280)
// bf16 weights / staging (top region, no overlap — verified end-to-start chain)
constexpr long long O_W2INB=SCR+32505856;               // ends 33030144
constexpr long long O_XPWB =SCR+33030144;               // ends 33161216
constexpr long long O_OUTWB=SCR+33161216;               // ends 33423360
constexpr long long O_XT2B =SCR+33423360;               // ends 35520512
constexpr long long WS_FLOATS = SCR + 36700160;

struct PtrTab { const void* p[53]; };

__constant__ long long c_inoff[53] = { 0, 9216, 10944, 10976, 1198816, 1203936, 1205216,
 1205232, 1205248, 1205264, 1206288, 1730576, 3303440, 3304464, 3304496, 3304528, 3308624,
 3309200, 3309264, 3317968, 3318480, 3318736, 3322832, 3323088, 3323152, 3323216, 3325264,
 3325552, 3325584, 3327632, 3327696, 3328272, 3328336, 3336528, 3336656, 3484112, 3484240,
 3517008, 3517264, 4696912, 4697424, 4697936, 4698448, 5747024, 5756240, 5757264, 6019408,
 6150480, 6154576, 6220112, 6224208, 6225232, 6226256 };

DEV int scan_addr(int k, int l, int lg, int Lm1){
  int p = (k & 2) ? (Lm1 - l) : l;
  int mask = (1 << lg) - 1;
  if (k & 1) p = ((p & mask) << lg) | (p >> lg);
  return p;
}

// =============== ingest ===============
__global__ void k_ingest(PtrTab t, float* __restrict__ W){
  long long idx = (long long)blockIdx.x*256 + threadIdx.x;
  if (idx >= TOTAL_IN) return;
  int j = 0;
  #pragma unroll
  for (int q=1; q<53; ++q) if (idx >= c_inoff[q]) j = q;
  int local = (int)(idx - c_inoff[j]);
  bool bf = (*(const unsigned int*)t.p[9]) == 0x3F803F80u;
  float v;
  if (bf){
    unsigned short u = ((const unsigned short*)t.p[j])[local];
    v = __uint_as_float(((unsigned int)u) << 16);
  } else {
    v = ((const float*)t.p[j])[local];
  }
  W[idx] = v;
}

// =============== converts ===============
__global__ void k_tobf16(const float* __restrict__ src, unsigned short* __restrict__ dst, int n){
  int i = blockIdx.x*256 + threadIdx.x;
  if (i < n) dst[i] = f2bf(src[i]);
}

// FCW (512,256,3,3) -> A2[c][tap*256+i2] bf16
__global__ void k_fcw2(const float* __restrict__ W, unsigned short* __restrict__ dst){
  int i = blockIdx.x*256 + threadIdx.x;
  if (i >= 512*2304) return;
  int c = i / 2304, r = i % 2304, tap = r >> 8, i2 = r & 255;
  dst[i] = f2bf(W[I_FCW + ((long long)(c*256 + i2))*9 + tap]);
}

// =============== transposes ===============
__global__ void k_transpose(const float* __restrict__ in, float* __restrict__ out,
                            int rows, int cols, long long instride, long long outstride){
  __shared__ float tile[32][33];
  int tx = threadIdx.x & 31, ty = threadIdx.x >> 5;
  long long c0 = (long long)blockIdx.x*32, r0 = (long long)blockIdx.y*32;
  #pragma unroll
  for (int i=0;i<32;i+=8){
    long long r = r0 + ty + i, c = c0 + tx;
    if (r < rows && c < cols) tile[ty+i][tx] = in[r*instride + c];
  }
  __syncthreads();
  #pragma unroll
  for (int i=0;i<32;i+=8){
    long long r = r0 + tx, c = c0 + ty + i;
    if (r < rows && c < cols) out[c*outstride + r] = tile[tx][ty+i];
  }
}

// transpose with optional f32 + bf16 outputs
__global__ void k_transpose_dual(const float* __restrict__ in, float* __restrict__ outF,
                                 unsigned short* __restrict__ outB,
                                 int rows, int cols, long long instride, long long outstride){
  __shared__ float tile[32][33];
  int tx = threadIdx.x & 31, ty = threadIdx.x >> 5;
  long long c0 = (long long)blockIdx.x*32, r0 = (long long)blockIdx.y*32;
  #pragma unroll
  for (int i=0;i<32;i+=8){
    long long r = r0 + ty + i, c = c0 + tx;
    if (r < rows && c < cols) tile[ty+i][tx] = in[r*instride + c];
  }
  __syncthreads();
  #pragma unroll
  for (int i=0;i<32;i+=8){
    long long r = r0 + tx, c = c0 + ty + i;
    if (r < rows && c < cols){
      float v = tile[tx][ty+i];
      if (outF) outF[c*outstride + r] = v;
      outB[c*outstride + r] = f2bf(v);
    }
  }
}

// =============== bf16 MFMA GEMM: C[m][n] = sum_k A[m][k]*B[n][k] ===============
template<int MODE>
__global__ __launch_bounds__(256)
void k_gemm_bt(const unsigned short* __restrict__ A, const unsigned short* __restrict__ B,
               int K, int N, float* __restrict__ Cout, const float* __restrict__ bias,
               const float* __restrict__ res, const unsigned int* flagp, void* dout){
  constexpr int LDK = 72;  // 64 + 8 pad
  __shared__ unsigned short As[128*LDK], Bs[128*LDK];
  int m0 = blockIdx.x*128, n0 = blockIdx.y*128;
  int tid = threadIdx.x;
  int wave = tid >> 6, lane = tid & 63, quad = lane >> 4, l16 = lane & 15;
  int wm = wave >> 1, wn = wave & 1;
  f32x4 acc[4][4];
  #pragma unroll
  for (int a=0;a<4;++a)
    #pragma unroll
    for (int b=0;b<4;++b) acc[a][b] = (f32x4){0.f,0.f,0.f,0.f};
  int srow = tid >> 1, shalf = (tid & 1)*32;
  for (int kt = 0; kt < K; kt += 64){
    const u16x8* ga = (const u16x8*)(A + (long long)(m0+srow)*K + kt + shalf);
    const u16x8* gb = (const u16x8*)(B + (long long)(n0+srow)*K + kt + shalf);
    u16x8* da = (u16x8*)&As[srow*LDK + shalf];
    u16x8* db = (u16x8*)&Bs[srow*LDK + shalf];
    #pragma unroll
    for (int c=0;c<4;++c){ da[c] = ga[c]; db[c] = gb[c]; }
    __syncthreads();
    #pragma unroll
    for (int ks=0; ks<64; ks+=32){
      bf16x8 af[4], bfr[4];
      #pragma unroll
      for (int mi=0;mi<4;++mi)
        af[mi] = *(const bf16x8*)&As[(wm*64 + mi*16 + l16)*LDK + ks + quad*8];
      #pragma unroll
      for (int ni=0;ni<4;++ni)
        bfr[ni] = *(const bf16x8*)&Bs[(wn*64 + ni*16 + l16)*LDK + ks + quad*8];
      #pragma unroll
      for (int mi=0;mi<4;++mi)
        #pragma unroll
        for (int ni=0;ni<4;++ni)
          acc[mi][ni] = __builtin_amdgcn_mfma_f32_16x16x32_bf16(af[mi], bfr[ni], acc[mi][ni], 0, 0, 0);
    }
    __syncthreads();
  }
  bool bf = (MODE == 2) ? ((*flagp) == 0x3F803F80u) : false;
  #pragma unroll
  for (int mi=0;mi<4;++mi){
    #pragma unroll
    for (int ni=0;ni<4;++ni){
      #pragma unroll
      for (int r=0;r<4;++r){
        int m = m0 + wm*64 + mi*16 + quad*4 + r;
        int n = n0 + wn*64 + ni*16 + l16;
        float v = acc[mi][ni][r];
        if (MODE == 1) v += bias[m];
        if (MODE == 2){
          v += res[(long long)m*N + n];
          if (bf) ((unsigned short*)dout)[(long long)m*N + n] = f2bf(v);
          else    ((float*)dout)[(long long)m*N + n] = v;
        } else {
          Cout[(long long)m*N + n] = v;
        }
      }
    }
  }
}

// =============== chunked selective-scan (3 passes) ===============
// GATHER=true: dbl rows are stored in PIXEL order; stage via scan_addr gather.
template<int DCH, int TD, int L, int LG, int T, int R, int CROWS, bool GATHER>
__global__ void k_scan_p1(float* __restrict__ W, long long o_dbl, long long o_xt,
                          long long o_p, long long o_s,
                          long long i_dtw, long long i_dtb, long long i_alog){
  constexpr int NT = DCH/TD;
  int k = blockIdx.x / NT, tile = blockIdx.x % NT;
  int c = blockIdx.y;
  int t = threadIdx.x;
  int dch = tile*TD + t;
  __shared__ float lds[CROWS*T];
  const float* dbl = W + o_dbl + (long long)k*CROWS*L;
  const int Lm1 = L-1, mask = (1<<LG)-1;
  for (int idx = t; idx < CROWS*T; idx += TD){
    int row = idx / T, col = idx % T;
    int l = c*T + col;
    int cc = GATHER ? scan_addr(k, l, LG, Lm1) : l;
    lds[idx] = dbl[(long long)row*L + cc];
  }
  __syncthreads();
  float w[R], A[16], p[16], s[16];
  #pragma unroll
  for (int r=0;r<R;++r) w[r] = W[i_dtw + (long long)(k*DCH+dch)*R + r];
  float bias = W[i_dtb + k*DCH + dch];
  #pragma unroll
  for (int n=0;n<16;++n){
    A[n] = -expf(W[i_alog + (long long)(k*DCH+dch)*16 + n]);
    p[n] = 1.f; s[n] = 0.f;
  }
  const float* XT = W + o_xt;
  for (int j=0;j<T;++j){
    int l = c*T + j;
    int p_ = (k&2)? (Lm1-l) : l;
    int ua = (k&1)? (((p_&mask)<<LG)|(p_>>LG)) : p_;
    float u = XT[(long long)ua*DCH + dch];
    float dt = bias;
    #pragma unroll
    for (int r=0;r<R;++r) dt += lds[r*T+j]*w[r];
    dt = softplusf(dt);
    float du = dt*u;
    #pragma unroll
    for (int n=0;n<16;++n){
      float dA = __expf(dt*A[n]);
      float B = lds[(R+n)*T + j];
      p[n] *= dA;
      s[n] = s[n]*dA + du*B;
    }
  }
  float* P = W + o_p; float* S = W + o_s;
  long long base = (long long)c*(4LL*DCH*16) + (long long)k*DCH*16 + (long long)dch*16;
  #pragma unroll
  for (int n=0;n<16;++n){ P[base+n] = p[n]; S[base+n] = s[n]; }
}

template<int NSTATE, int CH>
__global__ void k_carry(float* __restrict__ W, long long o_p, long long o_s){
  int idx = blockIdx.x*256 + threadIdx.x;
  if (idx >= NSTATE) return;
  const float* P = W + o_p; float* S = W + o_s;
  float h = 0.f;
  for (int c=0;c<CH;++c){
    float p = P[(long long)c*NSTATE + idx];
    float s = S[(long long)c*NSTATE + idx];
    S[(long long)c*NSTATE + idx] = h;
    h = h*p + s;
  }
}

template<int DCH, int TD, int L, int LG, int T, int R, int CROWS, bool GATHER>
__global__ void k_scan_p3(float* __restrict__ W, long long o_dbl, long long o_xt,
                          long long o_s, long long o_ys,
                          long long i_dtw, long long i_dtb, long long i_alog, long long i_dd){
  constexpr int NT = DCH/TD;
  int k = blockIdx.x / NT, tile = blockIdx.x % NT;
  int c = blockIdx.y;
  int t = threadIdx.x;
  int dch = tile*TD + t;
  __shared__ float lds[CROWS*T];
  const float* dbl = W + o_dbl + (long long)k*CROWS*L;
  const int Lm1 = L-1, mask = (1<<LG)-1;
  for (int idx = t; idx < CROWS*T; idx += TD){
    int row = idx / T, col = idx % T;
    int l = c*T + col;
    int cc = GATHER ? scan_addr(k, l, LG, Lm1) : l;
    lds[idx] = dbl[(long long)row*L + cc];
  }
  __syncthreads();
  float w[R], A[16], s[16];
  #pragma unroll
  for (int r=0;r<R;++r) w[r] = W[i_dtw + (long long)(k*DCH+dch)*R + r];
  float bias = W[i_dtb + k*DCH + dch];
  float Dv = W[i_dd + k*DCH + dch];
  long long sbase = (long long)c*(4LL*DCH*16) + (long long)k*DCH*16 + (long long)dch*16;
  #pragma unroll
  for (int n=0;n<16;++n){
    A[n] = -expf(W[i_alog + (long long)(k*DCH+dch)*16 + n]);
    s[n] = W[o_s + sbase + n];
  }
  const float* XT = W + o_xt;
  __half* Y = (__half*)(W + o_ys);
  for (int j=0;j<T;++j){
    int l = c*T + j;
    int p_ = (k&2)? (Lm1-l) : l;
    int ua = (k&1)? (((p_&mask)<<LG)|(p_>>LG)) : p_;
    float u = XT[(long long)ua*DCH + dch];
    float dt = bias;
    #pragma unroll
    for (int r=0;r<R;++r) dt += lds[r*T+j]*w[r];
    dt = softplusf(dt);
    float du = dt*u;
    float y = Dv*u;
    #pragma unroll
    for (int n=0;n<16;++n){
      float dA = __expf(dt*A[n]);
      float B = lds[(R+n)*T + j];
      float C = lds[(R+16+n)*T + j];
      s[n] = s[n]*dA + du*B;
      y += s[n]*C;
    }
    Y[(long long)l*(4*DCH) + k*DCH + dch] = __float2half(y);
  }
}

// =============== stage A: c0 ===============
__global__ void k_c0(float* __restrict__ W){
  int i = blockIdx.x*256 + threadIdx.x; if (i >= 32*512) return;
  int c = i >> 9, l = i & 511;
  float acc = W[I_C0B + c];
  for (int ii=0; ii<18; ++ii)
    for (int j=0; j<3; ++j){
      int p = l-1+j;
      if (p >= 0 && p < 512) acc += W[I_LD + ii*512 + p] * W[I_C0W + (c*18+ii)*3 + j];
    }
  W[O_X0 + i] = acc;
}

// =============== stage B: mamba2 ===============
// zx: one block per output feature j; 256 thr = 32 l x 8 K-chunks; LDS weight row
__global__ void k_zxf(float* __restrict__ W){
  int j = blockIdx.x;                 // 0..2319
  int t = threadIdx.x, l = t & 31, kc = t >> 5;
  __shared__ float wrow[512];
  for (int idx = t; idx < 512; idx += 256) wrow[idx] = W[I_MINW + (long long)j*512 + idx];
  __syncthreads();
  float acc = 0.f;
  const float* u = W + O_X0 + l*512;
  for (int d = kc*64; d < kc*64 + 64; ++d) acc += u[d]*wrow[d];
  __shared__ float red[256];
  red[t] = acc; __syncthreads();
  if (kc == 0){
    float s = 0.f;
    #pragma unroll
    for (int q=0;q<8;++q) s += red[l + q*32];
    W[O_ZX + l*2320 + j] = s;
  }
}

__global__ void k_conv4(float* __restrict__ W){
  int i = blockIdx.x*256 + threadIdx.x; if (i >= 32*1280) return;
  int l = i / 1280, c = i % 1280;
  float acc = W[I_MCONVB + c];
  for (int j=0; j<4; ++j){
    int p = l-3+j;
    if (p >= 0) acc += W[O_ZX + p*2320 + 1024 + c] * W[I_MCONVW + c*4 + j];
  }
  W[O_XBCC + l*1280 + c] = siluf(acc);
}

__global__ void k_dtm(float* __restrict__ W){
  int i = blockIdx.x*256 + threadIdx.x; if (i >= 512) return;
  int l = i >> 4, h = i & 15;
  W[O_DTM + i] = softplusf(W[O_ZX + l*2320 + 2304 + h] + W[I_MDTB + h]);
}

__global__ void k_mscan(float* __restrict__ W){
  int h = blockIdx.x >> 6, pp = blockIdx.x & 63;
  int lane = threadIdx.x;
  float A = -expf(W[I_MALOG + h]);
  float Dv = W[I_MD + h];
  float s0 = 0.f, s1 = 0.f;
  for (int l=0; l<32; ++l){
    float dt = W[O_DTM + l*16 + h];
    float xv = W[O_XBCC + l*1280 + h*64 + pp];
    float dA = expf(dt*A);
    float b0 = W[O_XBCC + l*1280 + 1024 + lane];
    float b1 = W[O_XBCC + l*1280 + 1088 + lane];
    float c0 = W[O_XBCC + l*1280 + 1152 + lane];
    float c1 = W[O_XBCC + l*1280 + 1216 + lane];
    float du = dt*xv;
    s0 = s0*dA + du*b0;
    s1 = s1*dA + du*b1;
    float part = s0*c0 + s1*c1;
    for (int off=32; off; off>>=1) part += __shfl_xor(part, off, 64);
    if (lane == 0) W[O_TPRE + l*1024 + h*64 + pp] = part + Dv*xv;
  }
}

__global__ void k_gaterms(float* __restrict__ W){
  int l = blockIdx.x, t = threadIdx.x;
  float vals[4]; float ss = 0.f;
  for (int q=0; q<4; ++q){
    int c = t + q*256;
    float z = W[O_ZX + l*2320 + c];
    float y = W[O_TPRE + l*1024 + c];
    float v = y * siluf(z);
    vals[q] = v; ss += v*v;
  }
  for (int off=32; off; off>>=1) ss += __shfl_xor(ss, off, 64);
  __shared__ float sm[4];
  if ((t & 63) == 0) sm[t>>6] = ss;
  __syncthreads();
  float tot = sm[0]+sm[1]+sm[2]+sm[3];
  float r = rsqrtf(tot/1024.f + 1e-5f);
  for (int q=0; q<4; ++q){
    int c = t + q*256;
    W[O_TG + l*1024 + c] = vals[q]*r*W[I_MNORMW + c];
  }
}

// outm: one block per output dim d; 256 thr = 32 l x 8 K-chunks (128 each)
__global__ void k_outmf(float* __restrict__ W){
  int d = blockIdx.x;                 // 0..511
  int t = threadIdx.x, l = t & 31, kc = t >> 5;
  __shared__ float wrow[1024];
  for (int idx = t; idx < 1024; idx += 256) wrow[idx] = W[I_MOUTW + (long long)d*1024 + idx];
  __syncthreads();
  float acc = 0.f;
  const float* tg = W + O_TG + l*1024;
  for (int c = kc*128; c < kc*128 + 128; ++c) acc += tg[c]*wrow[c];
  __shared__ float red[256];
  red[t] = acc; __syncthreads();
  if (kc == 0){
    float s = 0.f;
    #pragma unroll
    for (int q=0;q<8;++q) s += red[l + q*32];
    W[O_OUTM + l*512 + d] = s;
  }
}

// =============== stage C: c1 — one block per out-channel o ===============
__global__ void k_c1f(float* __restrict__ W){
  int o = blockIdx.x;                 // 0..1023
  int t = threadIdx.x, l = t & 31, kc = t >> 5;
  __shared__ float wrow[1536];
  for (int idx = t; idx < 1536; idx += 256) wrow[idx] = W[I_C1W + (long long)o*1536 + idx];
  __syncthreads();
  float acc = 0.f;
  for (int ii = kc*64; ii < kc*64 + 64; ++ii){
    #pragma unroll
    for (int j=0;j<3;++j){
      int p = l-1+j;
      if (p >= 0 && p < 32) acc += W[O_OUTM + p*512 + ii] * wrow[ii*3+j];
    }
  }
  __shared__ float red[256];
  red[t] = acc; __syncthreads();
  if (kc == 0){
    float s = W[I_C1B + o];
    #pragma unroll
    for (int q=0;q<8;++q) s += red[l + q*32];
    W[O_Y1 + o*32 + l] = s;
  }
}

// =============== vssblock 1 ===============
__global__ void k_ln1(float* __restrict__ W){
  int l = blockIdx.x*256 + threadIdx.x; if (l >= 1024) return;
  float s = 0.f, s2 = 0.f;
  for (int c=0; c<32; ++c){ float v = W[O_Y1 + l*32 + c]; s += v; s2 += v*v; }
  float mu = s/32.f, var = s2/32.f - mu*mu, rs = rsqrtf(var + 1e-5f);
  for (int c=0; c<32; ++c){
    float v = W[O_Y1 + l*32 + c];
    W[O_H1 + l*32 + c] = (v-mu)*rs*W[I_V1LNW + c] + W[I_V1LNB + c];
  }
}

__global__ void k_xz1(float* __restrict__ W){
  int i = blockIdx.x*256 + threadIdx.x; if (i >= 1024*128) return;
  int l = i >> 7, j = i & 127;
  float acc = 0.f;
  for (int c=0; c<32; ++c) acc += W[O_H1 + l*32 + c] * W[I_V1INW + j*32 + c];
  W[O_XZ1 + i] = acc;
}

__global__ void k_dwcs1(float* __restrict__ W){
  int i = blockIdx.x*256 + threadIdx.x; if (i >= 64*1024) return;
  int ch = i >> 10, pix = i & 1023, a = pix >> 5, b = pix & 31;
  float acc = W[I_V1CONVB + ch];
  for (int dy=0; dy<3; ++dy){
    int aa = a+dy-1; if (aa < 0 || aa > 31) continue;
    for (int dx=0; dx<3; ++dx){
      int bb = b+dx-1; if (bb < 0 || bb > 31) continue;
      acc += W[O_XZ1 + (aa*32+bb)*128 + ch] * W[I_V1CONVW + ch*9 + dy*3 + dx];
    }
  }
  W[O_XC1 + i] = siluf(acc);
}

// dbl1: PIXEL-major output now (scan gathers); coalesced XC1 reads
__global__ void k_dbl1(float* __restrict__ W){
  int i = blockIdx.x*256 + threadIdx.x; if (i >= 4*34*1024) return;
  int k = i / 34816, r = i % 34816, c = r / 1024, l = r % 1024;
  float acc = 0.f;
  for (int d=0; d<64; ++d) acc += W[O_XC1 + d*1024 + l] * W[I_V1XPW + (k*34+c)*64 + d];
  W[O_DBL1 + (k*34+c)*1024 + l] = acc;
}

__global__ void k_comb1(float* __restrict__ W){
  int l = blockIdx.x, dch = threadIdx.x;
  int t1 = ((l & 31) << 5) | (l >> 5);
  const __half* Y = (const __half*)(W + O_YS1);
  float x = __half2float(Y[l*256 + dch])
          + __half2float(Y[t1*256 + 64 + dch])
          + __half2float(Y[(1023-l)*256 + 128 + dch])
          + __half2float(Y[(1023-t1)*256 + 192 + dch]);
  float s = x, s2 = x*x;
  for (int off=32; off; off>>=1){ s += __shfl_xor(s, off, 64); s2 += __shfl_xor(s2, off, 64); }
  float mu = s/64.f, var = s2/64.f - mu*mu, rs = rsqrtf(var + 1e-5f);
  float yn = (x-mu)*rs*W[I_V1ONW + dch] + W[I_V1ONB + dch];
  float z = W[O_XZ1 + l*128 + 64 + dch];
  W[O_G1 + l*64 + dch] = yn * siluf(z);
}

__global__ void k_oproj1(float* __restrict__ W){
  int i = blockIdx.x*256 + threadIdx.x; if (i >= 1024*32) return;
  int l = i >> 5, c = i & 31;
  float acc = W[O_Y1 + i];
  for (int d=0; d<64; ++d) acc += W[O_G1 + l*64 + d] * W[I_V1OUTW + c*64 + d];
  W[O_OUTD + i] = acc;
}

// =============== stage E: conv stack ===============
__global__ void k_dw1(float* __restrict__ W){
  int i = blockIdx.x*256 + threadIdx.x; if (i >= 32*1024) return;
  int c = i >> 10, pix = i & 1023, a = pix >> 5, b = pix & 31;
  float acc = W[I_DW1B + c];
  for (int dy=0; dy<3; ++dy){
    int aa = a+dy-1; if (aa < 0 || aa > 31) continue;
    for (int dx=0; dx<3; ++dx){
      int bb = b+dx-1; if (bb < 0 || bb > 31) continue;
      acc += W[O_OUTD + (aa*32+bb)*32 + c] * W[I_DW1W + c*9 + dy*3 + dx];
    }
  }
  W[O_E1 + i] = acc;
}

__global__ void k_pw1(float* __restrict__ W){
  int i = blockIdx.x*256 + threadIdx.x; if (i >= 64*1024) return;
  int o = i >> 10, pix = i & 1023;
  float acc = W[I_PW1B + o];
  for (int c=0; c<32; ++c) acc += W[I_PW1W + o*32 + c] * W[O_E1 + c*1024 + pix];
  W[O_E2 + i] = acc;
}

__global__ void k_dw2(float* __restrict__ W){
  int i = blockIdx.x*256 + threadIdx.x; if (i >= 64*1024) return;
  int c = i >> 10, pix = i & 1023, a = pix >> 5, b = pix & 31;
  float acc = W[I_DW2B + c];
  for (int dy=0; dy<3; ++dy){
    int aa = a+dy-1; if (aa < 0 || aa > 31) continue;
    for (int dx=0; dx<3; ++dx){
      int bb = b+dx-1; if (bb < 0 || bb > 31) continue;
      acc += W[O_E2 + c*1024 + aa*32 + bb] * W[I_DW2W + c*9 + dy*3 + dx];
    }
  }
  W[O_E3 + i] = acc;
}

__global__ void k_pw2(float* __restrict__ W){
  int i = blockIdx.x*256 + threadIdx.x; if (i >= 128*1024) return;
  int o = i >> 10, pix = i & 1023;
  float acc = W[I_PW2B + o];
  for (int c=0; c<64; ++c) acc += W[I_PW2W + o*64 + c] * W[O_E3 + c*1024 + pix];
  W[O_E4 + i] = acc;
}

DEV void rs_coef(int o, int n, int& i0, int& i1, float& w0, float& w1){
  float src = 0.5f*(float)o - 0.25f;
  float f = floorf(src);
  float fr = src - f;
  int a = (int)f;
  if (a < 0){ i0 = 0; i1 = 0; w0 = 0.f; w1 = 1.f; }
  else if (a >= n-1){ i0 = n-1; i1 = n-1; w0 = 1.f; w1 = 0.f; }
  else { i0 = a; i1 = a+1; w0 = 1.f-fr; w1 = fr; }
}

__global__ void k_resize(float* __restrict__ W){
  int i = blockIdx.x*256 + threadIdx.x; if (i >= 128*4096) return;
  int c = i >> 12, pix = i & 4095, y = pix >> 6, x = pix & 63;
  int iy0, iy1, ix0, ix1; float wy0, wy1, wx0, wx1;
  rs_coef(y, 32, iy0, iy1, wy0, wy1);
  rs_coef(x, 32, ix0, ix1, wx0, wx1);
  const float* in = W + O_E4 + c*1024;
  float v = wy0*(wx0*in[iy0*32+ix0] + wx1*in[iy0*32+ix1])
          + wy1*(wx0*in[iy1*32+ix0] + wx1*in[iy1*32+ix1]);
  W[O_E5 + i] = v;
}

__global__ void k_cv1(float* __restrict__ W){
  int og = blockIdx.x >> 4, pt = blockIdx.x & 15;
  int pix = pt*256 + threadIdx.x;
  int y = pix >> 6, x = pix & 63;
  float acc[4];
  #pragma unroll
  for (int q=0; q<4; ++q) acc[q] = W[I_CV1B + og*4 + q];
  for (int i2=0; i2<128; ++i2){
    const float* in = W + O_E5 + i2*4096;
    for (int dy=0; dy<3; ++dy){
      int yy = y+dy-1; if (yy < 0 || yy > 63) continue;
      for (int dx=0; dx<3; ++dx){
        int xx = x+dx-1; if (xx < 0 || xx > 63) continue;
        float v = in[yy*64+xx];
        #pragma unroll
        for (int q=0; q<4; ++q)
          acc[q] += v * W[I_CV1W + ((long long)(og*4+q)*128 + i2)*9 + dy*3 + dx];
      }
    }
  }
  #pragma unroll
  for (int q=0; q<4; ++q) W[O_E6 + (long long)(og*4+q)*4096 + pix] = acc[q];
}

// fc im2col: B2[p][tap*256+d] = E7T[p shifted by tap][d] (0 if OOB)
__global__ void k_im2col(const unsigned short* __restrict__ E7T, unsigned short* __restrict__ B2){
  int r = blockIdx.x*256 + threadIdx.x;
  if (r >= 2304) return;
  int p = blockIdx.y;
  int tap = r >> 8, d = r & 255;
  int dy = tap/3 - 1, dx = tap%3 - 1;
  int y = p >> 6, x = p & 63;
  int yy = y + dy, xx = x + dx;
  unsigned short v = 0;
  if (yy >= 0 && yy < 64 && xx >= 0 && xx < 64) v = E7T[(yy*64+xx)*256 + d];
  B2[(long long)p*2304 + r] = v;
}

// =============== stage F: vssblock2 ===============
__global__ void k_ln2(float* __restrict__ W){
  int l = blockIdx.x, t = threadIdx.x;
  float v0 = W[O_E8 + (long long)t*4096 + l];
  float v1 = W[O_E8 + (long long)(t+256)*4096 + l];
  float s = v0+v1, s2 = v0*v0 + v1*v1;
  for (int off=32; off; off>>=1){ s += __shfl_xor(s, off, 64); s2 += __shfl_xor(s2, off, 64); }
  __shared__ float a[4], b[4];
  if ((t & 63) == 0){ a[t>>6] = s; b[t>>6] = s2; }
  __syncthreads();
  float S = a[0]+a[1]+a[2]+a[3], S2 = b[0]+b[1]+b[2]+b[3];
  float mu = S/512.f, var = S2/512.f - mu*mu, rs = rsqrtf(var + 1e-5f);
  unsigned short* H = (unsigned short*)(W + O_LN2);
  H[(long long)l*512 + t]     = f2bf((v0-mu)*rs*W[I_V2LNW + t]     + W[I_V2LNB + t]);
  H[(long long)l*512 + t+256] = f2bf((v1-mu)*rs*W[I_V2LNW + t+256] + W[I_V2LNB + t+256]);
}

__global__ void k_dwcs2(float* __restrict__ W){
  long long i = (long long)blockIdx.x*256 + threadIdx.x;
  int ch = (int)(i >> 12), pix = (int)(i & 4095), a = pix >> 6, b = pix & 63;
  float acc = W[I_V2CONVB + ch];
  const float* xp = W + O_XT2 + (long long)ch*4096;
  for (int dy=0; dy<3; ++dy){
    int aa = a+dy-1; if (aa < 0 || aa > 63) continue;
    for (int dx=0; dx<3; ++dx){
      int bb = b+dx-1; if (bb < 0 || bb > 63) continue;
      acc += xp[aa*64+bb] * W[I_V2CONVW + ch*9 + dy*3 + dx];
    }
  }
  W[O_XC2 + i] = siluf(acc);
}

__global__ void k_comb2(float* __restrict__ W){
  int l = blockIdx.x, t = threadIdx.x;
  int t1 = ((l & 63) << 6) | (l >> 6);
  const __half* Y = (const __half*)(W + O_YS2);
  float v[4]; float s = 0.f, s2 = 0.f;
  for (int q=0; q<4; ++q){
    int dch = t + q*256;
    float x = __half2float(Y[(long long)l*4096 + dch])
            + __half2float(Y[(long long)t1*4096 + 1024 + dch])
            + __half2float(Y[(long long)(4095-l)*4096 + 2048 + dch])
            + __half2float(Y[(long long)(4095-t1)*4096 + 3072 + dch]);
    v[q] = x; s += x; s2 += x*x;
  }
  for (int off=32; off; off>>=1){ s += __shfl_xor(s, off, 64); s2 += __shfl_xor(s2, off, 64); }
  __shared__ float a[4], b[4];
  if ((t & 63) == 0){ a[t>>6] = s; b[t>>6] = s2; }
  __syncthreads();
  float S = a[0]+a[1]+a[2]+a[3], S2 = b[0]+b[1]+b[2]+b[3];
  float mu = S/1024.f, var = S2/1024.f - mu*mu, rs = rsqrtf(var + 1e-5f);
  unsigned short* G = (unsigned short*)(W + O_G2);
  for (int q=0; q<4; ++q){
    int dch = t + q*256;
    float yn = (v[q]-mu)*rs*W[I_V2ONW + dch] + W[I_V2ONB + dch];
    float z = W[O_XZ2 + (long long)l*2048 + 1024 + dch];
    G[(long long)l*1024 + dch] = f2bf(yn * siluf(z));
  }
}

// =============== launch ===============
extern "C" void kernel_launch(void* const* d_in, const int* in_sizes, int n_in,
                              void* d_out, int out_size, void* d_ws, size_t ws_size,
                              hipStream_t stream){
  if (ws_size < (size_t)WS_FLOATS * sizeof(float)) return;
  float* W = (float*)d_ws;
  PtrTab tab;
  for (int i=0; i<53; ++i) tab.p[i] = d_in[i];
  const unsigned int* flagp = (const unsigned int*)d_in[9];

  k_ingest<<<INGEST_BLOCKS, 256, 0, stream>>>(tab, W);
  // bf16 weight conversions (depend only on ingest)
  k_tobf16<<<4096, 256, 0, stream>>>(W + I_V2INW,  (unsigned short*)(W + O_W2INB), 2048*512);
  k_tobf16<<<1024, 256, 0, stream>>>(W + I_V2XPW,  (unsigned short*)(W + O_XPWB),  256*1024);
  k_tobf16<<<2048, 256, 0, stream>>>(W + I_V2OUTW, (unsigned short*)(W + O_OUTWB), 512*1024);
  k_tobf16<<<128, 256, 0, stream>>>(W + I_CV2W,    (unsigned short*)(W + O_CV2WB), 256*128);
  k_fcw2  <<<4608, 256, 0, stream>>>(W, (unsigned short*)(W + O_FCW2));

  k_c0    <<<64, 256, 0, stream>>>(W);
  k_zxf   <<<2320, 256, 0, stream>>>(W);
  k_conv4 <<<160, 256, 0, stream>>>(W);
  k_dtm   <<<2, 256, 0, stream>>>(W);
  k_mscan <<<1024, 64, 0, stream>>>(W);
  k_gaterms<<<32, 256, 0, stream>>>(W);
  k_outmf <<<512, 256, 0, stream>>>(W);
  k_c1f   <<<1024, 256, 0, stream>>>(W);
  k_ln1   <<<4, 256, 0, stream>>>(W);
  k_xz1   <<<512, 256, 0, stream>>>(W);
  k_dwcs1 <<<256, 256, 0, stream>>>(W);
  k_dbl1  <<<544, 256, 0, stream>>>(W);
  // vss1 chunked scan (f32 path, pixel-major dbl + gather)
  k_transpose<<<dim3(32, 2), 256, 0, stream>>>(W + O_XC1, W + O_XT1, 64, 1024, 1024, 64);
  k_scan_p1<64,64,1024,5,64,2,34,true><<<dim3(4,16), 64, 0, stream>>>(W, O_DBL1, O_XT1, O_P1, O_S1,
                                                                 I_V1DTW, I_V1DTB, I_V1ALOG);
  k_carry<4096,16><<<16, 256, 0, stream>>>(W, O_P1, O_S1);
  k_scan_p3<64,64,1024,5,64,2,34,true><<<dim3(4,16), 64, 0, stream>>>(W, O_DBL1, O_XT1, O_S1, O_YS1,
                                                                 I_V1DTW, I_V1DTB, I_V1ALOG, I_V1D);
  k_comb1 <<<1024, 64, 0, stream>>>(W);
  k_oproj1<<<128, 256, 0, stream>>>(W);
  k_dw1   <<<128, 256, 0, stream>>>(W);
  k_pw1   <<<256, 256, 0, stream>>>(W);
  k_dw2   <<<256, 256, 0, stream>>>(W);
  k_pw2   <<<512, 256, 0, stream>>>(W);
  k_resize<<<2048, 256, 0, stream>>>(W);
  k_cv1   <<<512, 256, 0, stream>>>(W);
  // cv2 via MFMA: E6 -> E6T(bf16, pix-major) -> GEMM(+bias) -> E7 f32 [ch][pix]
  k_transpose_dual<<<dim3(128, 4), 256, 0, stream>>>(W + O_E6, nullptr,
                      (unsigned short*)(W + O_E6TB), 128, 4096, 4096, 128);
  k_gemm_bt<1><<<dim3(2, 32), 256, 0, stream>>>((const unsigned short*)(W + O_CV2WB),
                      (const unsigned short*)(W + O_E6TB), 128, 4096,
                      W + O_E7, W + I_CV2B, nullptr, nullptr, nullptr);
  // fc via MFMA: E7 -> E7T(bf16) -> im2col B2 -> GEMM(+bias) -> E8
  k_transpose_dual<<<dim3(128, 8), 256, 0, stream>>>(W + O_E7, nullptr,
                      (unsigned short*)(W + O_E7T), 256, 4096, 4096, 256);
  k_im2col<<<dim3(9, 4096), 256, 0, stream>>>((const unsigned short*)(W + O_E7T),
                      (unsigned short*)(W + O_B2));
  k_gemm_bt<1><<<dim3(4, 32), 256, 0, stream>>>((const unsigned short*)(W + O_FCW2),
                      (const unsigned short*)(W + O_B2), 2304, 4096,
                      W + O_E8, W + I_FCB, nullptr, nullptr, nullptr);
  // vss2
  k_ln2   <<<4096, 256, 0, stream>>>(W);
  k_gemm_bt<0><<<dim3(32, 16), 256, 0, stream>>>((const unsigned short*)(W + O_LN2),
                      (const unsigned short*)(W + O_W2INB), 512, 2048,
                      W + O_XZ2, nullptr, nullptr, nullptr, nullptr);
  k_transpose<<<dim3(32, 128), 256, 0, stream>>>(W + O_XZ2, W + O_XT2, 4096, 1024, 2048, 4096); // XP[ch][pix]
  k_dwcs2 <<<16384, 256, 0, stream>>>(W);
  k_transpose_dual<<<dim3(128, 32), 256, 0, stream>>>(W + O_XC2, W + O_XT2,
                      (unsigned short*)(W + O_XT2B), 1024, 4096, 4096, 1024); // XT[pix][ch] f32+bf16
  // dbl2 as one GEMM: G[256][4096] = XPW x XT2B (pixel-major)
  k_gemm_bt<0><<<dim3(2, 32), 256, 0, stream>>>((const unsigned short*)(W + O_XPWB),
                      (const unsigned short*)(W + O_XT2B), 1024, 4096,
                      W + O_DBL2, nullptr, nullptr, nullptr, nullptr);
  k_scan_p1<1024,256,4096,6,64,32,64,true><<<dim3(16,64), 256, 0, stream>>>(W, O_DBL2, O_XT2, O_P2, O_S2,
                                                                       I_V2DTW, I_V2DTB, I_V2ALOG);
  k_carry<65536,64><<<256, 256, 0, stream>>>(W, O_P2, O_S2);
  k_scan_p3<1024,256,4096,6,64,32,64,true><<<dim3(16,64), 256, 0, stream>>>(W, O_DBL2, O_XT2, O_S2, O_YS2,
                                                                       I_V2DTW, I_V2DTB, I_V2ALOG, I_V2D);
  k_comb2 <<<4096, 256, 0, stream>>>(W);
  k_gemm_bt<2><<<dim3(4, 32), 256, 0, stream>>>((const unsigned short*)(W + O_OUTWB),
                      (const unsigned short*)(W + O_G2), 1024, 4096,
                      nullptr, nullptr, W + O_E8, flagp, d_out);
}

// Round 8
// 1007.740 us; speedup vs baseline: 6.8424x; 1.2480x over previous
//
#include <hip/hip_runtime.h>
#include <hip/hip_bf16.h>
#include <hip/hip_fp16.h>
#include <math.h>

#define DEV static __device__ __forceinline__

DEV float siluf(float x){ return x / (1.f + expf(-x)); }
DEV float softplusf(float x){ return (x > 20.f) ? x : log1pf(__expf(x)); }

DEV unsigned short f2bf(float f){
  unsigned int u = __float_as_uint(f);
  unsigned int r = (u + 0x7FFFu + ((u >> 16) & 1u)) >> 16;
  return (unsigned short)r;
}

using bf16x8 = __attribute__((ext_vector_type(8))) short;
using u16x8  = __attribute__((ext_vector_type(8))) unsigned short;
using f32x4  = __attribute__((ext_vector_type(4))) float;

// ---------------- input arena offsets (floats) ----------------
constexpr long long I_LD=0, I_C0W=9216, I_C0B=10944, I_MINW=10976, I_MCONVW=1198816,
 I_MCONVB=1203936, I_MDTB=1205216, I_MALOG=1205232, I_MD=1205248, I_MNORMW=1205264,
 I_MOUTW=1206288, I_C1W=1730576, I_C1B=3303440, I_V1LNW=3304464, I_V1LNB=3304496,
 I_V1INW=3304528, I_V1CONVW=3308624, I_V1CONVB=3309200, I_V1XPW=3309264, I_V1DTW=3317968,
 I_V1DTB=3318480, I_V1ALOG=3318736, I_V1D=3322832, I_V1ONW=3323088, I_V1ONB=3323152,
 I_V1OUTW=3323216, I_DW1W=3325264, I_DW1B=3325552, I_PW1W=3325584, I_PW1B=3327632,
 I_DW2W=3327696, I_DW2B=3328272, I_PW2W=3328336, I_PW2B=3336528, I_CV1W=3336656,
 I_CV1B=3484112, I_CV2W=3484240, I_CV2B=3517008, I_FCW=3517264, I_FCB=4696912,
 I_V2LNW=4697424, I_V2LNB=4697936, I_V2INW=4698448, I_V2CONVW=5747024, I_V2CONVB=5756240,
 I_V2XPW=5757264, I_V2DTW=6019408, I_V2DTB=6150480, I_V2ALOG=6154576, I_V2D=6220112,
 I_V2ONW=6224208, I_V2ONB=6225232, I_V2OUTW=6226256;
constexpr long long TOTAL_IN = 6750544;
constexpr int INGEST_BLOCKS = (int)((TOTAL_IN + 255) / 256);
constexpr long long O_E8 = 6750544;                // (512,4096) f32, lives to the end
constexpr long long SCR  = 8847696;
// phase 1 (stages A-E)
constexpr long long O_X0=SCR+0, O_ZX=SCR+16384, O_XBCC=SCR+90624, O_DTM=SCR+131584,
 O_TPRE=SCR+132096, O_TG=SCR+164864, O_OUTM=SCR+197632, O_Y1=SCR+214016, O_H1=SCR+246784,
 O_XZ1=SCR+279552, O_XC1=SCR+410624, O_DBL1=SCR+476160, O_YS1=SCR+615424, O_G1=SCR+877568,
 O_OUTD=SCR+943104, O_E1=SCR+975872, O_E2=SCR+1008640, O_E3=SCR+1074176, O_E4=SCR+1139712,
 O_E5=SCR+1270784, O_E6=SCR+1795072, O_E7=SCR+2319360;
// vss1 scan scratch
constexpr long long O_XT1=SCR+3367936, O_P1=SCR+3433472, O_S1=SCR+3499008;   // S1 ends 3564544
// free gap 3564544..4000000
constexpr long long O_CV2WB=SCR+3564544;  // 256x128 bf16 = 16384 slots, ends 3580928
constexpr long long O_CV1WB=SCR+3580928;  // 128x1152 bf16 = 73728 slots, ends 3654656
// fc/cv MFMA scratch (phase-1 tail; dead before XZ2 is written)
constexpr long long O_FCW2=SCR+4000000;   // 512x2304 bf16 (589824 slots, ends 4589824)
constexpr long long O_E7T =SCR+4600000;   // 4096x256 bf16 (524288 slots, ends 5124288)
constexpr long long O_E6TB=O_E7T;         // 4096x128 bf16 — sequential reuse
constexpr long long O_E5TB=O_E7T;         // 4096x128 bf16 — sequential reuse (cv1, earliest)
constexpr long long O_B2  =SCR+5242880;   // 4096x2304 bf16 (4718592 slots, ends 9961472)
constexpr long long O_CV1B2=O_B2;         // 4096x1152 bf16 (2359296 slots) — used before fc's B2
// phase 2 (stage F)
constexpr long long O_XZ2=SCR+0;                        // 4096x2048 f32 (ends 8388608)
constexpr long long O_XC2=SCR+8388608;                  // 1024x4096 f32 (dead after dual transpose)
constexpr long long O_P2 =O_XC2;                        // overlay: P written in scan pass 1
constexpr long long O_XT2=SCR+12582912;                 // XP[ch][pix] f32, then XT[pix][ch] f32
constexpr long long O_G2 =O_XT2;                        // overlay: bf16 G2 (comb2 out, XT2 dead)
constexpr long long O_DBL2=SCR+16777216;                // G[256][4096] f32 (ends 17825792)
constexpr long long O_S2 =SCR+17825792;                 // (ends 22020096)
constexpr long long O_YS2=SCR+22020096;                 // fp16 ys (ends 30408704)
constexpr long long O_LN2=SCR+30408704;                 // bf16 LN2 (524288 slots, ends 31457280)
// bf16 weights / staging (top region, no overlap)
constexpr long long O_W2INB=SCR+32505856;               // ends 33030144
constexpr long long O_XPWB =SCR+33030144;               // ends 33161216
constexpr long long O_OUTWB=SCR+33161216;               // ends 33423360
constexpr long long O_XT2B =SCR+33423360;               // ends 35520512
constexpr long long WS_FLOATS = SCR + 36700160;

struct PtrTab { const void* p[53]; };

__constant__ long long c_inoff[53] = { 0, 9216, 10944, 10976, 1198816, 1203936, 1205216,
 1205232, 1205248, 1205264, 1206288, 1730576, 3303440, 3304464, 3304496, 3304528, 3308624,
 3309200, 3309264, 3317968, 3318480, 3318736, 3322832, 3323088, 3323152, 3323216, 3325264,
 3325552, 3325584, 3327632, 3327696, 3328272, 3328336, 3336528, 3336656, 3484112, 3484240,
 3517008, 3517264, 4696912, 4697424, 4697936, 4698448, 5747024, 5756240, 5757264, 6019408,
 6150480, 6154576, 6220112, 6224208, 6225232, 6226256 };

DEV int scan_addr(int k, int l, int lg, int Lm1){
  int p = (k & 2) ? (Lm1 - l) : l;
  int mask = (1 << lg) - 1;
  if (k & 1) p = ((p & mask) << lg) | (p >> lg);
  return p;
}

// =============== ingest ===============
__global__ void k_ingest(PtrTab t, float* __restrict__ W){
  long long idx = (long long)blockIdx.x*256 + threadIdx.x;
  if (idx >= TOTAL_IN) return;
  int j = 0;
  #pragma unroll
  for (int q=1; q<53; ++q) if (idx >= c_inoff[q]) j = q;
  int local = (int)(idx - c_inoff[j]);
  bool bf = (*(const unsigned int*)t.p[9]) == 0x3F803F80u;
  float v;
  if (bf){
    unsigned short u = ((const unsigned short*)t.p[j])[local];
    v = __uint_as_float(((unsigned int)u) << 16);
  } else {
    v = ((const float*)t.p[j])[local];
  }
  W[idx] = v;
}

// =============== converts ===============
__global__ void k_tobf16(const float* __restrict__ src, unsigned short* __restrict__ dst, int n){
  int i = blockIdx.x*256 + threadIdx.x;
  if (i < n) dst[i] = f2bf(src[i]);
}

// conv weight (rows, CIN, 3, 3) -> A[c][tap*CIN+i2] bf16
template<int CIN>
__global__ void k_wpack(const float* __restrict__ src, unsigned short* __restrict__ dst, int rows){
  int i = blockIdx.x*256 + threadIdx.x;
  if (i >= rows*9*CIN) return;
  int c = i / (9*CIN), r = i % (9*CIN), tap = r / CIN, i2 = r % CIN;
  dst[i] = f2bf(src[((long long)(c*CIN + i2))*9 + tap]);
}

// im2col: B2[p][tap*CIN+d] = XT[p shifted by tap][d] (0 if OOB), 64x64 image
template<int CIN>
__global__ void k_im2colT(const unsigned short* __restrict__ XT, unsigned short* __restrict__ B2){
  int r = blockIdx.x*256 + threadIdx.x;
  if (r >= 9*CIN) return;
  int p = blockIdx.y;
  int tap = r / CIN, d = r % CIN;
  int dy = tap/3 - 1, dx = tap%3 - 1;
  int y = p >> 6, x = p & 63;
  int yy = y + dy, xx = x + dx;
  unsigned short v = 0;
  if (yy >= 0 && yy < 64 && xx >= 0 && xx < 64) v = XT[(long long)(yy*64+xx)*CIN + d];
  B2[(long long)p*(9*CIN) + r] = v;
}

// =============== transposes ===============
__global__ void k_transpose(const float* __restrict__ in, float* __restrict__ out,
                            int rows, int cols, long long instride, long long outstride){
  __shared__ float tile[32][33];
  int tx = threadIdx.x & 31, ty = threadIdx.x >> 5;
  long long c0 = (long long)blockIdx.x*32, r0 = (long long)blockIdx.y*32;
  #pragma unroll
  for (int i=0;i<32;i+=8){
    long long r = r0 + ty + i, c = c0 + tx;
    if (r < rows && c < cols) tile[ty+i][tx] = in[r*instride + c];
  }
  __syncthreads();
  #pragma unroll
  for (int i=0;i<32;i+=8){
    long long r = r0 + tx, c = c0 + ty + i;
    if (r < rows && c < cols) out[c*outstride + r] = tile[tx][ty+i];
  }
}

__global__ void k_transpose_dual(const float* __restrict__ in, float* __restrict__ outF,
                                 unsigned short* __restrict__ outB,
                                 int rows, int cols, long long instride, long long outstride){
  __shared__ float tile[32][33];
  int tx = threadIdx.x & 31, ty = threadIdx.x >> 5;
  long long c0 = (long long)blockIdx.x*32, r0 = (long long)blockIdx.y*32;
  #pragma unroll
  for (int i=0;i<32;i+=8){
    long long r = r0 + ty + i, c = c0 + tx;
    if (r < rows && c < cols) tile[ty+i][tx] = in[r*instride + c];
  }
  __syncthreads();
  #pragma unroll
  for (int i=0;i<32;i+=8){
    long long r = r0 + tx, c = c0 + ty + i;
    if (r < rows && c < cols){
      float v = tile[tx][ty+i];
      if (outF) outF[c*outstride + r] = v;
      outB[c*outstride + r] = f2bf(v);
    }
  }
}

// =============== bf16 MFMA GEMM: C[m][n] = sum_k A[m][k]*B[n][k] ===============
template<int MODE>
__global__ __launch_bounds__(256)
void k_gemm_bt(const unsigned short* __restrict__ A, const unsigned short* __restrict__ B,
               int K, int N, float* __restrict__ Cout, const float* __restrict__ bias,
               const float* __restrict__ res, const unsigned int* flagp, void* dout){
  constexpr int LDK = 72;  // 64 + 8 pad
  __shared__ unsigned short As[128*LDK], Bs[128*LDK];
  int m0 = blockIdx.x*128, n0 = blockIdx.y*128;
  int tid = threadIdx.x;
  int wave = tid >> 6, lane = tid & 63, quad = lane >> 4, l16 = lane & 15;
  int wm = wave >> 1, wn = wave & 1;
  f32x4 acc[4][4];
  #pragma unroll
  for (int a=0;a<4;++a)
    #pragma unroll
    for (int b=0;b<4;++b) acc[a][b] = (f32x4){0.f,0.f,0.f,0.f};
  int srow = tid >> 1, shalf = (tid & 1)*32;
  for (int kt = 0; kt < K; kt += 64){
    const u16x8* ga = (const u16x8*)(A + (long long)(m0+srow)*K + kt + shalf);
    const u16x8* gb = (const u16x8*)(B + (long long)(n0+srow)*K + kt + shalf);
    u16x8* da = (u16x8*)&As[srow*LDK + shalf];
    u16x8* db = (u16x8*)&Bs[srow*LDK + shalf];
    #pragma unroll
    for (int c=0;c<4;++c){ da[c] = ga[c]; db[c] = gb[c]; }
    __syncthreads();
    #pragma unroll
    for (int ks=0; ks<64; ks+=32){
      bf16x8 af[4], bfr[4];
      #pragma unroll
      for (int mi=0;mi<4;++mi)
        af[mi] = *(const bf16x8*)&As[(wm*64 + mi*16 + l16)*LDK + ks + quad*8];
      #pragma unroll
      for (int ni=0;ni<4;++ni)
        bfr[ni] = *(const bf16x8*)&Bs[(wn*64 + ni*16 + l16)*LDK + ks + quad*8];
      #pragma unroll
      for (int mi=0;mi<4;++mi)
        #pragma unroll
        for (int ni=0;ni<4;++ni)
          acc[mi][ni] = __builtin_amdgcn_mfma_f32_16x16x32_bf16(af[mi], bfr[ni], acc[mi][ni], 0, 0, 0);
    }
    __syncthreads();
  }
  bool bf = (MODE == 2) ? ((*flagp) == 0x3F803F80u) : false;
  #pragma unroll
  for (int mi=0;mi<4;++mi){
    #pragma unroll
    for (int ni=0;ni<4;++ni){
      #pragma unroll
      for (int r=0;r<4;++r){
        int m = m0 + wm*64 + mi*16 + quad*4 + r;
        int n = n0 + wn*64 + ni*16 + l16;
        float v = acc[mi][ni][r];
        if (MODE == 1) v += bias[m];
        if (MODE == 2){
          v += res[(long long)m*N + n];
          if (bf) ((unsigned short*)dout)[(long long)m*N + n] = f2bf(v);
          else    ((float*)dout)[(long long)m*N + n] = v;
        } else {
          Cout[(long long)m*N + n] = v;
        }
      }
    }
  }
}

// =============== chunked selective-scan (3 passes) ===============
// dbl rows stored PIXEL-major; staged transposed: stage[j][slot], slot: dt r -> r,
// B n -> BOFF+n, C n -> BOFF+16+n. STRIDE mult of 4, BOFF mult of 4 (b128-aligned).
// Fast paths: dtsum->P identity (exact); A[n]==-(n+1) pattern -> one exp + power chain.
template<int DCH, int TD, int L, int LG, int T, int R, int CROWS, int STRIDE, int BOFF>
__global__ void k_scan_p1(float* __restrict__ W, long long o_dbl, long long o_xt,
                          long long o_p, long long o_s,
                          long long i_dtw, long long i_dtb, long long i_alog){
  constexpr int NT = DCH/TD;
  int k = blockIdx.x / NT, tile = blockIdx.x % NT;
  int c = blockIdx.y;
  int t = threadIdx.x;
  int dch = tile*TD + t;
  __shared__ __align__(16) float stage[T*STRIDE];
  const float* dbl = W + o_dbl + (long long)k*CROWS*L;
  const int Lm1 = L-1, mask = (1<<LG)-1;
  for (int idx = t; idx < CROWS*T; idx += TD){
    int row = idx / T, col = idx % T;
    int l = c*T + col;
    int cc = scan_addr(k, l, LG, Lm1);
    int slot = (row < R) ? row : (BOFF + row - R);
    stage[col*STRIDE + slot] = dbl[(long long)row*L + cc];
  }
  __syncthreads();
  float w[R], A[16], s[16];
  #pragma unroll
  for (int r=0;r<R;++r) w[r] = W[i_dtw + (long long)(k*DCH+dch)*R + r];
  float bias = W[i_dtb + k*DCH + dch];
  bool pat = true;
  #pragma unroll
  for (int n=0;n<16;++n){
    A[n] = -expf(W[i_alog + (long long)(k*DCH+dch)*16 + n]);
    pat = pat && (fabsf(A[n] + (float)(n+1)) <= 1e-3f*(float)(n+1));
    s[n] = 0.f;
  }
  const float* XT = W + o_xt;
  float dtsum = 0.f;
  for (int j=0;j<T;++j){
    int l = c*T + j;
    int p_ = (k&2)? (Lm1-l) : l;
    int ua = (k&1)? (((p_&mask)<<LG)|(p_>>LG)) : p_;
    float u = XT[(long long)ua*DCH + dch];
    float x = bias;
    if (R == 2){
      x += stage[j*STRIDE]*w[0] + stage[j*STRIDE+1]*w[1];
    } else {
      const f32x4* dp = (const f32x4*)&stage[j*STRIDE];
      #pragma unroll
      for (int r4=0; r4<R/4; ++r4){
        f32x4 v = dp[r4];
        x += v[0]*w[r4*4] + v[1]*w[r4*4+1] + v[2]*w[r4*4+2] + v[3]*w[r4*4+3];
      }
    }
    float e = __expf(x);
    float dt = (x > 15.f) ? x : __logf(1.f + e);
    dtsum += dt;
    float du = dt*u;
    const f32x4* bp = (const f32x4*)&stage[j*STRIDE + BOFF];
    if (pat){
      float q = __expf(-dt), qp = q;
      #pragma unroll
      for (int n4=0;n4<4;++n4){
        f32x4 B = bp[n4];
        #pragma unroll
        for (int i=0;i<4;++i){ s[n4*4+i] = s[n4*4+i]*qp + du*B[i]; qp *= q; }
      }
    } else {
      #pragma unroll
      for (int n4=0;n4<4;++n4){
        f32x4 B = bp[n4];
        #pragma unroll
        for (int i=0;i<4;++i){ int n=n4*4+i; s[n] = s[n]*__expf(dt*A[n]) + du*B[i]; }
      }
    }
  }
  float* P = W + o_p; float* S = W + o_s;
  long long base = (long long)c*(4LL*DCH*16) + (long long)k*DCH*16 + (long long)dch*16;
  #pragma unroll
  for (int n=0;n<16;++n){ P[base+n] = __expf(dtsum*A[n]); S[base+n] = s[n]; }
}

template<int NSTATE, int CH>
__global__ void k_carry(float* __restrict__ W, long long o_p, long long o_s){
  int idx = blockIdx.x*256 + threadIdx.x;
  if (idx >= NSTATE) return;
  const float* P = W + o_p; float* S = W + o_s;
  float h = 0.f;
  for (int c=0;c<CH;++c){
    float p = P[(long long)c*NSTATE + idx];
    float s = S[(long long)c*NSTATE + idx];
    S[(long long)c*NSTATE + idx] = h;
    h = h*p + s;
  }
}

template<int DCH, int TD, int L, int LG, int T, int R, int CROWS, int STRIDE, int BOFF>
__global__ void k_scan_p3(float* __restrict__ W, long long o_dbl, long long o_xt,
                          long long o_s, long long o_ys,
                          long long i_dtw, long long i_dtb, long long i_alog, long long i_dd){
  constexpr int NT = DCH/TD;
  int k = blockIdx.x / NT, tile = blockIdx.x % NT;
  int c = blockIdx.y;
  int t = threadIdx.x;
  int dch = tile*TD + t;
  __shared__ __align__(16) float stage[T*STRIDE];
  const float* dbl = W + o_dbl + (long long)k*CROWS*L;
  const int Lm1 = L-1, mask = (1<<LG)-1;
  for (int idx = t; idx < CROWS*T; idx += TD){
    int row = idx / T, col = idx % T;
    int l = c*T + col;
    int cc = scan_addr(k, l, LG, Lm1);
    int slot = (row < R) ? row : (BOFF + row - R);
    stage[col*STRIDE + slot] = dbl[(long long)row*L + cc];
  }
  __syncthreads();
  float w[R], A[16], s[16];
  #pragma unroll
  for (int r=0;r<R;++r) w[r] = W[i_dtw + (long long)(k*DCH+dch)*R + r];
  float bias = W[i_dtb + k*DCH + dch];
  float Dv = W[i_dd + k*DCH + dch];
  long long sbase = (long long)c*(4LL*DCH*16) + (long long)k*DCH*16 + (long long)dch*16;
  bool pat = true;
  #pragma unroll
  for (int n=0;n<16;++n){
    A[n] = -expf(W[i_alog + (long long)(k*DCH+dch)*16 + n]);
    pat = pat && (fabsf(A[n] + (float)(n+1)) <= 1e-3f*(float)(n+1));
    s[n] = W[o_s + sbase + n];
  }
  const float* XT = W + o_xt;
  __half* Y = (__half*)(W + o_ys);
  for (int j=0;j<T;++j){
    int l = c*T + j;
    int p_ = (k&2)? (Lm1-l) : l;
    int ua = (k&1)? (((p_&mask)<<LG)|(p_>>LG)) : p_;
    float u = XT[(long long)ua*DCH + dch];
    float x = bias;
    if (R == 2){
      x += stage[j*STRIDE]*w[0] + stage[j*STRIDE+1]*w[1];
    } else {
      const f32x4* dp = (const f32x4*)&stage[j*STRIDE];
      #pragma unroll
      for (int r4=0; r4<R/4; ++r4){
        f32x4 v = dp[r4];
        x += v[0]*w[r4*4] + v[1]*w[r4*4+1] + v[2]*w[r4*4+2] + v[3]*w[r4*4+3];
      }
    }
    float e = __expf(x);
    float dt = (x > 15.f) ? x : __logf(1.f + e);
    float du = dt*u;
    float y = Dv*u;
    const f32x4* bp = (const f32x4*)&stage[j*STRIDE + BOFF];
    const f32x4* cp = (const f32x4*)&stage[j*STRIDE + BOFF + 16];
    if (pat){
      float q = __expf(-dt), qp = q;
      #pragma unroll
      for (int n4=0;n4<4;++n4){
        f32x4 B = bp[n4], C = cp[n4];
        #pragma unroll
        for (int i=0;i<4;++i){
          int n = n4*4+i;
          s[n] = s[n]*qp + du*B[i];
          y += s[n]*C[i];
          qp *= q;
        }
      }
    } else {
      #pragma unroll
      for (int n4=0;n4<4;++n4){
        f32x4 B = bp[n4], C = cp[n4];
        #pragma unroll
        for (int i=0;i<4;++i){
          int n = n4*4+i;
          s[n] = s[n]*__expf(dt*A[n]) + du*B[i];
          y += s[n]*C[i];
        }
      }
    }
    Y[(long long)l*(4*DCH) + k*DCH + dch] = __float2half(y);
  }
}

// =============== stage A: c0 ===============
__global__ void k_c0(float* __restrict__ W){
  int i = blockIdx.x*256 + threadIdx.x; if (i >= 32*512) return;
  int c = i >> 9, l = i & 511;
  float acc = W[I_C0B + c];
  for (int ii=0; ii<18; ++ii)
    for (int j=0; j<3; ++j){
      int p = l-1+j;
      if (p >= 0 && p < 512) acc += W[I_LD + ii*512 + p] * W[I_C0W + (c*18+ii)*3 + j];
    }
  W[O_X0 + i] = acc;
}

// =============== stage B: mamba2 ===============
__global__ void k_zxf(float* __restrict__ W){
  int j = blockIdx.x;
  int t = threadIdx.x, l = t & 31, kc = t >> 5;
  __shared__ float wrow[512];
  for (int idx = t; idx < 512; idx += 256) wrow[idx] = W[I_MINW + (long long)j*512 + idx];
  __syncthreads();
  float acc = 0.f;
  const float* u = W + O_X0 + l*512;
  for (int d = kc*64; d < kc*64 + 64; ++d) acc += u[d]*wrow[d];
  __shared__ float red[256];
  red[t] = acc; __syncthreads();
  if (kc == 0){
    float s = 0.f;
    #pragma unroll
    for (int q=0;q<8;++q) s += red[l + q*32];
    W[O_ZX + l*2320 + j] = s;
  }
}

__global__ void k_conv4(float* __restrict__ W){
  int i = blockIdx.x*256 + threadIdx.x; if (i >= 32*1280) return;
  int l = i / 1280, c = i % 1280;
  float acc = W[I_MCONVB + c];
  for (int j=0; j<4; ++j){
    int p = l-3+j;
    if (p >= 0) acc += W[O_ZX + p*2320 + 1024 + c] * W[I_MCONVW + c*4 + j];
  }
  W[O_XBCC + l*1280 + c] = siluf(acc);
}

__global__ void k_dtm(float* __restrict__ W){
  int i = blockIdx.x*256 + threadIdx.x; if (i >= 512) return;
  int l = i >> 4, h = i & 15;
  W[O_DTM + i] = softplusf(W[O_ZX + l*2320 + 2304 + h] + W[I_MDTB + h]);
}

__global__ void k_mscan(float* __restrict__ W){
  int h = blockIdx.x >> 6, pp = blockIdx.x & 63;
  int lane = threadIdx.x;
  float A = -expf(W[I_MALOG + h]);
  float Dv = W[I_MD + h];
  float s0 = 0.f, s1 = 0.f;
  for (int l=0; l<32; ++l){
    float dt = W[O_DTM + l*16 + h];
    float xv = W[O_XBCC + l*1280 + h*64 + pp];
    float dA = expf(dt*A);
    float b0 = W[O_XBCC + l*1280 + 1024 + lane];
    float b1 = W[O_XBCC + l*1280 + 1088 + lane];
    float c0 = W[O_XBCC + l*1280 + 1152 + lane];
    float c1 = W[O_XBCC + l*1280 + 1216 + lane];
    float du = dt*xv;
    s0 = s0*dA + du*b0;
    s1 = s1*dA + du*b1;
    float part = s0*c0 + s1*c1;
    for (int off=32; off; off>>=1) part += __shfl_xor(part, off, 64);
    if (lane == 0) W[O_TPRE + l*1024 + h*64 + pp] = part + Dv*xv;
  }
}

__global__ void k_gaterms(float* __restrict__ W){
  int l = blockIdx.x, t = threadIdx.x;
  float vals[4]; float ss = 0.f;
  for (int q=0; q<4; ++q){
    int c = t + q*256;
    float z = W[O_ZX + l*2320 + c];
    float y = W[O_TPRE + l*1024 + c];
    float v = y * siluf(z);
    vals[q] = v; ss += v*v;
  }
  for (int off=32; off; off>>=1) ss += __shfl_xor(ss, off, 64);
  __shared__ float sm[4];
  if ((t & 63) == 0) sm[t>>6] = ss;
  __syncthreads();
  float tot = sm[0]+sm[1]+sm[2]+sm[3];
  float r = rsqrtf(tot/1024.f + 1e-5f);
  for (int q=0; q<4; ++q){
    int c = t + q*256;
    W[O_TG + l*1024 + c] = vals[q]*r*W[I_MNORMW + c];
  }
}

__global__ void k_outmf(float* __restrict__ W){
  int d = blockIdx.x;
  int t = threadIdx.x, l = t & 31, kc = t >> 5;
  __shared__ float wrow[1024];
  for (int idx = t; idx < 1024; idx += 256) wrow[idx] = W[I_MOUTW + (long long)d*1024 + idx];
  __syncthreads();
  float acc = 0.f;
  const float* tg = W + O_TG + l*1024;
  for (int c = kc*128; c < kc*128 + 128; ++c) acc += tg[c]*wrow[c];
  __shared__ float red[256];
  red[t] = acc; __syncthreads();
  if (kc == 0){
    float s = 0.f;
    #pragma unroll
    for (int q=0;q<8;++q) s += red[l + q*32];
    W[O_OUTM + l*512 + d] = s;
  }
}

// =============== stage C: c1 ===============
__global__ void k_c1f(float* __restrict__ W){
  int o = blockIdx.x;
  int t = threadIdx.x, l = t & 31, kc = t >> 5;
  __shared__ float wrow[1536];
  for (int idx = t; idx < 1536; idx += 256) wrow[idx] = W[I_C1W + (long long)o*1536 + idx];
  __syncthreads();
  float acc = 0.f;
  for (int ii = kc*64; ii < kc*64 + 64; ++ii){
    #pragma unroll
    for (int j=0;j<3;++j){
      int p = l-1+j;
      if (p >= 0 && p < 32) acc += W[O_OUTM + p*512 + ii] * wrow[ii*3+j];
    }
  }
  __shared__ float red[256];
  red[t] = acc; __syncthreads();
  if (kc == 0){
    float s = W[I_C1B + o];
    #pragma unroll
    for (int q=0;q<8;++q) s += red[l + q*32];
    W[O_Y1 + o*32 + l] = s;
  }
}

// =============== vssblock 1 ===============
__global__ void k_ln1(float* __restrict__ W){
  int l = blockIdx.x*256 + threadIdx.x; if (l >= 1024) return;
  float s = 0.f, s2 = 0.f;
  for (int c=0; c<32; ++c){ float v = W[O_Y1 + l*32 + c]; s += v; s2 += v*v; }
  float mu = s/32.f, var = s2/32.f - mu*mu, rs = rsqrtf(var + 1e-5f);
  for (int c=0; c<32; ++c){
    float v = W[O_Y1 + l*32 + c];
    W[O_H1 + l*32 + c] = (v-mu)*rs*W[I_V1LNW + c] + W[I_V1LNB + c];
  }
}

__global__ void k_xz1(float* __restrict__ W){
  int i = blockIdx.x*256 + threadIdx.x; if (i >= 1024*128) return;
  int l = i >> 7, j = i & 127;
  float acc = 0.f;
  for (int c=0; c<32; ++c) acc += W[O_H1 + l*32 + c] * W[I_V1INW + j*32 + c];
  W[O_XZ1 + i] = acc;
}

__global__ void k_dwcs1(float* __restrict__ W){
  int i = blockIdx.x*256 + threadIdx.x; if (i >= 64*1024) return;
  int ch = i >> 10, pix = i & 1023, a = pix >> 5, b = pix & 31;
  float acc = W[I_V1CONVB + ch];
  for (int dy=0; dy<3; ++dy){
    int aa = a+dy-1; if (aa < 0 || aa > 31) continue;
    for (int dx=0; dx<3; ++dx){
      int bb = b+dx-1; if (bb < 0 || bb > 31) continue;
      acc += W[O_XZ1 + (aa*32+bb)*128 + ch] * W[I_V1CONVW + ch*9 + dy*3 + dx];
    }
  }
  W[O_XC1 + i] = siluf(acc);
}

__global__ void k_dbl1(float* __restrict__ W){
  int i = blockIdx.x*256 + threadIdx.x; if (i >= 4*34*1024) return;
  int k = i / 34816, r = i % 34816, c = r / 1024, l = r % 1024;
  float acc = 0.f;
  for (int d=0; d<64; ++d) acc += W[O_XC1 + d*1024 + l] * W[I_V1XPW + (k*34+c)*64 + d];
  W[O_DBL1 + (k*34+c)*1024 + l] = acc;
}

__global__ void k_comb1(float* __restrict__ W){
  int l = blockIdx.x, dch = threadIdx.x;
  int t1 = ((l & 31) << 5) | (l >> 5);
  const __half* Y = (const __half*)(W + O_YS1);
  float x = __half2float(Y[l*256 + dch])
          + __half2float(Y[t1*256 + 64 + dch])
          + __half2float(Y[(1023-l)*256 + 128 + dch])
          + __half2float(Y[(1023-t1)*256 + 192 + dch]);
  float s = x, s2 = x*x;
  for (int off=32; off; off>>=1){ s += __shfl_xor(s, off, 64); s2 += __shfl_xor(s2, off, 64); }
  float mu = s/64.f, var = s2/64.f - mu*mu, rs = rsqrtf(var + 1e-5f);
  float yn = (x-mu)*rs*W[I_V1ONW + dch] + W[I_V1ONB + dch];
  float z = W[O_XZ1 + l*128 + 64 + dch];
  W[O_G1 + l*64 + dch] = yn * siluf(z);
}

__global__ void k_oproj1(float* __restrict__ W){
  int i = blockIdx.x*256 + threadIdx.x; if (i >= 1024*32) return;
  int l = i >> 5, c = i & 31;
  float acc = W[O_Y1 + i];
  for (int d=0; d<64; ++d) acc += W[O_G1 + l*64 + d] * W[I_V1OUTW + c*64 + d];
  W[O_OUTD + i] = acc;
}

// =============== stage E: conv stack ===============
__global__ void k_dw1(float* __restrict__ W){
  int i = blockIdx.x*256 + threadIdx.x; if (i >= 32*1024) return;
  int c = i >> 10, pix = i & 1023, a = pix >> 5, b = pix & 31;
  float acc = W[I_DW1B + c];
  for (int dy=0; dy<3; ++dy){
    int aa = a+dy-1; if (aa < 0 || aa > 31) continue;
    for (int dx=0; dx<3; ++dx){
      int bb = b+dx-1; if (bb < 0 || bb > 31) continue;
      acc += W[O_OUTD + (aa*32+bb)*32 + c] * W[I_DW1W + c*9 + dy*3 + dx];
    }
  }
  W[O_E1 + i] = acc;
}

__global__ void k_pw1(float* __restrict__ W){
  int i = blockIdx.x*256 + threadIdx.x; if (i >= 64*1024) return;
  int o = i >> 10, pix = i & 1023;
  float acc = W[I_PW1B + o];
  for (int c=0; c<32; ++c) acc += W[I_PW1W + o*32 + c] * W[O_E1 + c*1024 + pix];
  W[O_E2 + i] = acc;
}

__global__ void k_dw2(float* __restrict__ W){
  int i = blockIdx.x*256 + threadIdx.x; if (i >= 64*1024) return;
  int c = i >> 10, pix = i & 1023, a = pix >> 5, b = pix & 31;
  float acc = W[I_DW2B + c];
  for (int dy=0; dy<3; ++dy){
    int aa = a+dy-1; if (aa < 0 || aa > 31) continue;
    for (int dx=0; dx<3; ++dx){
      int bb = b+dx-1; if (bb < 0 || bb > 31) continue;
      acc += W[O_E2 + c*1024 + aa*32 + bb] * W[I_DW2W + c*9 + dy*3 + dx];
    }
  }
  W[O_E3 + i] = acc;
}

__global__ void k_pw2(float* __restrict__ W){
  int i = blockIdx.x*256 + threadIdx.x; if (i >= 128*1024) return;
  int o = i >> 10, pix = i & 1023;
  float acc = W[I_PW2B + o];
  for (int c=0; c<64; ++c) acc += W[I_PW2W + o*64 + c] * W[O_E3 + c*1024 + pix];
  W[O_E4 + i] = acc;
}

DEV void rs_coef(int o, int n, int& i0, int& i1, float& w0, float& w1){
  float src = 0.5f*(float)o - 0.25f;
  float f = floorf(src);
  float fr = src - f;
  int a = (int)f;
  if (a < 0){ i0 = 0; i1 = 0; w0 = 0.f; w1 = 1.f; }
  else if (a >= n-1){ i0 = n-1; i1 = n-1; w0 = 1.f; w1 = 0.f; }
  else { i0 = a; i1 = a+1; w0 = 1.f-fr; w1 = fr; }
}

__global__ void k_resize(float* __restrict__ W){
  int i = blockIdx.x*256 + threadIdx.x; if (i >= 128*4096) return;
  int c = i >> 12, pix = i & 4095, y = pix >> 6, x = pix & 63;
  int iy0, iy1, ix0, ix1; float wy0, wy1, wx0, wx1;
  rs_coef(y, 32, iy0, iy1, wy0, wy1);
  rs_coef(x, 32, ix0, ix1, wx0, wx1);
  const float* in = W + O_E4 + c*1024;
  float v = wy0*(wx0*in[iy0*32+ix0] + wx1*in[iy0*32+ix1])
          + wy1*(wx0*in[iy1*32+ix0] + wx1*in[iy1*32+ix1]);
  W[O_E5 + i] = v;
}

// =============== stage F: vssblock2 ===============
__global__ void k_ln2(float* __restrict__ W){
  int l = blockIdx.x, t = threadIdx.x;
  float v0 = W[O_E8 + (long long)t*4096 + l];
  float v1 = W[O_E8 + (long long)(t+256)*4096 + l];
  float s = v0+v1, s2 = v0*v0 + v1*v1;
  for (int off=32; off; off>>=1){ s += __shfl_xor(s, off, 64); s2 += __shfl_xor(s2, off, 64); }
  __shared__ float a[4], b[4];
  if ((t & 63) == 0){ a[t>>6] = s; b[t>>6] = s2; }
  __syncthreads();
  float S = a[0]+a[1]+a[2]+a[3], S2 = b[0]+b[1]+b[2]+b[3];
  float mu = S/512.f, var = S2/512.f - mu*mu, rs = rsqrtf(var + 1e-5f);
  unsigned short* H = (unsigned short*)(W + O_LN2);
  H[(long long)l*512 + t]     = f2bf((v0-mu)*rs*W[I_V2LNW + t]     + W[I_V2LNB + t]);
  H[(long long)l*512 + t+256] = f2bf((v1-mu)*rs*W[I_V2LNW + t+256] + W[I_V2LNB + t+256]);
}

__global__ void k_dwcs2(float* __restrict__ W){
  long long i = (long long)blockIdx.x*256 + threadIdx.x;
  int ch = (int)(i >> 12), pix = (int)(i & 4095), a = pix >> 6, b = pix & 63;
  float acc = W[I_V2CONVB + ch];
  const float* xp = W + O_XT2 + (long long)ch*4096;
  for (int dy=0; dy<3; ++dy){
    int aa = a+dy-1; if (aa < 0 || aa > 63) continue;
    for (int dx=0; dx<3; ++dx){
      int bb = b+dx-1; if (bb < 0 || bb > 63) continue;
      acc += xp[aa*64+bb] * W[I_V2CONVW + ch*9 + dy*3 + dx];
    }
  }
  W[O_XC2 + i] = siluf(acc);
}

__global__ void k_comb2(float* __restrict__ W){
  int l = blockIdx.x, t = threadIdx.x;
  int t1 = ((l & 63) << 6) | (l >> 6);
  const __half* Y = (const __half*)(W + O_YS2);
  float v[4]; float s = 0.f, s2 = 0.f;
  for (int q=0; q<4; ++q){
    int dch = t + q*256;
    float x = __half2float(Y[(long long)l*4096 + dch])
            + __half2float(Y[(long long)t1*4096 + 1024 + dch])
            + __half2float(Y[(long long)(4095-l)*4096 + 2048 + dch])
            + __half2float(Y[(long long)(4095-t1)*4096 + 3072 + dch]);
    v[q] = x; s += x; s2 += x*x;
  }
  for (int off=32; off; off>>=1){ s += __shfl_xor(s, off, 64); s2 += __shfl_xor(s2, off, 64); }
  __shared__ float a[4], b[4];
  if ((t & 63) == 0){ a[t>>6] = s; b[t>>6] = s2; }
  __syncthreads();
  float S = a[0]+a[1]+a[2]+a[3], S2 = b[0]+b[1]+b[2]+b[3];
  float mu = S/1024.f, var = S2/1024.f - mu*mu, rs = rsqrtf(var + 1e-5f);
  unsigned short* G = (unsigned short*)(W + O_G2);
  for (int q=0; q<4; ++q){
    int dch = t + q*256;
    float yn = (v[q]-mu)*rs*W[I_V2ONW + dch] + W[I_V2ONB + dch];
    float z = W[O_XZ2 + (long long)l*2048 + 1024 + dch];
    G[(long long)l*1024 + dch] = f2bf(yn * siluf(z));
  }
}

// =============== launch ===============
extern "C" void kernel_launch(void* const* d_in, const int* in_sizes, int n_in,
                              void* d_out, int out_size, void* d_ws, size_t ws_size,
                              hipStream_t stream){
  if (ws_size < (size_t)WS_FLOATS * sizeof(float)) return;
  float* W = (float*)d_ws;
  PtrTab tab;
  for (int i=0; i<53; ++i) tab.p[i] = d_in[i];
  const unsigned int* flagp = (const unsigned int*)d_in[9];

  k_ingest<<<INGEST_BLOCKS, 256, 0, stream>>>(tab, W);
  // bf16 weight conversions (depend only on ingest)
  k_tobf16<<<4096, 256, 0, stream>>>(W + I_V2INW,  (unsigned short*)(W + O_W2INB), 2048*512);
  k_tobf16<<<1024, 256, 0, stream>>>(W + I_V2XPW,  (unsigned short*)(W + O_XPWB),  256*1024);
  k_tobf16<<<2048, 256, 0, stream>>>(W + I_V2OUTW, (unsigned short*)(W + O_OUTWB), 512*1024);
  k_tobf16<<<128, 256, 0, stream>>>(W + I_CV2W,    (unsigned short*)(W + O_CV2WB), 256*128);
  k_wpack<128><<<576, 256, 0, stream>>>(W + I_CV1W, (unsigned short*)(W + O_CV1WB), 128);
  k_wpack<256><<<4608, 256, 0, stream>>>(W + I_FCW, (unsigned short*)(W + O_FCW2), 512);

  k_c0    <<<64, 256, 0, stream>>>(W);
  k_zxf   <<<2320, 256, 0, stream>>>(W);
  k_conv4 <<<160, 256, 0, stream>>>(W);
  k_dtm   <<<2, 256, 0, stream>>>(W);
  k_mscan <<<1024, 64, 0, stream>>>(W);
  k_gaterms<<<32, 256, 0, stream>>>(W);
  k_outmf <<<512, 256, 0, stream>>>(W);
  k_c1f   <<<1024, 256, 0, stream>>>(W);
  k_ln1   <<<4, 256, 0, stream>>>(W);
  k_xz1   <<<512, 256, 0, stream>>>(W);
  k_dwcs1 <<<256, 256, 0, stream>>>(W);
  k_dbl1  <<<544, 256, 0, stream>>>(W);
  // vss1 chunked scan
  k_transpose<<<dim3(32, 2), 256, 0, stream>>>(W + O_XC1, W + O_XT1, 64, 1024, 1024, 64);
  k_scan_p1<64,64,1024,5,64,2,34,40,4><<<dim3(4,16), 64, 0, stream>>>(W, O_DBL1, O_XT1, O_P1, O_S1,
                                                                 I_V1DTW, I_V1DTB, I_V1ALOG);
  k_carry<4096,16><<<16, 256, 0, stream>>>(W, O_P1, O_S1);
  k_scan_p3<64,64,1024,5,64,2,34,40,4><<<dim3(4,16), 64, 0, stream>>>(W, O_DBL1, O_XT1, O_S1, O_YS1,
                                                                 I_V1DTW, I_V1DTB, I_V1ALOG, I_V1D);
  k_comb1 <<<1024, 64, 0, stream>>>(W);
  k_oproj1<<<128, 256, 0, stream>>>(W);
  k_dw1   <<<128, 256, 0, stream>>>(W);
  k_pw1   <<<256, 256, 0, stream>>>(W);
  k_dw2   <<<256, 256, 0, stream>>>(W);
  k_pw2   <<<512, 256, 0, stream>>>(W);
  k_resize<<<2048, 256, 0, stream>>>(W);
  // cv1 via MFMA: E5 -> E5T(bf16) -> im2col -> GEMM(+bias) -> E6 f32 [c][pix]
  k_transpose_dual<<<dim3(128, 4), 256, 0, stream>>>(W + O_E5, nullptr,
                      (unsigned short*)(W + O_E5TB), 128, 4096, 4096, 128);
  k_im2colT<128><<<dim3(5, 4096), 256, 0, stream>>>((const unsigned short*)(W + O_E5TB),
                      (unsigned short*)(W + O_CV1B2));
  k_gemm_bt<1><<<dim3(1, 32), 256, 0, stream>>>((const unsigned short*)(W + O_CV1WB),
                      (const unsigned short*)(W + O_CV1B2), 1152, 4096,
                      W + O_E6, W + I_CV1B, nullptr, nullptr, nullptr);
  // cv2 via MFMA: E6 -> E6T(bf16) -> GEMM(+bias) -> E7 f32 [ch][pix]
  k_transpose_dual<<<dim3(128, 4), 256, 0, stream>>>(W + O_E6, nullptr,
                      (unsigned short*)(W + O_E6TB), 128, 4096, 4096, 128);
  k_gemm_bt<1><<<dim3(2, 32), 256, 0, stream>>>((const unsigned short*)(W + O_CV2WB),
                      (const unsigned short*)(W + O_E6TB), 128, 4096,
                      W + O_E7, W + I_CV2B, nullptr, nullptr, nullptr);
  // fc via MFMA: E7 -> E7T(bf16) -> im2col B2 -> GEMM(+bias) -> E8
  k_transpose_dual<<<dim3(128, 8), 256, 0, stream>>>(W + O_E7, nullptr,
                      (unsigned short*)(W + O_E7T), 256, 4096, 4096, 256);
  k_im2colT<256><<<dim3(9, 4096), 256, 0, stream>>>((const unsigned short*)(W + O_E7T),
                      (unsigned short*)(W + O_B2));
  k_gemm_bt<1><<<dim3(4, 32), 256, 0, stream>>>((const unsigned short*)(W + O_FCW2),
                      (const unsigned short*)(W + O_B2), 2304, 4096,
                      W + O_E8, W + I_FCB, nullptr, nullptr, nullptr);
  // vss2
  k_ln2   <<<4096, 256, 0, stream>>>(W);
  k_gemm_bt<0><<<dim3(32, 16), 256, 0, stream>>>((const unsigned short*)(W + O_LN2),
                      (const unsigned short*)(W + O_W2INB), 512, 2048,
                      W + O_XZ2, nullptr, nullptr, nullptr, nullptr);
  k_transpose<<<dim3(32, 128), 256, 0, stream>>>(W + O_XZ2, W + O_XT2, 4096, 1024, 2048, 4096); // XP[ch][pix]
  k_dwcs2 <<<16384, 256, 0, stream>>>(W);
  k_transpose_dual<<<dim3(128, 32), 256, 0, stream>>>(W + O_XC2, W + O_XT2,
                      (unsigned short*)(W + O_XT2B), 1024, 4096, 4096, 1024); // XT[pix][ch] f32+bf16
  // dbl2 as one GEMM: G[256][4096] = XPW x XT2B (pixel-major)
  k_gemm_bt<0><<<dim3(2, 32), 256, 0, stream>>>((const unsigned short*)(W + O_XPWB),
                      (const unsigned short*)(W + O_XT2B), 1024, 4096,
                      W + O_DBL2, nullptr, nullptr, nullptr, nullptr);
  k_scan_p1<1024,256,4096,6,64,32,64,68,32><<<dim3(16,64), 256, 0, stream>>>(W, O_DBL2, O_XT2, O_P2, O_S2,
                                                                       I_V2DTW, I_V2DTB, I_V2ALOG);
  k_carry<65536,64><<<256, 256, 0, stream>>>(W, O_P2, O_S2);
  k_scan_p3<1024,256,4096,6,64,32,64,68,32><<<dim3(16,64), 256, 0, stream>>>(W, O_DBL2, O_XT2, O_S2, O_YS2,
                                                                       I_V2DTW, I_V2DTB, I_V2ALOG, I_V2D);
  k_comb2 <<<4096, 256, 0, stream>>>(W);
  k_gemm_bt<2><<<dim3(4, 32), 256, 0, stream>>>((const unsigned short*)(W + O_OUTWB),
                      (const unsigned short*)(W + O_G2), 1024, 4096,
                      nullptr, nullptr, W + O_E8, flagp, d_out);
}

// Round 9
// 986.161 us; speedup vs baseline: 6.9921x; 1.0219x over previous
//
#include <hip/hip_runtime.h>
#include <hip/hip_bf16.h>
#include <hip/hip_fp16.h>
#include <math.h>

#define DEV static __device__ __forceinline__

DEV float siluf(float x){ return x / (1.f + expf(-x)); }
DEV float softplusf(float x){ return (x > 20.f) ? x : log1pf(__expf(x)); }

DEV unsigned short f2bf(float f){
  unsigned int u = __float_as_uint(f);
  unsigned int r = (u + 0x7FFFu + ((u >> 16) & 1u)) >> 16;
  return (unsigned short)r;
}

using bf16x8 = __attribute__((ext_vector_type(8))) short;
using u16x8  = __attribute__((ext_vector_type(8))) unsigned short;
using f32x4  = __attribute__((ext_vector_type(4))) float;

// ---------------- input arena offsets (floats) ----------------
constexpr long long I_LD=0, I_C0W=9216, I_C0B=10944, I_MINW=10976, I_MCONVW=1198816,
 I_MCONVB=1203936, I_MDTB=1205216, I_MALOG=1205232, I_MD=1205248, I_MNORMW=1205264,
 I_MOUTW=1206288, I_C1W=1730576, I_C1B=3303440, I_V1LNW=3304464, I_V1LNB=3304496,
 I_V1INW=3304528, I_V1CONVW=3308624, I_V1CONVB=3309200, I_V1XPW=3309264, I_V1DTW=3317968,
 I_V1DTB=3318480, I_V1ALOG=3318736, I_V1D=3322832, I_V1ONW=3323088, I_V1ONB=3323152,
 I_V1OUTW=3323216, I_DW1W=3325264, I_DW1B=3325552, I_PW1W=3325584, I_PW1B=3327632,
 I_DW2W=3327696, I_DW2B=3328272, I_PW2W=3328336, I_PW2B=3336528, I_CV1W=3336656,
 I_CV1B=3484112, I_CV2W=3484240, I_CV2B=3517008, I_FCW=3517264, I_FCB=4696912,
 I_V2LNW=4697424, I_V2LNB=4697936, I_V2INW=4698448, I_V2CONVW=5747024, I_V2CONVB=5756240,
 I_V2XPW=5757264, I_V2DTW=6019408, I_V2DTB=6150480, I_V2ALOG=6154576, I_V2D=6220112,
 I_V2ONW=6224208, I_V2ONB=6225232, I_V2OUTW=6226256;
constexpr long long TOTAL_IN = 6750544;
constexpr int INGEST_BLOCKS = (int)((TOTAL_IN + 255) / 256);
constexpr long long O_E8 = 6750544;                // (512,4096) f32, lives to the end
constexpr long long SCR  = 8847696;
// phase 1 (stages A-E)
constexpr long long O_X0=SCR+0, O_ZX=SCR+16384, O_XBCC=SCR+90624, O_DTM=SCR+131584,
 O_TPRE=SCR+132096, O_TG=SCR+164864, O_OUTM=SCR+197632, O_Y1=SCR+214016, O_H1=SCR+246784,
 O_XZ1=SCR+279552, O_XC1=SCR+410624, O_DBL1=SCR+476160, O_YS1=SCR+615424, O_G1=SCR+877568,
 O_OUTD=SCR+943104, O_E1=SCR+975872, O_E2=SCR+1008640, O_E3=SCR+1074176, O_E4=SCR+1139712,
 O_E5=SCR+1270784, O_E6=SCR+1795072, O_E7=SCR+2319360;
// vss1 scan scratch
constexpr long long O_XT1=SCR+3367936, O_P1=SCR+3433472, O_S1=SCR+3499008;   // S1 ends 3564544
// free gap 3564544..4000000
constexpr long long O_CV2WB=SCR+3564544;  // 256x128 bf16 = 16384 slots, ends 3580928
constexpr long long O_CV1WB=SCR+3580928;  // 128x1152 bf16 = 73728 slots, ends 3654656
// fc/cv MFMA scratch (phase-1 tail; dead before XZ2 is written)
constexpr long long O_FCW2=SCR+4000000;   // 512x2304 bf16 (589824 slots, ends 4589824)
constexpr long long O_E7T =SCR+4600000;   // 4096x256 bf16 (524288 slots, ends 5124288)
constexpr long long O_E6TB=O_E7T;         // sequential reuse
constexpr long long O_E5TB=O_E7T;         // sequential reuse (cv1, earliest)
constexpr long long O_B2  =SCR+5242880;   // 4096x2304 bf16 (4718592 slots, ends 9961472)
constexpr long long O_CV1B2=O_B2;         // 4096x1152 bf16 — used before fc's B2
// phase 2 (stage F)
constexpr long long O_XZ2=SCR+0;                        // 4096x2048 f32 (ends 8388608)
constexpr long long O_XC2=SCR+8388608;                  // 1024x4096 f32 (dead after dual transpose)
constexpr long long O_P2 =O_XC2;                        // overlay: P written in scan pass 1
constexpr long long O_XT2=SCR+12582912;                 // XP[ch][pix] f32, then XT[pix][ch] f32
constexpr long long O_G2 =O_XT2;                        // overlay: bf16 G2 (comb2 out, XT2 dead)
constexpr long long O_DBL2=SCR+16777216;                // G[256][4096] f32 (ends 17825792)
constexpr long long O_S2 =SCR+17825792;                 // (ends 22020096)
constexpr long long O_YS2=SCR+22020096;                 // fp16 ys (ends 30408704)
constexpr long long O_LN2=SCR+30408704;                 // bf16 LN2 (524288 slots, ends 31457280)
// bf16 weights / staging (top region, no overlap)
constexpr long long O_W2INB=SCR+32505856;               // ends 33030144
constexpr long long O_XPWB =SCR+33030144;               // ends 33161216
constexpr long long O_OUTWB=SCR+33161216;               // ends 33423360
constexpr long long O_XT2B =SCR+33423360;               // ends 35520512
constexpr long long WS_FLOATS = SCR + 36700160;

struct PtrTab { const void* p[53]; };

__constant__ long long c_inoff[53] = { 0, 9216, 10944, 10976, 1198816, 1203936, 1205216,
 1205232, 1205248, 1205264, 1206288, 1730576, 3303440, 3304464, 3304496, 3304528, 3308624,
 3309200, 3309264, 3317968, 3318480, 3318736, 3322832, 3323088, 3323152, 3323216, 3325264,
 3325552, 3325584, 3327632, 3327696, 3328272, 3328336, 3336528, 3336656, 3484112, 3484240,
 3517008, 3517264, 4696912, 4697424, 4697936, 4698448, 5747024, 5756240, 5757264, 6019408,
 6150480, 6154576, 6220112, 6224208, 6225232, 6226256 };

DEV int scan_addr(int k, int l, int lg, int Lm1){
  int p = (k & 2) ? (Lm1 - l) : l;
  int mask = (1 << lg) - 1;
  if (k & 1) p = ((p & mask) << lg) | (p >> lg);
  return p;
}

// =============== ingest ===============
__global__ void k_ingest(PtrTab t, float* __restrict__ W){
  long long idx = (long long)blockIdx.x*256 + threadIdx.x;
  if (idx >= TOTAL_IN) return;
  int j = 0;
  #pragma unroll
  for (int q=1; q<53; ++q) if (idx >= c_inoff[q]) j = q;
  int local = (int)(idx - c_inoff[j]);
  bool bf = (*(const unsigned int*)t.p[9]) == 0x3F803F80u;
  float v;
  if (bf){
    unsigned short u = ((const unsigned short*)t.p[j])[local];
    v = __uint_as_float(((unsigned int)u) << 16);
  } else {
    v = ((const float*)t.p[j])[local];
  }
  W[idx] = v;
}

// =============== merged weight prep: all bf16 conversions in one kernel ===============
// segs: 0 W2INB 1048576 | 1 XPWB 262144 | 2 OUTWB 524288 | 3 CV2WB 32768
//       4 CV1WB wpack(128,128) 147456 | 5 FCW2 wpack(256,512) 1179648   total 3194880
__global__ void k_prep(float* __restrict__ W){
  long long i = (long long)blockIdx.x*256 + threadIdx.x;
  if (i < 1048576){
    ((unsigned short*)(W + O_W2INB))[i] = f2bf(W[I_V2INW + i]);
  } else if (i < 1310720){
    long long d = i - 1048576;
    ((unsigned short*)(W + O_XPWB))[d] = f2bf(W[I_V2XPW + d]);
  } else if (i < 1835008){
    long long d = i - 1310720;
    ((unsigned short*)(W + O_OUTWB))[d] = f2bf(W[I_V2OUTW + d]);
  } else if (i < 1867776){
    long long d = i - 1835008;
    ((unsigned short*)(W + O_CV2WB))[d] = f2bf(W[I_CV2W + d]);
  } else if (i < 2015232){
    long long d = i - 1867776;
    int c = (int)(d / 1152), r = (int)(d % 1152), tap = r / 128, i2 = r % 128;
    ((unsigned short*)(W + O_CV1WB))[d] = f2bf(W[I_CV1W + ((long long)(c*128 + i2))*9 + tap]);
  } else if (i < 3194880){
    long long d = i - 2015232;
    int c = (int)(d / 2304), r = (int)(d % 2304), tap = r / 256, i2 = r % 256;
    ((unsigned short*)(W + O_FCW2))[d] = f2bf(W[I_FCW + ((long long)(c*256 + i2))*9 + tap]);
  }
}

// im2col: B2[p][tap*CIN+d] = XT[p shifted by tap][d] (0 if OOB), 64x64 image
template<int CIN>
__global__ void k_im2colT(const unsigned short* __restrict__ XT, unsigned short* __restrict__ B2){
  int r = blockIdx.x*256 + threadIdx.x;
  if (r >= 9*CIN) return;
  int p = blockIdx.y;
  int tap = r / CIN, d = r % CIN;
  int dy = tap/3 - 1, dx = tap%3 - 1;
  int y = p >> 6, x = p & 63;
  int yy = y + dy, xx = x + dx;
  unsigned short v = 0;
  if (yy >= 0 && yy < 64 && xx >= 0 && xx < 64) v = XT[(long long)(yy*64+xx)*CIN + d];
  B2[(long long)p*(9*CIN) + r] = v;
}

// =============== transposes ===============
__global__ void k_transpose(const float* __restrict__ in, float* __restrict__ out,
                            int rows, int cols, long long instride, long long outstride){
  __shared__ float tile[32][33];
  int tx = threadIdx.x & 31, ty = threadIdx.x >> 5;
  long long c0 = (long long)blockIdx.x*32, r0 = (long long)blockIdx.y*32;
  #pragma unroll
  for (int i=0;i<32;i+=8){
    long long r = r0 + ty + i, c = c0 + tx;
    if (r < rows && c < cols) tile[ty+i][tx] = in[r*instride + c];
  }
  __syncthreads();
  #pragma unroll
  for (int i=0;i<32;i+=8){
    long long r = r0 + tx, c = c0 + ty + i;
    if (r < rows && c < cols) out[c*outstride + r] = tile[tx][ty+i];
  }
}

__global__ void k_transpose_dual(const float* __restrict__ in, float* __restrict__ outF,
                                 unsigned short* __restrict__ outB,
                                 int rows, int cols, long long instride, long long outstride){
  __shared__ float tile[32][33];
  int tx = threadIdx.x & 31, ty = threadIdx.x >> 5;
  long long c0 = (long long)blockIdx.x*32, r0 = (long long)blockIdx.y*32;
  #pragma unroll
  for (int i=0;i<32;i+=8){
    long long r = r0 + ty + i, c = c0 + tx;
    if (r < rows && c < cols) tile[ty+i][tx] = in[r*instride + c];
  }
  __syncthreads();
  #pragma unroll
  for (int i=0;i<32;i+=8){
    long long r = r0 + tx, c = c0 + ty + i;
    if (r < rows && c < cols){
      float v = tile[tx][ty+i];
      if (outF) outF[c*outstride + r] = v;
      outB[c*outstride + r] = f2bf(v);
    }
  }
}

// =============== bf16 MFMA GEMM: C[m][n] = sum_k A[m][k]*B[n][k] ===============
template<int MODE>
__global__ __launch_bounds__(256)
void k_gemm_bt(const unsigned short* __restrict__ A, const unsigned short* __restrict__ B,
               int K, int N, float* __restrict__ Cout, const float* __restrict__ bias,
               const float* __restrict__ res, const unsigned int* flagp, void* dout){
  constexpr int LDK = 72;  // 64 + 8 pad
  __shared__ unsigned short As[128*LDK], Bs[128*LDK];
  int m0 = blockIdx.x*128, n0 = blockIdx.y*128;
  int tid = threadIdx.x;
  int wave = tid >> 6, lane = tid & 63, quad = lane >> 4, l16 = lane & 15;
  int wm = wave >> 1, wn = wave & 1;
  f32x4 acc[4][4];
  #pragma unroll
  for (int a=0;a<4;++a)
    #pragma unroll
    for (int b=0;b<4;++b) acc[a][b] = (f32x4){0.f,0.f,0.f,0.f};
  int srow = tid >> 1, shalf = (tid & 1)*32;
  for (int kt = 0; kt < K; kt += 64){
    const u16x8* ga = (const u16x8*)(A + (long long)(m0+srow)*K + kt + shalf);
    const u16x8* gb = (const u16x8*)(B + (long long)(n0+srow)*K + kt + shalf);
    u16x8* da = (u16x8*)&As[srow*LDK + shalf];
    u16x8* db = (u16x8*)&Bs[srow*LDK + shalf];
    #pragma unroll
    for (int c=0;c<4;++c){ da[c] = ga[c]; db[c] = gb[c]; }
    __syncthreads();
    #pragma unroll
    for (int ks=0; ks<64; ks+=32){
      bf16x8 af[4], bfr[4];
      #pragma unroll
      for (int mi=0;mi<4;++mi)
        af[mi] = *(const bf16x8*)&As[(wm*64 + mi*16 + l16)*LDK + ks + quad*8];
      #pragma unroll
      for (int ni=0;ni<4;++ni)
        bfr[ni] = *(const bf16x8*)&Bs[(wn*64 + ni*16 + l16)*LDK + ks + quad*8];
      #pragma unroll
      for (int mi=0;mi<4;++mi)
        #pragma unroll
        for (int ni=0;ni<4;++ni)
          acc[mi][ni] = __builtin_amdgcn_mfma_f32_16x16x32_bf16(af[mi], bfr[ni], acc[mi][ni], 0, 0, 0);
    }
    __syncthreads();
  }
  bool bf = (MODE == 2) ? ((*flagp) == 0x3F803F80u) : false;
  #pragma unroll
  for (int mi=0;mi<4;++mi){
    #pragma unroll
    for (int ni=0;ni<4;++ni){
      #pragma unroll
      for (int r=0;r<4;++r){
        int m = m0 + wm*64 + mi*16 + quad*4 + r;
        int n = n0 + wn*64 + ni*16 + l16;
        float v = acc[mi][ni][r];
        if (MODE == 1) v += bias[m];
        if (MODE == 2){
          v += res[(long long)m*N + n];
          if (bf) ((unsigned short*)dout)[(long long)m*N + n] = f2bf(v);
          else    ((float*)dout)[(long long)m*N + n] = v;
        } else {
          Cout[(long long)m*N + n] = v;
        }
      }
    }
  }
}

// =============== chunked selective-scan (3 passes) ===============
// stage[j][slot]: dt r -> r, B n -> BOFF+n, C n -> BOFF+16+n.
// Sigmoid identity: q = exp(-softplus(x)) = 1/(1+e^x)  [exact]; log-depth powers.
template<int DCH, int TD, int L, int LG, int T, int R, int CROWS, int STRIDE, int BOFF>
__global__ void k_scan_p1(float* __restrict__ W, long long o_dbl, long long o_xt,
                          long long o_p, long long o_s,
                          long long i_dtw, long long i_dtb, long long i_alog){
  constexpr int NT = DCH/TD;
  int k = blockIdx.x / NT, tile = blockIdx.x % NT;
  int c = blockIdx.y;
  int t = threadIdx.x;
  int dch = tile*TD + t;
  __shared__ __align__(16) float stage[T*STRIDE];
  const float* dbl = W + o_dbl + (long long)k*CROWS*L;
  const int Lm1 = L-1, mask = (1<<LG)-1;
  for (int idx = t; idx < CROWS*T; idx += TD){
    int row = idx / T, col = idx % T;
    int l = c*T + col;
    int cc = scan_addr(k, l, LG, Lm1);
    int slot = (row < R) ? row : (BOFF + row - R);
    stage[col*STRIDE + slot] = dbl[(long long)row*L + cc];
  }
  __syncthreads();
  float w[R], A[16], s[16];
  #pragma unroll
  for (int r=0;r<R;++r) w[r] = W[i_dtw + (long long)(k*DCH+dch)*R + r];
  float bias = W[i_dtb + k*DCH + dch];
  bool pat = true;
  #pragma unroll
  for (int n=0;n<16;++n){
    A[n] = -expf(W[i_alog + (long long)(k*DCH+dch)*16 + n]);
    pat = pat && (fabsf(A[n] + (float)(n+1)) <= 1e-3f*(float)(n+1));
    s[n] = 0.f;
  }
  const float* XT = W + o_xt;
  float dtsum = 0.f;
  for (int j=0;j<T;++j){
    int l = c*T + j;
    int p_ = (k&2)? (Lm1-l) : l;
    int ua = (k&1)? (((p_&mask)<<LG)|(p_>>LG)) : p_;
    float u = XT[(long long)ua*DCH + dch];
    float x = bias;
    if (R == 2){
      x += stage[j*STRIDE]*w[0] + stage[j*STRIDE+1]*w[1];
    } else {
      const f32x4* dp = (const f32x4*)&stage[j*STRIDE];
      #pragma unroll
      for (int r4=0; r4<R/4; ++r4){
        f32x4 v = dp[r4];
        x += v[0]*w[r4*4] + v[1]*w[r4*4+1] + v[2]*w[r4*4+2] + v[3]*w[r4*4+3];
      }
    }
    float e = __expf(x);
    float dt = (x > 15.f) ? x : __logf(1.f + e);
    dtsum += dt;
    float du = dt*u;
    const f32x4* bp = (const f32x4*)&stage[j*STRIDE + BOFF];
    if (pat){
      float q = 1.f/(1.f + e);            // = exp(-dt), exact identity
      float q2 = q*q, q4 = q2*q2;
      f32x4 f0; f0[0]=q; f0[1]=q2; f0[2]=q2*q; f0[3]=q4;
      f32x4 f1 = f0*q4, f2 = f1*q4, f3 = f2*q4;
      f32x4 B0 = bp[0], B1 = bp[1], B2 = bp[2], B3 = bp[3];
      #pragma unroll
      for (int i=0;i<4;++i){
        s[i]    = s[i]   *f0[i] + du*B0[i];
        s[4+i]  = s[4+i] *f1[i] + du*B1[i];
        s[8+i]  = s[8+i] *f2[i] + du*B2[i];
        s[12+i] = s[12+i]*f3[i] + du*B3[i];
      }
    } else {
      #pragma unroll
      for (int n4=0;n4<4;++n4){
        f32x4 B = bp[n4];
        #pragma unroll
        for (int i=0;i<4;++i){ int n=n4*4+i; s[n] = s[n]*__expf(dt*A[n]) + du*B[i]; }
      }
    }
  }
  float* P = W + o_p; float* S = W + o_s;
  long long base = (long long)c*(4LL*DCH*16) + (long long)k*DCH*16 + (long long)dch*16;
  #pragma unroll
  for (int n=0;n<16;++n){ P[base+n] = __expf(dtsum*A[n]); S[base+n] = s[n]; }
}

template<int NSTATE, int CH>
__global__ void k_carry(float* __restrict__ W, long long o_p, long long o_s){
  int idx = blockIdx.x*256 + threadIdx.x;
  if (idx >= NSTATE) return;
  const float* P = W + o_p; float* S = W + o_s;
  float h = 0.f;
  for (int c=0;c<CH;++c){
    float p = P[(long long)c*NSTATE + idx];
    float s = S[(long long)c*NSTATE + idx];
    S[(long long)c*NSTATE + idx] = h;
    h = h*p + s;
  }
}

template<int DCH, int TD, int L, int LG, int T, int R, int CROWS, int STRIDE, int BOFF>
__global__ void k_scan_p3(float* __restrict__ W, long long o_dbl, long long o_xt,
                          long long o_s, long long o_ys,
                          long long i_dtw, long long i_dtb, long long i_alog, long long i_dd){
  constexpr int NT = DCH/TD;
  int k = blockIdx.x / NT, tile = blockIdx.x % NT;
  int c = blockIdx.y;
  int t = threadIdx.x;
  int dch = tile*TD + t;
  __shared__ __align__(16) float stage[T*STRIDE];
  const float* dbl = W + o_dbl + (long long)k*CROWS*L;
  const int Lm1 = L-1, mask = (1<<LG)-1;
  for (int idx = t; idx < CROWS*T; idx += TD){
    int row = idx / T, col = idx % T;
    int l = c*T + col;
    int cc = scan_addr(k, l, LG, Lm1);
    int slot = (row < R) ? row : (BOFF + row - R);
    stage[col*STRIDE + slot] = dbl[(long long)row*L + cc];
  }
  __syncthreads();
  float w[R], A[16], s[16];
  #pragma unroll
  for (int r=0;r<R;++r) w[r] = W[i_dtw + (long long)(k*DCH+dch)*R + r];
  float bias = W[i_dtb + k*DCH + dch];
  float Dv = W[i_dd + k*DCH + dch];
  long long sbase = (long long)c*(4LL*DCH*16) + (long long)k*DCH*16 + (long long)dch*16;
  bool pat = true;
  #pragma unroll
  for (int n=0;n<16;++n){
    A[n] = -expf(W[i_alog + (long long)(k*DCH+dch)*16 + n]);
    pat = pat && (fabsf(A[n] + (float)(n+1)) <= 1e-3f*(float)(n+1));
    s[n] = W[o_s + sbase + n];
  }
  const float* XT = W + o_xt;
  __half* Y = (__half*)(W + o_ys);
  for (int j=0;j<T;++j){
    int l = c*T + j;
    int p_ = (k&2)? (Lm1-l) : l;
    int ua = (k&1)? (((p_&mask)<<LG)|(p_>>LG)) : p_;
    float u = XT[(long long)ua*DCH + dch];
    float x = bias;
    if (R == 2){
      x += stage[j*STRIDE]*w[0] + stage[j*STRIDE+1]*w[1];
    } else {
      const f32x4* dp = (const f32x4*)&stage[j*STRIDE];
      #pragma unroll
      for (int r4=0; r4<R/4; ++r4){
        f32x4 v = dp[r4];
        x += v[0]*w[r4*4] + v[1]*w[r4*4+1] + v[2]*w[r4*4+2] + v[3]*w[r4*4+3];
      }
    }
    float e = __expf(x);
    float dt = (x > 15.f) ? x : __logf(1.f + e);
    float du = dt*u;
    float y = Dv*u;
    const f32x4* bp = (const f32x4*)&stage[j*STRIDE + BOFF];
    const f32x4* cp = (const f32x4*)&stage[j*STRIDE + BOFF + 16];
    if (pat){
      float q = 1.f/(1.f + e);
      float q2 = q*q, q4 = q2*q2;
      f32x4 f0; f0[0]=q; f0[1]=q2; f0[2]=q2*q; f0[3]=q4;
      f32x4 f1 = f0*q4, f2 = f1*q4, f3 = f2*q4;
      f32x4 B0 = bp[0], B1 = bp[1], B2 = bp[2], B3 = bp[3];
      f32x4 C0 = cp[0], C1 = cp[1], C2 = cp[2], C3 = cp[3];
      #pragma unroll
      for (int i=0;i<4;++i){
        s[i]    = s[i]   *f0[i] + du*B0[i];
        s[4+i]  = s[4+i] *f1[i] + du*B1[i];
        s[8+i]  = s[8+i] *f2[i] + du*B2[i];
        s[12+i] = s[12+i]*f3[i] + du*B3[i];
      }
      #pragma unroll
      for (int i=0;i<4;++i)
        y += s[i]*C0[i] + s[4+i]*C1[i] + s[8+i]*C2[i] + s[12+i]*C3[i];
    } else {
      #pragma unroll
      for (int n4=0;n4<4;++n4){
        f32x4 B = bp[n4], C = cp[n4];
        #pragma unroll
        for (int i=0;i<4;++i){
          int n = n4*4+i;
          s[n] = s[n]*__expf(dt*A[n]) + du*B[i];
          y += s[n]*C[i];
        }
      }
    }
    Y[(long long)l*(4*DCH) + k*DCH + dch] = __float2half(y);
  }
}

// =============== stage A: c0 ===============
__global__ void k_c0(float* __restrict__ W){
  int i = blockIdx.x*256 + threadIdx.x; if (i >= 32*512) return;
  int c = i >> 9, l = i & 511;
  float acc = W[I_C0B + c];
  for (int ii=0; ii<18; ++ii)
    for (int j=0; j<3; ++j){
      int p = l-1+j;
      if (p >= 0 && p < 512) acc += W[I_LD + ii*512 + p] * W[I_C0W + (c*18+ii)*3 + j];
    }
  W[O_X0 + i] = acc;
}

// =============== stage B: mamba2 ===============
__global__ void k_zxf(float* __restrict__ W){
  int j = blockIdx.x;
  int t = threadIdx.x, l = t & 31, kc = t >> 5;
  __shared__ float wrow[512];
  for (int idx = t; idx < 512; idx += 256) wrow[idx] = W[I_MINW + (long long)j*512 + idx];
  __syncthreads();
  float acc = 0.f;
  const float* u = W + O_X0 + l*512;
  for (int d = kc*64; d < kc*64 + 64; ++d) acc += u[d]*wrow[d];
  __shared__ float red[256];
  red[t] = acc; __syncthreads();
  if (kc == 0){
    float s = 0.f;
    #pragma unroll
    for (int q=0;q<8;++q) s += red[l + q*32];
    W[O_ZX + l*2320 + j] = s;
  }
}

__global__ void k_conv4(float* __restrict__ W){
  int i = blockIdx.x*256 + threadIdx.x; if (i >= 32*1280) return;
  int l = i / 1280, c = i % 1280;
  float acc = W[I_MCONVB + c];
  for (int j=0; j<4; ++j){
    int p = l-3+j;
    if (p >= 0) acc += W[O_ZX + p*2320 + 1024 + c] * W[I_MCONVW + c*4 + j];
  }
  W[O_XBCC + l*1280 + c] = siluf(acc);
}

__global__ void k_dtm(float* __restrict__ W){
  int i = blockIdx.x*256 + threadIdx.x; if (i >= 512) return;
  int l = i >> 4, h = i & 15;
  W[O_DTM + i] = softplusf(W[O_ZX + l*2320 + 2304 + h] + W[I_MDTB + h]);
}

__global__ void k_mscan(float* __restrict__ W){
  int h = blockIdx.x >> 6, pp = blockIdx.x & 63;
  int lane = threadIdx.x;
  float A = -expf(W[I_MALOG + h]);
  float Dv = W[I_MD + h];
  float s0 = 0.f, s1 = 0.f;
  for (int l=0; l<32; ++l){
    float dt = W[O_DTM + l*16 + h];
    float xv = W[O_XBCC + l*1280 + h*64 + pp];
    float dA = expf(dt*A);
    float b0 = W[O_XBCC + l*1280 + 1024 + lane];
    float b1 = W[O_XBCC + l*1280 + 1088 + lane];
    float c0 = W[O_XBCC + l*1280 + 1152 + lane];
    float c1 = W[O_XBCC + l*1280 + 1216 + lane];
    float du = dt*xv;
    s0 = s0*dA + du*b0;
    s1 = s1*dA + du*b1;
    float part = s0*c0 + s1*c1;
    for (int off=32; off; off>>=1) part += __shfl_xor(part, off, 64);
    if (lane == 0) W[O_TPRE + l*1024 + h*64 + pp] = part + Dv*xv;
  }
}

__global__ void k_gaterms(float* __restrict__ W){
  int l = blockIdx.x, t = threadIdx.x;
  float vals[4]; float ss = 0.f;
  for (int q=0; q<4; ++q){
    int c = t + q*256;
    float z = W[O_ZX + l*2320 + c];
    float y = W[O_TPRE + l*1024 + c];
    float v = y * siluf(z);
    vals[q] = v; ss += v*v;
  }
  for (int off=32; off; off>>=1) ss += __shfl_xor(ss, off, 64);
  __shared__ float sm[4];
  if ((t & 63) == 0) sm[t>>6] = ss;
  __syncthreads();
  float tot = sm[0]+sm[1]+sm[2]+sm[3];
  float r = rsqrtf(tot/1024.f + 1e-5f);
  for (int q=0; q<4; ++q){
    int c = t + q*256;
    W[O_TG + l*1024 + c] = vals[q]*r*W[I_MNORMW + c];
  }
}

__global__ void k_outmf(float* __restrict__ W){
  int d = blockIdx.x;
  int t = threadIdx.x, l = t & 31, kc = t >> 5;
  __shared__ float wrow[1024];
  for (int idx = t; idx < 1024; idx += 256) wrow[idx] = W[I_MOUTW + (long long)d*1024 + idx];
  __syncthreads();
  float acc = 0.f;
  const float* tg = W + O_TG + l*1024;
  for (int c = kc*128; c < kc*128 + 128; ++c) acc += tg[c]*wrow[c];
  __shared__ float red[256];
  red[t] = acc; __syncthreads();
  if (kc == 0){
    float s = 0.f;
    #pragma unroll
    for (int q=0;q<8;++q) s += red[l + q*32];
    W[O_OUTM + l*512 + d] = s;
  }
}

// =============== stage C: c1 ===============
__global__ void k_c1f(float* __restrict__ W){
  int o = blockIdx.x;
  int t = threadIdx.x, l = t & 31, kc = t >> 5;
  __shared__ float wrow[1536];
  for (int idx = t; idx < 1536; idx += 256) wrow[idx] = W[I_C1W + (long long)o*1536 + idx];
  __syncthreads();
  float acc = 0.f;
  for (int ii = kc*64; ii < kc*64 + 64; ++ii){
    #pragma unroll
    for (int j=0;j<3;++j){
      int p = l-1+j;
      if (p >= 0 && p < 32) acc += W[O_OUTM + p*512 + ii] * wrow[ii*3+j];
    }
  }
  __shared__ float red[256];
  red[t] = acc; __syncthreads();
  if (kc == 0){
    float s = W[I_C1B + o];
    #pragma unroll
    for (int q=0;q<8;++q) s += red[l + q*32];
    W[O_Y1 + o*32 + l] = s;
  }
}

// =============== vssblock 1 ===============
__global__ void k_ln1(float* __restrict__ W){
  int l = blockIdx.x*256 + threadIdx.x; if (l >= 1024) return;
  float s = 0.f, s2 = 0.f;
  for (int c=0; c<32; ++c){ float v = W[O_Y1 + l*32 + c]; s += v; s2 += v*v; }
  float mu = s/32.f, var = s2/32.f - mu*mu, rs = rsqrtf(var + 1e-5f);
  for (int c=0; c<32; ++c){
    float v = W[O_Y1 + l*32 + c];
    W[O_H1 + l*32 + c] = (v-mu)*rs*W[I_V1LNW + c] + W[I_V1LNB + c];
  }
}

__global__ void k_xz1(float* __restrict__ W){
  int i = blockIdx.x*256 + threadIdx.x; if (i >= 1024*128) return;
  int l = i >> 7, j = i & 127;
  float acc = 0.f;
  for (int c=0; c<32; ++c) acc += W[O_H1 + l*32 + c] * W[I_V1INW + j*32 + c];
  W[O_XZ1 + i] = acc;
}

__global__ void k_dwcs1(float* __restrict__ W){
  int i = blockIdx.x*256 + threadIdx.x; if (i >= 64*1024) return;
  int ch = i >> 10, pix = i & 1023, a = pix >> 5, b = pix & 31;
  float acc = W[I_V1CONVB + ch];
  for (int dy=0; dy<3; ++dy){
    int aa = a+dy-1; if (aa < 0 || aa > 31) continue;
    for (int dx=0; dx<3; ++dx){
      int bb = b+dx-1; if (bb < 0 || bb > 31) continue;
      acc += W[O_XZ1 + (aa*32+bb)*128 + ch] * W[I_V1CONVW + ch*9 + dy*3 + dx];
    }
  }
  W[O_XC1 + i] = siluf(acc);
}

__global__ void k_dbl1(float* __restrict__ W){
  int i = blockIdx.x*256 + threadIdx.x; if (i >= 4*34*1024) return;
  int k = i / 34816, r = i % 34816, c = r / 1024, l = r % 1024;
  float acc = 0.f;
  for (int d=0; d<64; ++d) acc += W[O_XC1 + d*1024 + l] * W[I_V1XPW + (k*34+c)*64 + d];
  W[O_DBL1 + (k*34+c)*1024 + l] = acc;
}

__global__ void k_comb1(float* __restrict__ W){
  int l = blockIdx.x, dch = threadIdx.x;
  int t1 = ((l & 31) << 5) | (l >> 5);
  const __half* Y = (const __half*)(W + O_YS1);
  float x = __half2float(Y[l*256 + dch])
          + __half2float(Y[t1*256 + 64 + dch])
          + __half2float(Y[(1023-l)*256 + 128 + dch])
          + __half2float(Y[(1023-t1)*256 + 192 + dch]);
  float s = x, s2 = x*x;
  for (int off=32; off; off>>=1){ s += __shfl_xor(s, off, 64); s2 += __shfl_xor(s2, off, 64); }
  float mu = s/64.f, var = s2/64.f - mu*mu, rs = rsqrtf(var + 1e-5f);
  float yn = (x-mu)*rs*W[I_V1ONW + dch] + W[I_V1ONB + dch];
  float z = W[O_XZ1 + l*128 + 64 + dch];
  W[O_G1 + l*64 + dch] = yn * siluf(z);
}

__global__ void k_oproj1(float* __restrict__ W){
  int i = blockIdx.x*256 + threadIdx.x; if (i >= 1024*32) return;
  int l = i >> 5, c = i & 31;
  float acc = W[O_Y1 + i];
  for (int d=0; d<64; ++d) acc += W[O_G1 + l*64 + d] * W[I_V1OUTW + c*64 + d];
  W[O_OUTD + i] = acc;
}

// =============== stage E: conv stack ===============
__global__ void k_dw1(float* __restrict__ W){
  int i = blockIdx.x*256 + threadIdx.x; if (i >= 32*1024) return;
  int c = i >> 10, pix = i & 1023, a = pix >> 5, b = pix & 31;
  float acc = W[I_DW1B + c];
  for (int dy=0; dy<3; ++dy){
    int aa = a+dy-1; if (aa < 0 || aa > 31) continue;
    for (int dx=0; dx<3; ++dx){
      int bb = b+dx-1; if (bb < 0 || bb > 31) continue;
      acc += W[O_OUTD + (aa*32+bb)*32 + c] * W[I_DW1W + c*9 + dy*3 + dx];
    }
  }
  W[O_E1 + i] = acc;
}

__global__ void k_pw1(float* __restrict__ W){
  int i = blockIdx.x*256 + threadIdx.x; if (i >= 64*1024) return;
  int o = i >> 10, pix = i & 1023;
  float acc = W[I_PW1B + o];
  for (int c=0; c<32; ++c) acc += W[I_PW1W + o*32 + c] * W[O_E1 + c*1024 + pix];
  W[O_E2 + i] = acc;
}

__global__ void k_dw2(float* __restrict__ W){
  int i = blockIdx.x*256 + threadIdx.x; if (i >= 64*1024) return;
  int c = i >> 10, pix = i & 1023, a = pix >> 5, b = pix & 31;
  float acc = W[I_DW2B + c];
  for (int dy=0; dy<3; ++dy){
    int aa = a+dy-1; if (aa < 0 || aa > 31) continue;
    for (int dx=0; dx<3; ++dx){
      int bb = b+dx-1; if (bb < 0 || bb > 31) continue;
      acc += W[O_E2 + c*1024 + aa*32 + bb] * W[I_DW2W + c*9 + dy*3 + dx];
    }
  }
  W[O_E3 + i] = acc;
}

__global__ void k_pw2(float* __restrict__ W){
  int i = blockIdx.x*256 + threadIdx.x; if (i >= 128*1024) return;
  int o = i >> 10, pix = i & 1023;
  float acc = W[I_PW2B + o];
  for (int c=0; c<64; ++c) acc += W[I_PW2W + o*64 + c] * W[O_E3 + c*1024 + pix];
  W[O_E4 + i] = acc;
}

DEV void rs_coef(int o, int n, int& i0, int& i1, float& w0, float& w1){
  float src = 0.5f*(float)o - 0.25f;
  float f = floorf(src);
  float fr = src - f;
  int a = (int)f;
  if (a < 0){ i0 = 0; i1 = 0; w0 = 0.f; w1 = 1.f; }
  else if (a >= n-1){ i0 = n-1; i1 = n-1; w0 = 1.f; w1 = 0.f; }
  else { i0 = a; i1 = a+1; w0 = 1.f-fr; w1 = fr; }
}

__global__ void k_resize(float* __restrict__ W){
  int i = blockIdx.x*256 + threadIdx.x; if (i >= 128*4096) return;
  int c = i >> 12, pix = i & 4095, y = pix >> 6, x = pix & 63;
  int iy0, iy1, ix0, ix1; float wy0, wy1, wx0, wx1;
  rs_coef(y, 32, iy0, iy1, wy0, wy1);
  rs_coef(x, 32, ix0, ix1, wx0, wx1);
  const float* in = W + O_E4 + c*1024;
  float v = wy0*(wx0*in[iy0*32+ix0] + wx1*in[iy0*32+ix1])
          + wy1*(wx0*in[iy1*32+ix0] + wx1*in[iy1*32+ix1]);
  W[O_E5 + i] = v;
}

// =============== stage F: vssblock2 ===============
__global__ void k_ln2(float* __restrict__ W){
  int l = blockIdx.x, t = threadIdx.x;
  float v0 = W[O_E8 + (long long)t*4096 + l];
  float v1 = W[O_E8 + (long long)(t+256)*4096 + l];
  float s = v0+v1, s2 = v0*v0 + v1*v1;
  for (int off=32; off; off>>=1){ s += __shfl_xor(s, off, 64); s2 += __shfl_xor(s2, off, 64); }
  __shared__ float a[4], b[4];
  if ((t & 63) == 0){ a[t>>6] = s; b[t>>6] = s2; }
  __syncthreads();
  float S = a[0]+a[1]+a[2]+a[3], S2 = b[0]+b[1]+b[2]+b[3];
  float mu = S/512.f, var = S2/512.f - mu*mu, rs = rsqrtf(var + 1e-5f);
  unsigned short* H = (unsigned short*)(W + O_LN2);
  H[(long long)l*512 + t]     = f2bf((v0-mu)*rs*W[I_V2LNW + t]     + W[I_V2LNB + t]);
  H[(long long)l*512 + t+256] = f2bf((v1-mu)*rs*W[I_V2LNW + t+256] + W[I_V2LNB + t+256]);
}

__global__ void k_dwcs2(float* __restrict__ W){
  long long i = (long long)blockIdx.x*256 + threadIdx.x;
  int ch = (int)(i >> 12), pix = (int)(i & 4095), a = pix >> 6, b = pix & 63;
  float acc = W[I_V2CONVB + ch];
  const float* xp = W + O_XT2 + (long long)ch*4096;
  for (int dy=0; dy<3; ++dy){
    int aa = a+dy-1; if (aa < 0 || aa > 63) continue;
    for (int dx=0; dx<3; ++dx){
      int bb = b+dx-1; if (bb < 0 || bb > 63) continue;
      acc += xp[aa*64+bb] * W[I_V2CONVW + ch*9 + dy*3 + dx];
    }
  }
  W[O_XC2 + i] = siluf(acc);
}

__global__ void k_comb2(float* __restrict__ W){
  int l = blockIdx.x, t = threadIdx.x;
  int t1 = ((l & 63) << 6) | (l >> 6);
  const __half* Y = (const __half*)(W + O_YS2);
  float v[4]; float s = 0.f, s2 = 0.f;
  for (int q=0; q<4; ++q){
    int dch = t + q*256;
    float x = __half2float(Y[(long long)l*4096 + dch])
            + __half2float(Y[(long long)t1*4096 + 1024 + dch])
            + __half2float(Y[(long long)(4095-l)*4096 + 2048 + dch])
            + __half2float(Y[(long long)(4095-t1)*4096 + 3072 + dch]);
    v[q] = x; s += x; s2 += x*x;
  }
  for (int off=32; off; off>>=1){ s += __shfl_xor(s, off, 64); s2 += __shfl_xor(s2, off, 64); }
  __shared__ float a[4], b[4];
  if ((t & 63) == 0){ a[t>>6] = s; b[t>>6] = s2; }
  __syncthreads();
  float S = a[0]+a[1]+a[2]+a[3], S2 = b[0]+b[1]+b[2]+b[3];
  float mu = S/1024.f, var = S2/1024.f - mu*mu, rs = rsqrtf(var + 1e-5f);
  unsigned short* G = (unsigned short*)(W + O_G2);
  for (int q=0; q<4; ++q){
    int dch = t + q*256;
    float yn = (v[q]-mu)*rs*W[I_V2ONW + dch] + W[I_V2ONB + dch];
    float z = W[O_XZ2 + (long long)l*2048 + 1024 + dch];
    G[(long long)l*1024 + dch] = f2bf(yn * siluf(z));
  }
}

// =============== launch ===============
extern "C" void kernel_launch(void* const* d_in, const int* in_sizes, int n_in,
                              void* d_out, int out_size, void* d_ws, size_t ws_size,
                              hipStream_t stream){
  if (ws_size < (size_t)WS_FLOATS * sizeof(float)) return;
  float* W = (float*)d_ws;
  PtrTab tab;
  for (int i=0; i<53; ++i) tab.p[i] = d_in[i];
  const unsigned int* flagp = (const unsigned int*)d_in[9];

  k_ingest<<<INGEST_BLOCKS, 256, 0, stream>>>(tab, W);
  k_prep  <<<12480, 256, 0, stream>>>(W);   // all bf16 weight conversions merged

  k_c0    <<<64, 256, 0, stream>>>(W);
  k_zxf   <<<2320, 256, 0, stream>>>(W);
  k_conv4 <<<160, 256, 0, stream>>>(W);
  k_dtm   <<<2, 256, 0, stream>>>(W);
  k_mscan <<<1024, 64, 0, stream>>>(W);
  k_gaterms<<<32, 256, 0, stream>>>(W);
  k_outmf <<<512, 256, 0, stream>>>(W);
  k_c1f   <<<1024, 256, 0, stream>>>(W);
  k_ln1   <<<4, 256, 0, stream>>>(W);
  k_xz1   <<<512, 256, 0, stream>>>(W);
  k_dwcs1 <<<256, 256, 0, stream>>>(W);
  k_dbl1  <<<544, 256, 0, stream>>>(W);
  // vss1 chunked scan
  k_transpose<<<dim3(32, 2), 256, 0, stream>>>(W + O_XC1, W + O_XT1, 64, 1024, 1024, 64);
  k_scan_p1<64,64,1024,5,64,2,34,40,4><<<dim3(4,16), 64, 0, stream>>>(W, O_DBL1, O_XT1, O_P1, O_S1,
                                                                 I_V1DTW, I_V1DTB, I_V1ALOG);
  k_carry<4096,16><<<16, 256, 0, stream>>>(W, O_P1, O_S1);
  k_scan_p3<64,64,1024,5,64,2,34,40,4><<<dim3(4,16), 64, 0, stream>>>(W, O_DBL1, O_XT1, O_S1, O_YS1,
                                                                 I_V1DTW, I_V1DTB, I_V1ALOG, I_V1D);
  k_comb1 <<<1024, 64, 0, stream>>>(W);
  k_oproj1<<<128, 256, 0, stream>>>(W);
  k_dw1   <<<128, 256, 0, stream>>>(W);
  k_pw1   <<<256, 256, 0, stream>>>(W);
  k_dw2   <<<256, 256, 0, stream>>>(W);
  k_pw2   <<<512, 256, 0, stream>>>(W);
  k_resize<<<2048, 256, 0, stream>>>(W);
  // cv1 via MFMA
  k_transpose_dual<<<dim3(128, 4), 256, 0, stream>>>(W + O_E5, nullptr,
                      (unsigned short*)(W + O_E5TB), 128, 4096, 4096, 128);
  k_im2colT<128><<<dim3(5, 4096), 256, 0, stream>>>((const unsigned short*)(W + O_E5TB),
                      (unsigned short*)(W + O_CV1B2));
  k_gemm_bt<1><<<dim3(1, 32), 256, 0, stream>>>((const unsigned short*)(W + O_CV1WB),
                      (const unsigned short*)(W + O_CV1B2), 1152, 4096,
                      W + O_E6, W + I_CV1B, nullptr, nullptr, nullptr);
  // cv2 via MFMA
  k_transpose_dual<<<dim3(128, 4), 256, 0, stream>>>(W + O_E6, nullptr,
                      (unsigned short*)(W + O_E6TB), 128, 4096, 4096, 128);
  k_gemm_bt<1><<<dim3(2, 32), 256, 0, stream>>>((const unsigned short*)(W + O_CV2WB),
                      (const unsigned short*)(W + O_E6TB), 128, 4096,
                      W + O_E7, W + I_CV2B, nullptr, nullptr, nullptr);
  // fc via MFMA
  k_transpose_dual<<<dim3(128, 8), 256, 0, stream>>>(W + O_E7, nullptr,
                      (unsigned short*)(W + O_E7T), 256, 4096, 4096, 256);
  k_im2colT<256><<<dim3(9, 4096), 256, 0, stream>>>((const unsigned short*)(W + O_E7T),
                      (unsigned short*)(W + O_B2));
  k_gemm_bt<1><<<dim3(4, 32), 256, 0, stream>>>((const unsigned short*)(W + O_FCW2),
                      (const unsigned short*)(W + O_B2), 2304, 4096,
                      W + O_E8, W + I_FCB, nullptr, nullptr, nullptr);
  // vss2
  k_ln2   <<<4096, 256, 0, stream>>>(W);
  k_gemm_bt<0><<<dim3(32, 16), 256, 0, stream>>>((const unsigned short*)(W + O_LN2),
                      (const unsigned short*)(W + O_W2INB), 512, 2048,
                      W + O_XZ2, nullptr, nullptr, nullptr, nullptr);
  k_transpose<<<dim3(32, 128), 256, 0, stream>>>(W + O_XZ2, W + O_XT2, 4096, 1024, 2048, 4096);
  k_dwcs2 <<<16384, 256, 0, stream>>>(W);
  k_transpose_dual<<<dim3(128, 32), 256, 0, stream>>>(W + O_XC2, W + O_XT2,
                      (unsigned short*)(W + O_XT2B), 1024, 4096, 4096, 1024);
  k_gemm_bt<0><<<dim3(2, 32), 256, 0, stream>>>((const unsigned short*)(W + O_XPWB),
                      (const unsigned short*)(W + O_XT2B), 1024, 4096,
                      W + O_DBL2, nullptr, nullptr, nullptr, nullptr);
  k_scan_p1<1024,256,4096,6,64,32,64,68,32><<<dim3(16,64), 256, 0, stream>>>(W, O_DBL2, O_XT2, O_P2, O_S2,
                                                                       I_V2DTW, I_V2DTB, I_V2ALOG);
  k_carry<65536,64><<<256, 256, 0, stream>>>(W, O_P2, O_S2);
  k_scan_p3<1024,256,4096,6,64,32,64,68,32><<<dim3(16,64), 256, 0, stream>>>(W, O_DBL2, O_XT2, O_S2, O_YS2,
                                                                       I_V2DTW, I_V2DTB, I_V2ALOG, I_V2D);
  k_comb2 <<<4096, 256, 0, stream>>>(W);
  k_gemm_bt<2><<<dim3(4, 32), 256, 0, stream>>>((const unsigned short*)(W + O_OUTWB),
                      (const unsigned short*)(W + O_G2), 1024, 4096,
                      nullptr, nullptr, W + O_E8, flagp, d_out);
}

// Round 10
// 975.069 us; speedup vs baseline: 7.0716x; 1.0114x over previous
//
#include <hip/hip_runtime.h>
#include <hip/hip_bf16.h>
#include <hip/hip_fp16.h>
#include <math.h>

#define DEV static __device__ __forceinline__

DEV float siluf(float x){ return x / (1.f + expf(-x)); }
DEV float softplusf(float x){ return (x > 20.f) ? x : log1pf(__expf(x)); }

DEV unsigned short f2bf(float f){
  unsigned int u = __float_as_uint(f);
  unsigned int r = (u + 0x7FFFu + ((u >> 16) & 1u)) >> 16;
  return (unsigned short)r;
}

using bf16x8 = __attribute__((ext_vector_type(8))) short;
using u16x8  = __attribute__((ext_vector_type(8))) unsigned short;
using f32x4  = __attribute__((ext_vector_type(4))) float;

// ---------------- input arena offsets (floats) ----------------
constexpr long long I_LD=0, I_C0W=9216, I_C0B=10944, I_MINW=10976, I_MCONVW=1198816,
 I_MCONVB=1203936, I_MDTB=1205216, I_MALOG=1205232, I_MD=1205248, I_MNORMW=1205264,
 I_MOUTW=1206288, I_C1W=1730576, I_C1B=3303440, I_V1LNW=3304464, I_V1LNB=3304496,
 I_V1INW=3304528, I_V1CONVW=3308624, I_V1CONVB=3309200, I_V1XPW=3309264, I_V1DTW=3317968,
 I_V1DTB=3318480, I_V1ALOG=3318736, I_V1D=3322832, I_V1ONW=3323088, I_V1ONB=3323152,
 I_V1OUTW=3323216, I_DW1W=3325264, I_DW1B=3325552, I_PW1W=3325584, I_PW1B=3327632,
 I_DW2W=3327696, I_DW2B=3328272, I_PW2W=3328336, I_PW2B=3336528, I_CV1W=3336656,
 I_CV1B=3484112, I_CV2W=3484240, I_CV2B=3517008, I_FCW=3517264, I_FCB=4696912,
 I_V2LNW=4697424, I_V2LNB=4697936, I_V2INW=4698448, I_V2CONVW=5747024, I_V2CONVB=5756240,
 I_V2XPW=5757264, I_V2DTW=6019408, I_V2DTB=6150480, I_V2ALOG=6154576, I_V2D=6220112,
 I_V2ONW=6224208, I_V2ONB=6225232, I_V2OUTW=6226256;
constexpr long long TOTAL_IN = 6750544;
constexpr int INGEST_BLOCKS = (int)((TOTAL_IN + 255) / 256);
constexpr long long O_E8 = 6750544;                // (512,4096) f32, lives to the end
constexpr long long SCR  = 8847696;
// phase 1 (stages A-E)
constexpr long long O_X0=SCR+0, O_ZX=SCR+16384, O_XBCC=SCR+90624, O_DTM=SCR+131584,
 O_TPRE=SCR+132096, O_TG=SCR+164864, O_OUTM=SCR+197632, O_Y1=SCR+214016, O_H1=SCR+246784,
 O_XZ1=SCR+279552, O_XC1=SCR+410624, O_DBL1=SCR+476160, O_YS1=SCR+615424, O_G1=SCR+877568,
 O_OUTD=SCR+943104, O_E1=SCR+975872, O_E2=SCR+1008640, O_E3=SCR+1074176, O_E4=SCR+1139712,
 O_E5=SCR+1270784, O_E6=SCR+1795072, O_E7=SCR+2319360;
// vss1 scan scratch
constexpr long long O_XT1=SCR+3367936, O_P1=SCR+3433472, O_S1=SCR+3499008;   // S1 ends 3564544
// free gap 3564544..4000000
constexpr long long O_CV2WB=SCR+3564544;  // 256x128 bf16 = 16384 slots, ends 3580928
constexpr long long O_CV1WB=SCR+3580928;  // 128x1152 bf16 = 73728 slots, ends 3654656
// fc/cv MFMA scratch (phase-1 tail; dead before XZ2 is written)
constexpr long long O_FCW2=SCR+4000000;   // 512x2304 bf16 (589824 slots, ends 4589824)
constexpr long long O_E7T =SCR+4600000;   // 4096x256 bf16 (524288 slots, ends 5124288)
constexpr long long O_E6TB=O_E7T;         // sequential reuse
constexpr long long O_E5TB=O_E7T;         // sequential reuse (cv1, earliest)
constexpr long long O_B2  =SCR+5242880;   // 4096x2304 bf16 (4718592 slots, ends 9961472)
constexpr long long O_CV1B2=O_B2;         // 4096x1152 bf16 — used before fc's B2
// phase 2 (stage F)
constexpr long long O_XZ2=SCR+0;                        // 4096x2048 f32 (ends 8388608)
constexpr long long O_XC2=SCR+8388608;                  // 1024x4096 f32 (dead after dual transpose)
constexpr long long O_P2 =O_XC2;                        // overlay: P written in scan pass 1
constexpr long long O_XT2=SCR+12582912;                 // XP[ch][pix] f32, then XT[pix][ch] f32
constexpr long long O_G2 =O_XT2;                        // overlay: bf16 G2 (comb2 out, XT2 dead)
constexpr long long O_DBL2=SCR+16777216;                // G[256][4096] f32 (ends 17825792)
constexpr long long O_S2 =SCR+17825792;                 // (ends 22020096)
constexpr long long O_YS2=SCR+22020096;                 // fp16 ys (ends 30408704)
constexpr long long O_LN2=SCR+30408704;                 // bf16 LN2 (524288 slots, ends 31457280)
// bf16 weights / staging (top region, no overlap)
constexpr long long O_W2INB=SCR+32505856;               // ends 33030144
constexpr long long O_XPWB =SCR+33030144;               // ends 33161216
constexpr long long O_OUTWB=SCR+33161216;               // ends 33423360
constexpr long long O_XT2B =SCR+33423360;               // ends 35520512
constexpr long long WS_FLOATS = SCR + 36700160;

struct PtrTab { const void* p[53]; };

__constant__ long long c_inoff[53] = { 0, 9216, 10944, 10976, 1198816, 1203936, 1205216,
 1205232, 1205248, 1205264, 1206288, 1730576, 3303440, 3304464, 3304496, 3304528, 3308624,
 3309200, 3309264, 3317968, 3318480, 3318736, 3322832, 3323088, 3323152, 3323216, 3325264,
 3325552, 3325584, 3327632, 3327696, 3328272, 3328336, 3336528, 3336656, 3484112, 3484240,
 3517008, 3517264, 4696912, 4697424, 4697936, 4698448, 5747024, 5756240, 5757264, 6019408,
 6150480, 6154576, 6220112, 6224208, 6225232, 6226256 };

DEV int scan_addr(int k, int l, int lg, int Lm1){
  int p = (k & 2) ? (Lm1 - l) : l;
  int mask = (1 << lg) - 1;
  if (k & 1) p = ((p & mask) << lg) | (p >> lg);
  return p;
}

// =============== ingest ===============
__global__ void k_ingest(PtrTab t, float* __restrict__ W){
  long long idx = (long long)blockIdx.x*256 + threadIdx.x;
  if (idx >= TOTAL_IN) return;
  int j = 0;
  #pragma unroll
  for (int q=1; q<53; ++q) if (idx >= c_inoff[q]) j = q;
  int local = (int)(idx - c_inoff[j]);
  bool bf = (*(const unsigned int*)t.p[9]) == 0x3F803F80u;
  float v;
  if (bf){
    unsigned short u = ((const unsigned short*)t.p[j])[local];
    v = __uint_as_float(((unsigned int)u) << 16);
  } else {
    v = ((const float*)t.p[j])[local];
  }
  W[idx] = v;
}

// =============== merged weight prep ===============
__global__ void k_prep(float* __restrict__ W){
  long long i = (long long)blockIdx.x*256 + threadIdx.x;
  if (i < 1048576){
    ((unsigned short*)(W + O_W2INB))[i] = f2bf(W[I_V2INW + i]);
  } else if (i < 1310720){
    long long d = i - 1048576;
    ((unsigned short*)(W + O_XPWB))[d] = f2bf(W[I_V2XPW + d]);
  } else if (i < 1835008){
    long long d = i - 1310720;
    ((unsigned short*)(W + O_OUTWB))[d] = f2bf(W[I_V2OUTW + d]);
  } else if (i < 1867776){
    long long d = i - 1835008;
    ((unsigned short*)(W + O_CV2WB))[d] = f2bf(W[I_CV2W + d]);
  } else if (i < 2015232){
    long long d = i - 1867776;
    int c = (int)(d / 1152), r = (int)(d % 1152), tap = r / 128, i2 = r % 128;
    ((unsigned short*)(W + O_CV1WB))[d] = f2bf(W[I_CV1W + ((long long)(c*128 + i2))*9 + tap]);
  } else if (i < 3194880){
    long long d = i - 2015232;
    int c = (int)(d / 2304), r = (int)(d % 2304), tap = r / 256, i2 = r % 256;
    ((unsigned short*)(W + O_FCW2))[d] = f2bf(W[I_FCW + ((long long)(c*256 + i2))*9 + tap]);
  }
}

// im2col
template<int CIN>
__global__ void k_im2colT(const unsigned short* __restrict__ XT, unsigned short* __restrict__ B2){
  int r = blockIdx.x*256 + threadIdx.x;
  if (r >= 9*CIN) return;
  int p = blockIdx.y;
  int tap = r / CIN, d = r % CIN;
  int dy = tap/3 - 1, dx = tap%3 - 1;
  int y = p >> 6, x = p & 63;
  int yy = y + dy, xx = x + dx;
  unsigned short v = 0;
  if (yy >= 0 && yy < 64 && xx >= 0 && xx < 64) v = XT[(long long)(yy*64+xx)*CIN + d];
  B2[(long long)p*(9*CIN) + r] = v;
}

// =============== transposes ===============
__global__ void k_transpose(const float* __restrict__ in, float* __restrict__ out,
                            int rows, int cols, long long instride, long long outstride){
  __shared__ float tile[32][33];
  int tx = threadIdx.x & 31, ty = threadIdx.x >> 5;
  long long c0 = (long long)blockIdx.x*32, r0 = (long long)blockIdx.y*32;
  #pragma unroll
  for (int i=0;i<32;i+=8){
    long long r = r0 + ty + i, c = c0 + tx;
    if (r < rows && c < cols) tile[ty+i][tx] = in[r*instride + c];
  }
  __syncthreads();
  #pragma unroll
  for (int i=0;i<32;i+=8){
    long long r = r0 + tx, c = c0 + ty + i;
    if (r < rows && c < cols) out[c*outstride + r] = tile[tx][ty+i];
  }
}

__global__ void k_transpose_dual(const float* __restrict__ in, float* __restrict__ outF,
                                 unsigned short* __restrict__ outB,
                                 int rows, int cols, long long instride, long long outstride){
  __shared__ float tile[32][33];
  int tx = threadIdx.x & 31, ty = threadIdx.x >> 5;
  long long c0 = (long long)blockIdx.x*32, r0 = (long long)blockIdx.y*32;
  #pragma unroll
  for (int i=0;i<32;i+=8){
    long long r = r0 + ty + i, c = c0 + tx;
    if (r < rows && c < cols) tile[ty+i][tx] = in[r*instride + c];
  }
  __syncthreads();
  #pragma unroll
  for (int i=0;i<32;i+=8){
    long long r = r0 + tx, c = c0 + ty + i;
    if (r < rows && c < cols){
      float v = tile[tx][ty+i];
      if (outF) outF[c*outstride + r] = v;
      outB[c*outstride + r] = f2bf(v);
    }
  }
}

// =============== bf16 MFMA GEMM ===============
template<int MODE>
__global__ __launch_bounds__(256)
void k_gemm_bt(const unsigned short* __restrict__ A, const unsigned short* __restrict__ B,
               int K, int N, float* __restrict__ Cout, const float* __restrict__ bias,
               const float* __restrict__ res, const unsigned int* flagp, void* dout){
  constexpr int LDK = 72;
  __shared__ unsigned short As[128*LDK], Bs[128*LDK];
  int m0 = blockIdx.x*128, n0 = blockIdx.y*128;
  int tid = threadIdx.x;
  int wave = tid >> 6, lane = tid & 63, quad = lane >> 4, l16 = lane & 15;
  int wm = wave >> 1, wn = wave & 1;
  f32x4 acc[4][4];
  #pragma unroll
  for (int a=0;a<4;++a)
    #pragma unroll
    for (int b=0;b<4;++b) acc[a][b] = (f32x4){0.f,0.f,0.f,0.f};
  int srow = tid >> 1, shalf = (tid & 1)*32;
  for (int kt = 0; kt < K; kt += 64){
    const u16x8* ga = (const u16x8*)(A + (long long)(m0+srow)*K + kt + shalf);
    const u16x8* gb = (const u16x8*)(B + (long long)(n0+srow)*K + kt + shalf);
    u16x8* da = (u16x8*)&As[srow*LDK + shalf];
    u16x8* db = (u16x8*)&Bs[srow*LDK + shalf];
    #pragma unroll
    for (int c=0;c<4;++c){ da[c] = ga[c]; db[c] = gb[c]; }
    __syncthreads();
    #pragma unroll
    for (int ks=0; ks<64; ks+=32){
      bf16x8 af[4], bfr[4];
      #pragma unroll
      for (int mi=0;mi<4;++mi)
        af[mi] = *(const bf16x8*)&As[(wm*64 + mi*16 + l16)*LDK + ks + quad*8];
      #pragma unroll
      for (int ni=0;ni<4;++ni)
        bfr[ni] = *(const bf16x8*)&Bs[(wn*64 + ni*16 + l16)*LDK + ks + quad*8];
      #pragma unroll
      for (int mi=0;mi<4;++mi)
        #pragma unroll
        for (int ni=0;ni<4;++ni)
          acc[mi][ni] = __builtin_amdgcn_mfma_f32_16x16x32_bf16(af[mi], bfr[ni], acc[mi][ni], 0, 0, 0);
    }
    __syncthreads();
  }
  bool bf = (MODE == 2) ? ((*flagp) == 0x3F803F80u) : false;
  #pragma unroll
  for (int mi=0;mi<4;++mi){
    #pragma unroll
    for (int ni=0;ni<4;++ni){
      #pragma unroll
      for (int r=0;r<4;++r){
        int m = m0 + wm*64 + mi*16 + quad*4 + r;
        int n = n0 + wn*64 + ni*16 + l16;
        float v = acc[mi][ni][r];
        if (MODE == 1) v += bias[m];
        if (MODE == 2){
          v += res[(long long)m*N + n];
          if (bf) ((unsigned short*)dout)[(long long)m*N + n] = f2bf(v);
          else    ((float*)dout)[(long long)m*N + n] = v;
        } else {
          Cout[(long long)m*N + n] = v;
        }
      }
    }
  }
}

// =============== chunked selective-scan (3 passes) ===============
// stage[j][slot]: dt r -> r, B n -> BOFF+n, C n -> BOFF+16+n.
// SROWS: number of leading dbl rows staged (p1: R+16, p3: R+32).
// u-prefetch: 8 independent global loads per group to hide L2 latency.
template<int DCH, int TD, int L, int LG, int T, int R, int CROWS, int STRIDE, int BOFF, int SROWS>
__global__ void k_scan_p1(float* __restrict__ W, long long o_dbl, long long o_xt,
                          long long o_p, long long o_s,
                          long long i_dtw, long long i_dtb, long long i_alog){
  constexpr int NT = DCH/TD;
  int k = blockIdx.x / NT, tile = blockIdx.x % NT;
  int c = blockIdx.y;
  int t = threadIdx.x;
  int dch = tile*TD + t;
  __shared__ __align__(16) float stage[T*STRIDE];
  const float* dbl = W + o_dbl + (long long)k*CROWS*L;
  const int Lm1 = L-1, mask = (1<<LG)-1;
  for (int idx = t; idx < SROWS*T; idx += TD){
    int row = idx / T, col = idx % T;
    int l = c*T + col;
    int cc = scan_addr(k, l, LG, Lm1);
    int slot = (row < R) ? row : (BOFF + row - R);
    stage[col*STRIDE + slot] = dbl[(long long)row*L + cc];
  }
  __syncthreads();
  float w[R], A[16], s[16];
  #pragma unroll
  for (int r=0;r<R;++r) w[r] = W[i_dtw + (long long)(k*DCH+dch)*R + r];
  float bias = W[i_dtb + k*DCH + dch];
  bool pat = true;
  #pragma unroll
  for (int n=0;n<16;++n){
    A[n] = -expf(W[i_alog + (long long)(k*DCH+dch)*16 + n]);
    pat = pat && (fabsf(A[n] + (float)(n+1)) <= 1e-3f*(float)(n+1));
    s[n] = 0.f;
  }
  const float* XT = W + o_xt;
  float dtsum = 0.f;
  for (int j0=0;j0<T;j0+=8){
    float uv[8];
    #pragma unroll
    for (int q=0;q<8;++q){
      int l = c*T + j0 + q;
      int p_ = (k&2)? (Lm1-l) : l;
      int ua = (k&1)? (((p_&mask)<<LG)|(p_>>LG)) : p_;
      uv[q] = XT[(long long)ua*DCH + dch];
    }
    #pragma unroll
    for (int q=0;q<8;++q){
      int j = j0 + q;
      float x = bias;
      if (R == 2){
        x += stage[j*STRIDE]*w[0] + stage[j*STRIDE+1]*w[1];
      } else {
        const f32x4* dp = (const f32x4*)&stage[j*STRIDE];
        #pragma unroll
        for (int r4=0; r4<R/4; ++r4){
          f32x4 v = dp[r4];
          x += v[0]*w[r4*4] + v[1]*w[r4*4+1] + v[2]*w[r4*4+2] + v[3]*w[r4*4+3];
        }
      }
      float e = __expf(x);
      float dt = (x > 15.f) ? x : __logf(1.f + e);
      dtsum += dt;
      float du = dt*uv[q];
      const f32x4* bp = (const f32x4*)&stage[j*STRIDE + BOFF];
      if (pat){
        float qq = 1.f/(1.f + e);
        float q2 = qq*qq, q4 = q2*q2;
        f32x4 f0; f0[0]=qq; f0[1]=q2; f0[2]=q2*qq; f0[3]=q4;
        f32x4 f1 = f0*q4, f2 = f1*q4, f3 = f2*q4;
        f32x4 B0 = bp[0], B1 = bp[1], B2 = bp[2], B3 = bp[3];
        #pragma unroll
        for (int i=0;i<4;++i){
          s[i]    = s[i]   *f0[i] + du*B0[i];
          s[4+i]  = s[4+i] *f1[i] + du*B1[i];
          s[8+i]  = s[8+i] *f2[i] + du*B2[i];
          s[12+i] = s[12+i]*f3[i] + du*B3[i];
        }
      } else {
        #pragma unroll
        for (int n4=0;n4<4;++n4){
          f32x4 B = bp[n4];
          #pragma unroll
          for (int i=0;i<4;++i){ int n=n4*4+i; s[n] = s[n]*__expf(dt*A[n]) + du*B[i]; }
        }
      }
    }
  }
  float* P = W + o_p; float* S = W + o_s;
  long long base = (long long)c*(4LL*DCH*16) + (long long)k*DCH*16 + (long long)dch*16;
  #pragma unroll
  for (int n=0;n<16;++n){ P[base+n] = __expf(dtsum*A[n]); S[base+n] = s[n]; }
}

template<int NSTATE, int CH>
__global__ void k_carry(float* __restrict__ W, long long o_p, long long o_s){
  int idx = blockIdx.x*256 + threadIdx.x;
  if (idx >= NSTATE) return;
  const float* P = W + o_p; float* S = W + o_s;
  float h = 0.f;
  for (int c=0;c<CH;++c){
    float p = P[(long long)c*NSTATE + idx];
    float s = S[(long long)c*NSTATE + idx];
    S[(long long)c*NSTATE + idx] = h;
    h = h*p + s;
  }
}

template<int DCH, int TD, int L, int LG, int T, int R, int CROWS, int STRIDE, int BOFF>
__global__ void k_scan_p3(float* __restrict__ W, long long o_dbl, long long o_xt,
                          long long o_s, long long o_ys,
                          long long i_dtw, long long i_dtb, long long i_alog, long long i_dd){
  constexpr int NT = DCH/TD;
  int k = blockIdx.x / NT, tile = blockIdx.x % NT;
  int c = blockIdx.y;
  int t = threadIdx.x;
  int dch = tile*TD + t;
  __shared__ __align__(16) float stage[T*STRIDE];
  const float* dbl = W + o_dbl + (long long)k*CROWS*L;
  const int Lm1 = L-1, mask = (1<<LG)-1;
  for (int idx = t; idx < CROWS*T; idx += TD){
    int row = idx / T, col = idx % T;
    int l = c*T + col;
    int cc = scan_addr(k, l, LG, Lm1);
    int slot = (row < R) ? row : (BOFF + row - R);
    stage[col*STRIDE + slot] = dbl[(long long)row*L + cc];
  }
  __syncthreads();
  float w[R], A[16], s[16];
  #pragma unroll
  for (int r=0;r<R;++r) w[r] = W[i_dtw + (long long)(k*DCH+dch)*R + r];
  float bias = W[i_dtb + k*DCH + dch];
  float Dv = W[i_dd + k*DCH + dch];
  long long sbase = (long long)c*(4LL*DCH*16) + (long long)k*DCH*16 + (long long)dch*16;
  bool pat = true;
  #pragma unroll
  for (int n=0;n<16;++n){
    A[n] = -expf(W[i_alog + (long long)(k*DCH+dch)*16 + n]);
    pat = pat && (fabsf(A[n] + (float)(n+1)) <= 1e-3f*(float)(n+1));
    s[n] = W[o_s + sbase + n];
  }
  const float* XT = W + o_xt;
  __half* Y = (__half*)(W + o_ys);
  for (int j0=0;j0<T;j0+=8){
    float uv[8];
    #pragma unroll
    for (int q=0;q<8;++q){
      int l = c*T + j0 + q;
      int p_ = (k&2)? (Lm1-l) : l;
      int ua = (k&1)? (((p_&mask)<<LG)|(p_>>LG)) : p_;
      uv[q] = XT[(long long)ua*DCH + dch];
    }
    #pragma unroll
    for (int q=0;q<8;++q){
      int j = j0 + q;
      int l = c*T + j;
      float x = bias;
      if (R == 2){
        x += stage[j*STRIDE]*w[0] + stage[j*STRIDE+1]*w[1];
      } else {
        const f32x4* dp = (const f32x4*)&stage[j*STRIDE];
        #pragma unroll
        for (int r4=0; r4<R/4; ++r4){
          f32x4 v = dp[r4];
          x += v[0]*w[r4*4] + v[1]*w[r4*4+1] + v[2]*w[r4*4+2] + v[3]*w[r4*4+3];
        }
      }
      float e = __expf(x);
      float dt = (x > 15.f) ? x : __logf(1.f + e);
      float du = dt*uv[q];
      float y = Dv*uv[q];
      const f32x4* bp = (const f32x4*)&stage[j*STRIDE + BOFF];
      const f32x4* cp = (const f32x4*)&stage[j*STRIDE + BOFF + 16];
      if (pat){
        float qq = 1.f/(1.f + e);
        float q2 = qq*qq, q4 = q2*q2;
        f32x4 f0; f0[0]=qq; f0[1]=q2; f0[2]=q2*qq; f0[3]=q4;
        f32x4 f1 = f0*q4, f2 = f1*q4, f3 = f2*q4;
        f32x4 B0 = bp[0], B1 = bp[1], B2 = bp[2], B3 = bp[3];
        f32x4 C0 = cp[0], C1 = cp[1], C2 = cp[2], C3 = cp[3];
        #pragma unroll
        for (int i=0;i<4;++i){
          s[i]    = s[i]   *f0[i] + du*B0[i];
          s[4+i]  = s[4+i] *f1[i] + du*B1[i];
          s[8+i]  = s[8+i] *f2[i] + du*B2[i];
          s[12+i] = s[12+i]*f3[i] + du*B3[i];
        }
        #pragma unroll
        for (int i=0;i<4;++i)
          y += s[i]*C0[i] + s[4+i]*C1[i] + s[8+i]*C2[i] + s[12+i]*C3[i];
      } else {
        #pragma unroll
        for (int n4=0;n4<4;++n4){
          f32x4 B = bp[n4], C = cp[n4];
          #pragma unroll
          for (int i=0;i<4;++i){
            int n = n4*4+i;
            s[n] = s[n]*__expf(dt*A[n]) + du*B[i];
            y += s[n]*C[i];
          }
        }
      }
      Y[(long long)l*(4*DCH) + k*DCH + dch] = __float2half(y);
    }
  }
}

// =============== stage A: c0 ===============
__global__ void k_c0(float* __restrict__ W){
  int i = blockIdx.x*256 + threadIdx.x; if (i >= 32*512) return;
  int c = i >> 9, l = i & 511;
  float acc = W[I_C0B + c];
  for (int ii=0; ii<18; ++ii)
    for (int j=0; j<3; ++j){
      int p = l-1+j;
      if (p >= 0 && p < 512) acc += W[I_LD + ii*512 + p] * W[I_C0W + (c*18+ii)*3 + j];
    }
  W[O_X0 + i] = acc;
}

// =============== stage B: mamba2 ===============
__global__ void k_zxf(float* __restrict__ W){
  int j = blockIdx.x;
  int t = threadIdx.x, l = t & 31, kc = t >> 5;
  __shared__ float wrow[512];
  for (int idx = t; idx < 512; idx += 256) wrow[idx] = W[I_MINW + (long long)j*512 + idx];
  __syncthreads();
  float acc = 0.f;
  const float* u = W + O_X0 + l*512;
  for (int d = kc*64; d < kc*64 + 64; ++d) acc += u[d]*wrow[d];
  __shared__ float red[256];
  red[t] = acc; __syncthreads();
  if (kc == 0){
    float s = 0.f;
    #pragma unroll
    for (int q=0;q<8;++q) s += red[l + q*32];
    W[O_ZX + l*2320 + j] = s;
  }
}

__global__ void k_conv4(float* __restrict__ W){
  int i = blockIdx.x*256 + threadIdx.x; if (i >= 32*1280) return;
  int l = i / 1280, c = i % 1280;
  float acc = W[I_MCONVB + c];
  for (int j=0; j<4; ++j){
    int p = l-3+j;
    if (p >= 0) acc += W[O_ZX + p*2320 + 1024 + c] * W[I_MCONVW + c*4 + j];
  }
  W[O_XBCC + l*1280 + c] = siluf(acc);
}

__global__ void k_dtm(float* __restrict__ W){
  int i = blockIdx.x*256 + threadIdx.x; if (i >= 512) return;
  int l = i >> 4, h = i & 15;
  W[O_DTM + i] = softplusf(W[O_ZX + l*2320 + 2304 + h] + W[I_MDTB + h]);
}

__global__ void k_mscan(float* __restrict__ W){
  int h = blockIdx.x >> 6, pp = blockIdx.x & 63;
  int lane = threadIdx.x;
  float A = -expf(W[I_MALOG + h]);
  float Dv = W[I_MD + h];
  float s0 = 0.f, s1 = 0.f;
  for (int l=0; l<32; ++l){
    float dt = W[O_DTM + l*16 + h];
    float xv = W[O_XBCC + l*1280 + h*64 + pp];
    float dA = expf(dt*A);
    float b0 = W[O_XBCC + l*1280 + 1024 + lane];
    float b1 = W[O_XBCC + l*1280 + 1088 + lane];
    float c0 = W[O_XBCC + l*1280 + 1152 + lane];
    float c1 = W[O_XBCC + l*1280 + 1216 + lane];
    float du = dt*xv;
    s0 = s0*dA + du*b0;
    s1 = s1*dA + du*b1;
    float part = s0*c0 + s1*c1;
    for (int off=32; off; off>>=1) part += __shfl_xor(part, off, 64);
    if (lane == 0) W[O_TPRE + l*1024 + h*64 + pp] = part + Dv*xv;
  }
}

__global__ void k_gaterms(float* __restrict__ W){
  int l = blockIdx.x, t = threadIdx.x;
  float vals[4]; float ss = 0.f;
  for (int q=0; q<4; ++q){
    int c = t + q*256;
    float z = W[O_ZX + l*2320 + c];
    float y = W[O_TPRE + l*1024 + c];
    float v = y * siluf(z);
    vals[q] = v; ss += v*v;
  }
  for (int off=32; off; off>>=1) ss += __shfl_xor(ss, off, 64);
  __shared__ float sm[4];
  if ((t & 63) == 0) sm[t>>6] = ss;
  __syncthreads();
  float tot = sm[0]+sm[1]+sm[2]+sm[3];
  float r = rsqrtf(tot/1024.f + 1e-5f);
  for (int q=0; q<4; ++q){
    int c = t + q*256;
    W[O_TG + l*1024 + c] = vals[q]*r*W[I_MNORMW + c];
  }
}

__global__ void k_outmf(float* __restrict__ W){
  int d = blockIdx.x;
  int t = threadIdx.x, l = t & 31, kc = t >> 5;
  __shared__ float wrow[1024];
  for (int idx = t; idx < 1024; idx += 256) wrow[idx] = W[I_MOUTW + (long long)d*1024 + idx];
  __syncthreads();
  float acc = 0.f;
  const float* tg = W + O_TG + l*1024;
  for (int c = kc*128; c < kc*128 + 128; ++c) acc += tg[c]*wrow[c];
  __shared__ float red[256];
  red[t] = acc; __syncthreads();
  if (kc == 0){
    float s = 0.f;
    #pragma unroll
    for (int q=0;q<8;++q) s += red[l + q*32];
    W[O_OUTM + l*512 + d] = s;
  }
}

// =============== stage C: c1 ===============
__global__ void k_c1f(float* __restrict__ W){
  int o = blockIdx.x;
  int t = threadIdx.x, l = t & 31, kc = t >> 5;
  __shared__ float wrow[1536];
  for (int idx = t; idx < 1536; idx += 256) wrow[idx] = W[I_C1W + (long long)o*1536 + idx];
  __syncthreads();
  float acc = 0.f;
  for (int ii = kc*64; ii < kc*64 + 64; ++ii){
    #pragma unroll
    for (int j=0;j<3;++j){
      int p = l-1+j;
      if (p >= 0 && p < 32) acc += W[O_OUTM + p*512 + ii] * wrow[ii*3+j];
    }
  }
  __shared__ float red[256];
  red[t] = acc; __syncthreads();
  if (kc == 0){
    float s = W[I_C1B + o];
    #pragma unroll
    for (int q=0;q<8;++q) s += red[l + q*32];
    W[O_Y1 + o*32 + l] = s;
  }
}

// =============== vssblock 1 ===============
__global__ void k_ln1(float* __restrict__ W){
  int l = blockIdx.x*256 + threadIdx.x; if (l >= 1024) return;
  float s = 0.f, s2 = 0.f;
  for (int c=0; c<32; ++c){ float v = W[O_Y1 + l*32 + c]; s += v; s2 += v*v; }
  float mu = s/32.f, var = s2/32.f - mu*mu, rs = rsqrtf(var + 1e-5f);
  for (int c=0; c<32; ++c){
    float v = W[O_Y1 + l*32 + c];
    W[O_H1 + l*32 + c] = (v-mu)*rs*W[I_V1LNW + c] + W[I_V1LNB + c];
  }
}

__global__ void k_xz1(float* __restrict__ W){
  int i = blockIdx.x*256 + threadIdx.x; if (i >= 1024*128) return;
  int l = i >> 7, j = i & 127;
  float acc = 0.f;
  for (int c=0; c<32; ++c) acc += W[O_H1 + l*32 + c] * W[I_V1INW + j*32 + c];
  W[O_XZ1 + i] = acc;
}

__global__ void k_dwcs1(float* __restrict__ W){
  int i = blockIdx.x*256 + threadIdx.x; if (i >= 64*1024) return;
  int ch = i >> 10, pix = i & 1023, a = pix >> 5, b = pix & 31;
  float acc = W[I_V1CONVB + ch];
  for (int dy=0; dy<3; ++dy){
    int aa = a+dy-1; if (aa < 0 || aa > 31) continue;
    for (int dx=0; dx<3; ++dx){
      int bb = b+dx-1; if (bb < 0 || bb > 31) continue;
      acc += W[O_XZ1 + (aa*32+bb)*128 + ch] * W[I_V1CONVW + ch*9 + dy*3 + dx];
    }
  }
  W[O_XC1 + i] = siluf(acc);
}

__global__ void k_dbl1(float* __restrict__ W){
  int i = blockIdx.x*256 + threadIdx.x; if (i >= 4*34*1024) return;
  int k = i / 34816, r = i % 34816, c = r / 1024, l = r % 1024;
  float acc = 0.f;
  for (int d=0; d<64; ++d) acc += W[O_XC1 + d*1024 + l] * W[I_V1XPW + (k*34+c)*64 + d];
  W[O_DBL1 + (k*34+c)*1024 + l] = acc;
}

__global__ void k_comb1(float* __restrict__ W){
  int l = blockIdx.x, dch = threadIdx.x;
  int t1 = ((l & 31) << 5) | (l >> 5);
  const __half* Y = (const __half*)(W + O_YS1);
  float x = __half2float(Y[l*256 + dch])
          + __half2float(Y[t1*256 + 64 + dch])
          + __half2float(Y[(1023-l)*256 + 128 + dch])
          + __half2float(Y[(1023-t1)*256 + 192 + dch]);
  float s = x, s2 = x*x;
  for (int off=32; off; off>>=1){ s += __shfl_xor(s, off, 64); s2 += __shfl_xor(s2, off, 64); }
  float mu = s/64.f, var = s2/64.f - mu*mu, rs = rsqrtf(var + 1e-5f);
  float yn = (x-mu)*rs*W[I_V1ONW + dch] + W[I_V1ONB + dch];
  float z = W[O_XZ1 + l*128 + 64 + dch];
  W[O_G1 + l*64 + dch] = yn * siluf(z);
}

__global__ void k_oproj1(float* __restrict__ W){
  int i = blockIdx.x*256 + threadIdx.x; if (i >= 1024*32) return;
  int l = i >> 5, c = i & 31;
  float acc = W[O_Y1 + i];
  for (int d=0; d<64; ++d) acc += W[O_G1 + l*64 + d] * W[I_V1OUTW + c*64 + d];
  W[O_OUTD + i] = acc;
}

// =============== stage E: conv stack ===============
__global__ void k_dw1(float* __restrict__ W){
  int i = blockIdx.x*256 + threadIdx.x; if (i >= 32*1024) return;
  int c = i >> 10, pix = i & 1023, a = pix >> 5, b = pix & 31;
  float acc = W[I_DW1B + c];
  for (int dy=0; dy<3; ++dy){
    int aa = a+dy-1; if (aa < 0 || aa > 31) continue;
    for (int dx=0; dx<3; ++dx){
      int bb = b+dx-1; if (bb < 0 || bb > 31) continue;
      acc += W[O_OUTD + (aa*32+bb)*32 + c] * W[I_DW1W + c*9 + dy*3 + dx];
    }
  }
  W[O_E1 + i] = acc;
}

__global__ void k_pw1(float* __restrict__ W){
  int i = blockIdx.x*256 + threadIdx.x; if (i >= 64*1024) return;
  int o = i >> 10, pix = i & 1023;
  float acc = W[I_PW1B + o];
  for (int c=0; c<32; ++c) acc += W[I_PW1W + o*32 + c] * W[O_E1 + c*1024 + pix];
  W[O_E2 + i] = acc;
}

__global__ void k_dw2(float* __restrict__ W){
  int i = blockIdx.x*256 + threadIdx.x; if (i >= 64*1024) return;
  int c = i >> 10, pix = i & 1023, a = pix >> 5, b = pix & 31;
  float acc = W[I_DW2B + c];
  for (int dy=0; dy<3; ++dy){
    int aa = a+dy-1; if (aa < 0 || aa > 31) continue;
    for (int dx=0; dx<3; ++dx){
      int bb = b+dx-1; if (bb < 0 || bb > 31) continue;
      acc += W[O_E2 + c*1024 + aa*32 + bb] * W[I_DW2W + c*9 + dy*3 + dx];
    }
  }
  W[O_E3 + i] = acc;
}

__global__ void k_pw2(float* __restrict__ W){
  int i = blockIdx.x*256 + threadIdx.x; if (i >= 128*1024) return;
  int o = i >> 10, pix = i & 1023;
  float acc = W[I_PW2B + o];
  for (int c=0; c<64; ++c) acc += W[I_PW2W + o*64 + c] * W[O_E3 + c*1024 + pix];
  W[O_E4 + i] = acc;
}

DEV void rs_coef(int o, int n, int& i0, int& i1, float& w0, float& w1){
  float src = 0.5f*(float)o - 0.25f;
  float f = floorf(src);
  float fr = src - f;
  int a = (int)f;
  if (a < 0){ i0 = 0; i1 = 0; w0 = 0.f; w1 = 1.f; }
  else if (a >= n-1){ i0 = n-1; i1 = n-1; w0 = 1.f; w1 = 0.f; }
  else { i0 = a; i1 = a+1; w0 = 1.f-fr; w1 = fr; }
}

__global__ void k_resize(float* __restrict__ W){
  int i = blockIdx.x*256 + threadIdx.x; if (i >= 128*4096) return;
  int c = i >> 12, pix = i & 4095, y = pix >> 6, x = pix & 63;
  int iy0, iy1, ix0, ix1; float wy0, wy1, wx0, wx1;
  rs_coef(y, 32, iy0, iy1, wy0, wy1);
  rs_coef(x, 32, ix0, ix1, wx0, wx1);
  const float* in = W + O_E4 + c*1024;
  float v = wy0*(wx0*in[iy0*32+ix0] + wx1*in[iy0*32+ix1])
          + wy1*(wx0*in[iy1*32+ix0] + wx1*in[iy1*32+ix1]);
  W[O_E5 + i] = v;
}

// =============== stage F: vssblock2 ===============
__global__ void k_ln2(float* __restrict__ W){
  int l = blockIdx.x, t = threadIdx.x;
  float v0 = W[O_E8 + (long long)t*4096 + l];
  float v1 = W[O_E8 + (long long)(t+256)*4096 + l];
  float s = v0+v1, s2 = v0*v0 + v1*v1;
  for (int off=32; off; off>>=1){ s += __shfl_xor(s, off, 64); s2 += __shfl_xor(s2, off, 64); }
  __shared__ float a[4], b[4];
  if ((t & 63) == 0){ a[t>>6] = s; b[t>>6] = s2; }
  __syncthreads();
  float S = a[0]+a[1]+a[2]+a[3], S2 = b[0]+b[1]+b[2]+b[3];
  float mu = S/512.f, var = S2/512.f - mu*mu, rs = rsqrtf(var + 1e-5f);
  unsigned short* H = (unsigned short*)(W + O_LN2);
  H[(long long)l*512 + t]     = f2bf((v0-mu)*rs*W[I_V2LNW + t]     + W[I_V2LNB + t]);
  H[(long long)l*512 + t+256] = f2bf((v1-mu)*rs*W[I_V2LNW + t+256] + W[I_V2LNB + t+256]);
}

__global__ void k_dwcs2(float* __restrict__ W){
  long long i = (long long)blockIdx.x*256 + threadIdx.x;
  int ch = (int)(i >> 12), pix = (int)(i & 4095), a = pix >> 6, b = pix & 63;
  float acc = W[I_V2CONVB + ch];
  const float* xp = W + O_XT2 + (long long)ch*4096;
  for (int dy=0; dy<3; ++dy){
    int aa = a+dy-1; if (aa < 0 || aa > 63) continue;
    for (int dx=0; dx<3; ++dx){
      int bb = b+dx-1; if (bb < 0 || bb > 63) continue;
      acc += xp[aa*64+bb] * W[I_V2CONVW + ch*9 + dy*3 + dx];
    }
  }
  W[O_XC2 + i] = siluf(acc);
}

__global__ void k_comb2(float* __restrict__ W){
  int l = blockIdx.x, t = threadIdx.x;
  int t1 = ((l & 63) << 6) | (l >> 6);
  const __half* Y = (const __half*)(W + O_YS2);
  float v[4]; float s = 0.f, s2 = 0.f;
  for (int q=0; q<4; ++q){
    int dch = t + q*256;
    float x = __half2float(Y[(long long)l*4096 + dch])
            + __half2float(Y[(long long)t1*4096 + 1024 + dch])
            + __half2float(Y[(long long)(4095-l)*4096 + 2048 + dch])
            + __half2float(Y[(long long)(4095-t1)*4096 + 3072 + dch]);
    v[q] = x; s += x; s2 += x*x;
  }
  for (int off=32; off; off>>=1){ s += __shfl_xor(s, off, 64); s2 += __shfl_xor(s2, off, 64); }
  __shared__ float a[4], b[4];
  if ((t & 63) == 0){ a[t>>6] = s; b[t>>6] = s2; }
  __syncthreads();
  float S = a[0]+a[1]+a[2]+a[3], S2 = b[0]+b[1]+b[2]+b[3];
  float mu = S/1024.f, var = S2/1024.f - mu*mu, rs = rsqrtf(var + 1e-5f);
  unsigned short* G = (unsigned short*)(W + O_G2);
  for (int q=0; q<4; ++q){
    int dch = t + q*256;
    float yn = (v[q]-mu)*rs*W[I_V2ONW + dch] + W[I_V2ONB + dch];
    float z = W[O_XZ2 + (long long)l*2048 + 1024 + dch];
    G[(long long)l*1024 + dch] = f2bf(yn * siluf(z));
  }
}

// =============== launch ===============
extern "C" void kernel_launch(void* const* d_in, const int* in_sizes, int n_in,
                              void* d_out, int out_size, void* d_ws, size_t ws_size,
                              hipStream_t stream){
  if (ws_size < (size_t)WS_FLOATS * sizeof(float)) return;
  float* W = (float*)d_ws;
  PtrTab tab;
  for (int i=0; i<53; ++i) tab.p[i] = d_in[i];
  const unsigned int* flagp = (const unsigned int*)d_in[9];

  k_ingest<<<INGEST_BLOCKS, 256, 0, stream>>>(tab, W);
  k_prep  <<<12480, 256, 0, stream>>>(W);

  k_c0    <<<64, 256, 0, stream>>>(W);
  k_zxf   <<<2320, 256, 0, stream>>>(W);
  k_conv4 <<<160, 256, 0, stream>>>(W);
  k_dtm   <<<2, 256, 0, stream>>>(W);
  k_mscan <<<1024, 64, 0, stream>>>(W);
  k_gaterms<<<32, 256, 0, stream>>>(W);
  k_outmf <<<512, 256, 0, stream>>>(W);
  k_c1f   <<<1024, 256, 0, stream>>>(W);
  k_ln1   <<<4, 256, 0, stream>>>(W);
  k_xz1   <<<512, 256, 0, stream>>>(W);
  k_dwcs1 <<<256, 256, 0, stream>>>(W);
  k_dbl1  <<<544, 256, 0, stream>>>(W);
  // vss1 chunked scan
  k_transpose<<<dim3(32, 2), 256, 0, stream>>>(W + O_XC1, W + O_XT1, 64, 1024, 1024, 64);
  k_scan_p1<64,64,1024,5,64,2,34,40,4,18><<<dim3(4,16), 64, 0, stream>>>(W, O_DBL1, O_XT1, O_P1, O_S1,
                                                                 I_V1DTW, I_V1DTB, I_V1ALOG);
  k_carry<4096,16><<<16, 256, 0, stream>>>(W, O_P1, O_S1);
  k_scan_p3<64,64,1024,5,64,2,34,40,4><<<dim3(4,16), 64, 0, stream>>>(W, O_DBL1, O_XT1, O_S1, O_YS1,
                                                                 I_V1DTW, I_V1DTB, I_V1ALOG, I_V1D);
  k_comb1 <<<1024, 64, 0, stream>>>(W);
  k_oproj1<<<128, 256, 0, stream>>>(W);
  k_dw1   <<<128, 256, 0, stream>>>(W);
  k_pw1   <<<256, 256, 0, stream>>>(W);
  k_dw2   <<<256, 256, 0, stream>>>(W);
  k_pw2   <<<512, 256, 0, stream>>>(W);
  k_resize<<<2048, 256, 0, stream>>>(W);
  // cv1 via MFMA
  k_transpose_dual<<<dim3(128, 4), 256, 0, stream>>>(W + O_E5, nullptr,
                      (unsigned short*)(W + O_E5TB), 128, 4096, 4096, 128);
  k_im2colT<128><<<dim3(5, 4096), 256, 0, stream>>>((const unsigned short*)(W + O_E5TB),
                      (unsigned short*)(W + O_CV1B2));
  k_gemm_bt<1><<<dim3(1, 32), 256, 0, stream>>>((const unsigned short*)(W + O_CV1WB),
                      (const unsigned short*)(W + O_CV1B2), 1152, 4096,
                      W + O_E6, W + I_CV1B, nullptr, nullptr, nullptr);
  // cv2 via MFMA
  k_transpose_dual<<<dim3(128, 4), 256, 0, stream>>>(W + O_E6, nullptr,
                      (unsigned short*)(W + O_E6TB), 128, 4096, 4096, 128);
  k_gemm_bt<1><<<dim3(2, 32), 256, 0, stream>>>((const unsigned short*)(W + O_CV2WB),
                      (const unsigned short*)(W + O_E6TB), 128, 4096,
                      W + O_E7, W + I_CV2B, nullptr, nullptr, nullptr);
  // fc via MFMA
  k_transpose_dual<<<dim3(128, 8), 256, 0, stream>>>(W + O_E7, nullptr,
                      (unsigned short*)(W + O_E7T), 256, 4096, 4096, 256);
  k_im2colT<256><<<dim3(9, 4096), 256, 0, stream>>>((const unsigned short*)(W + O_E7T),
                      (unsigned short*)(W + O_B2));
  k_gemm_bt<1><<<dim3(4, 32), 256, 0, stream>>>((const unsigned short*)(W + O_FCW2),
                      (const unsigned short*)(W + O_B2), 2304, 4096,
                      W + O_E8, W + I_FCB, nullptr, nullptr, nullptr);
  // vss2
  k_ln2   <<<4096, 256, 0, stream>>>(W);
  k_gemm_bt<0><<<dim3(32, 16), 256, 0, stream>>>((const unsigned short*)(W + O_LN2),
                      (const unsigned short*)(W + O_W2INB), 512, 2048,
                      W + O_XZ2, nullptr, nullptr, nullptr, nullptr);
  k_transpose<<<dim3(32, 128), 256, 0, stream>>>(W + O_XZ2, W + O_XT2, 4096, 1024, 2048, 4096);
  k_dwcs2 <<<16384, 256, 0, stream>>>(W);
  k_transpose_dual<<<dim3(128, 32), 256, 0, stream>>>(W + O_XC2, W + O_XT2,
                      (unsigned short*)(W + O_XT2B), 1024, 4096, 4096, 1024);
  k_gemm_bt<0><<<dim3(2, 32), 256, 0, stream>>>((const unsigned short*)(W + O_XPWB),
                      (const unsigned short*)(W + O_XT2B), 1024, 4096,
                      W + O_DBL2, nullptr, nullptr, nullptr, nullptr);
  k_scan_p1<1024,256,4096,6,64,32,64,68,32,48><<<dim3(16,64), 256, 0, stream>>>(W, O_DBL2, O_XT2, O_P2, O_S2,
                                                                       I_V2DTW, I_V2DTB, I_V2ALOG);
  k_carry<65536,64><<<256, 256, 0, stream>>>(W, O_P2, O_S2);
  k_scan_p3<1024,256,4096,6,64,32,64,68,32><<<dim3(16,64), 256, 0, stream>>>(W, O_DBL2, O_XT2, O_S2, O_YS2,
                                                                       I_V2DTW, I_V2DTB, I_V2ALOG, I_V2D);
  k_comb2 <<<4096, 256, 0, stream>>>(W);
  k_gemm_bt<2><<<dim3(4, 32), 256, 0, stream>>>((const unsigned short*)(W + O_OUTWB),
                      (const unsigned short*)(W + O_G2), 1024, 4096,
                      nullptr, nullptr, W + O_E8, flagp, d_out);
}